// Round 10
// baseline (1470.044 us; speedup 1.0000x reference)
//
#include <hip/hip_runtime.h>
#include <float.h>
#include <math.h>

#define B_ 8
#define C_ 256
#define H_ 96
#define W_ 96
#define HW_ 9216
#define NQ_ 100
#define EPS_ 1e-6f
#define PADW_ 98
#define PADIMG_ 9604          // 98*98 padded image
#define PALLOC_ 76880         // 8*9604 + slack rows for A-stage overrun

typedef unsigned short ushort_t;
typedef __attribute__((ext_vector_type(8))) short bf16x8;
typedef __attribute__((ext_vector_type(4))) float f32x4;
typedef __attribute__((ext_vector_type(16))) float f32x16;

typedef __attribute__((address_space(3))) unsigned int as3_u32;
typedef __attribute__((address_space(1))) unsigned int as1_u32;

__device__ __forceinline__ void gl16(const void* g, void* l) {
    __builtin_amdgcn_global_load_lds(
        (const as1_u32*)(unsigned long long)g,
        (as3_u32*)(unsigned int)(unsigned long long)l, 16, 0, 0);
}

__device__ __forceinline__ ushort_t bf16_of(float v) {
    unsigned u = __float_as_uint(v);
    u += 0x7fffu + ((u >> 16) & 1u);
    return (ushort_t)(u >> 16);
}
__device__ __forceinline__ float f_of_bf16(ushort_t h) {
    return __uint_as_float((unsigned)h << 16);
}

// ---------------------------------------------------------------------------
// Zero the 1-px border of each padded image (388 px/img), both splits.
// ---------------------------------------------------------------------------
__global__ __launch_bounds__(256)
void zero_border_kernel(ushort_t* __restrict__ bh, ushort_t* __restrict__ bl, int Cch)
{
    int per = 388 * Cch / 8;
    int id = blockIdx.x * 256 + threadIdx.x;
    if (id >= 8 * per) return;
    int b = id / per, i = id - b * per;
    int pi = (i * 8) / Cch, c8 = (i * 8) % Cch;
    int yy, xx;
    if (pi < 98)      { yy = 0;            xx = pi; }
    else if (pi < 196){ yy = 97;           xx = pi - 98; }
    else if (pi < 292){ yy = pi - 195;     xx = 0; }
    else              { yy = pi - 291;     xx = 97; }
    size_t base = ((size_t)b * PADIMG_ + yy * PADW_ + xx) * Cch + c8;
    *(bf16x8*)&bh[base] = (bf16x8)(short)0;
    *(bf16x8*)&bl[base] = (bf16x8)(short)0;
}

// Zero the head-logit output regions (atomicAdd targets). 276480 float4.
__global__ __launch_bounds__(256)
void zero_logits_kernel(float* __restrict__ p)
{
    int i = blockIdx.x * 256 + threadIdx.x;
    if (i < 276480) ((f32x4*)p)[i] = (f32x4){0.f, 0.f, 0.f, 0.f};
}

// ---------------------------------------------------------------------------
// Transpose+split into padded layout: in [b][C][96*96] fp32 ->
// oh/ol [b*PADIMG + (y+1)*98 + x+1][C] bf16 hi/lo (interior only)
// ---------------------------------------------------------------------------
__global__ __launch_bounds__(256)
void tsplit_kernel(const float* __restrict__ in, ushort_t* __restrict__ oh,
                   ushort_t* __restrict__ ol, int Cch)
{
    __shared__ float T[32][33];
    const int tx = threadIdx.x & 31, ty = threadIdx.x >> 5;
    const int p0 = blockIdx.x * 32, ci0 = blockIdx.y * 32, b = blockIdx.z;
#pragma unroll
    for (int i = 0; i < 4; ++i)
        T[ty + 8*i][tx] = in[((size_t)b*Cch + ci0 + ty + 8*i)*HW_ + p0 + tx];
    __syncthreads();
    const int y = p0 / 96, x0 = p0 - y * 96;
    const size_t Pp = (size_t)b*PADIMG_ + (size_t)(y + 1)*PADW_ + x0 + 1;
#pragma unroll
    for (int i = 0; i < 4; ++i) {
        float v = T[tx][ty + 8*i];
        ushort_t hi = bf16_of(v);
        float lo = v - f_of_bf16(hi);
        size_t o = (Pp + ty + 8*i)*Cch + ci0 + tx;
        oh[o] = hi;
        ol[o] = bf16_of(lo);
    }
}

// ---------------------------------------------------------------------------
// Weight repack: w [oc][ci][3][3] fp32 -> wh/wl [tap][g][oc][ci16] bf16 hi/lo
// ---------------------------------------------------------------------------
__global__ __launch_bounds__(256)
void repack_kernel(const float* __restrict__ w, ushort_t* __restrict__ wh,
                   ushort_t* __restrict__ wl, int Cout, int Cin)
{
    int id = blockIdx.x*256 + threadIdx.x;
    int tot = 9*Cout*Cin;
    if (id >= tot) return;
    int tap = id / (Cout*Cin);
    int r   = id - tap*(Cout*Cin);
    int g   = r / (Cout*16);
    int r2  = r - g*(Cout*16);
    int oc  = r2 >> 4, cr = r2 & 15;
    int ci  = g*16 + cr;
    float v = w[((size_t)oc*Cin + ci)*9 + tap];
    ushort_t hi = bf16_of(v);
    wh[id] = hi;
    wl[id] = bf16_of(v - f_of_bf16(hi));
}

// ---------------------------------------------------------------------------
// Pack per-head params: bias1all[3][256]; w2all[3][11][256] (zero-padded for
// L/R); b2all[3][11] (zero-padded).
// ---------------------------------------------------------------------------
__global__ __launch_bounds__(256)
void pack_heads3_kernel(const float* lb1, const float* rb1, const float* ob1,
                        const float* lw2, const float* rw2, const float* ow2,
                        const float* lb2, const float* rb2, const float* ob2,
                        float* __restrict__ bias1all, float* __restrict__ w2all,
                        float* __restrict__ b2all)
{
    int i = blockIdx.x * 256 + threadIdx.x;
    if (i < 768) bias1all[i] = (i < 256) ? lb1[i] : (i < 512) ? rb1[i-256] : ob1[i-512];
    if (i < 33) {
        int h = i / 11, k = i - h*11;
        b2all[i] = (h == 0) ? (k < 2 ? lb2[k] : 0.f)
                 : (h == 1) ? (k < 2 ? rb2[k] : 0.f)
                 : ob2[k];
    }
    if (i < 3*11*256) {
        int h = i / 2816, r = i - h*2816;
        int k = r / 256, oc = r - k*256;
        float v = 0.f;
        if (h == 0)      { if (k < 2) v = lw2[k*256 + oc]; }
        else if (h == 1) { if (k < 2) v = rw2[k*256 + oc]; }
        else             v = ow2[k*256 + oc];
        w2all[i] = v;
    }
}

// ---------------------------------------------------------------------------
// Implicit-GEMM conv3x3 (round-6 structure, for the contact branch only):
// A in LDS (double-buffered, gl16); B global->register 3-set rotation; one
// barrier per k-group, counted vmcnt.
//   MODE 1: bias+relu -> Oth/Otl padded-transposed [P'][COUT] bf16 hi/lo
//   MODE 2: bias+relu -> outf [b][COUT][HW] fp32 (LDS transpose)
// ---------------------------------------------------------------------------
template<int WM, int WN, int MFR, int NFR, int CIN, int MODE>
__global__ __launch_bounds__(WM*WN*64, (WM*WN + 3) / 4)
void conv_gemm_kernel(const ushort_t* __restrict__ Agh, const ushort_t* __restrict__ Agl,
                      const ushort_t* __restrict__ Wgh, const ushort_t* __restrict__ Wgl,
                      const float* __restrict__ bias1,
                      ushort_t* __restrict__ Oth, ushort_t* __restrict__ Otl,
                      float* __restrict__ outf)
{
    constexpr int NW    = WM*WN;
    constexpr int NT    = NW*64;
    constexpr int BM    = WM*MFR*32;      // 288
    constexpr int COUT  = WN*NFR*32;
    constexpr int NG    = CIN/16;
    constexpr int APAD  = 512;
    constexpr int ASZ   = 2*APAD*16;
    constexpr int AROUNDS = 32;
    static_assert(BM == 288, "BM must be 288");

    __shared__ __align__(16) ushort_t ALds[2*ASZ];

    const int tid  = threadIdx.x;
    const int lane = tid & 63;
    const int wid  = __builtin_amdgcn_readfirstlane(tid >> 6);
    const int wm   = wid / WN, wn = wid % WN;
    const int l31  = lane & 31, hh2 = lane >> 5;
    const int wnb  = wn * NFR * 32;

    const int cpx = gridDim.x >> 3;
    const int bid = (blockIdx.x & 7)*cpx + (blockIdx.x >> 3);
    const int bidx = bid >> 5;
    const int br   = bid & 31;
    const size_t S = (size_t)bidx*PADIMG_ + (size_t)(3*br)*PADW_;

    auto stageA = [&](int g, int sel) {
        ushort_t* dst = ALds + sel*ASZ;
#pragma unroll 1
        for (int c = wid; c < AROUNDS; c += NW) {
            int id = c*64 + lane;
            int split = id >> 10;
            int r2 = id & 1023;
            int row = r2 >> 1, slot = r2 & 1;
            int ch = slot ^ ((row >> 2) & 1);
            const ushort_t* src = (split ? Agl : Agh) + (S + row)*CIN + g*16 + ch*8;
            gl16(src, dst + (size_t)c*512);
        }
    };

    f32x16 acc[MFR][NFR];
#pragma unroll
    for (int i = 0; i < MFR; ++i)
#pragma unroll
        for (int j = 0; j < NFR; ++j)
#pragma unroll
            for (int r = 0; r < 16; ++r) acc[i][j][r] = 0.f;

    bf16x8 bh0[NFR], bl0[NFR], bh1[NFR], bl1[NFR], bh2[NFR], bl2[NFR];

#define LOADB(G, T, BH, BL)                                                    \
    {                                                                          \
        _Pragma("unroll")                                                      \
        for (int nf = 0; nf < NFR; ++nf) {                                     \
            size_t o = ((size_t)((T)*NG + (G))*COUT + (wnb + nf*32 + l31))*16  \
                       + hh2*8;                                                \
            BH[nf] = *(const bf16x8*)&Wgh[o];                                  \
            BL[nf] = *(const bf16x8*)&Wgl[o];                                  \
        }                                                                      \
    }

    stageA(0, 0);
    LOADB(0, 0, bh0, bl0);
    LOADB(0, 1, bh1, bl1);
    __builtin_amdgcn_sched_barrier(0);
    asm volatile("s_waitcnt vmcnt(%0)" :: "n"(4*NFR) : "memory");
    __builtin_amdgcn_s_barrier();
    __builtin_amdgcn_sched_barrier(0);

#define TAPBODY(T, BHC, BLC, BHN, BLN)                                         \
    {                                                                          \
        if ((T) <= 6)            LOADB(g,     (T)+2, BHN, BLN)                 \
        else if (g + 1 < NG)     LOADB(g+1,   (T)-7, BHN, BLN)                 \
        const int tapoff = ((T)/3)*PADW_ + ((T) % 3);                          \
        _Pragma("unroll")                                                      \
        for (int mf = 0; mf < MFR; ++mf) {                                     \
            int row = wm*PADW_ + tapoff + mf*32 + l31;                         \
            int o = abase + row*16 + ((hh2 ^ ((row >> 2) & 1)) << 3);          \
            bf16x8 ah = *(const bf16x8*)&ALds[o];                              \
            bf16x8 al = *(const bf16x8*)&ALds[o + APAD*16];                    \
            _Pragma("unroll")                                                  \
            for (int nf = 0; nf < NFR; ++nf) {                                 \
                acc[mf][nf] = __builtin_amdgcn_mfma_f32_32x32x16_bf16(         \
                    ah, BHC[nf], acc[mf][nf], 0, 0, 0);                        \
                acc[mf][nf] = __builtin_amdgcn_mfma_f32_32x32x16_bf16(         \
                    al, BHC[nf], acc[mf][nf], 0, 0, 0);                        \
                acc[mf][nf] = __builtin_amdgcn_mfma_f32_32x32x16_bf16(         \
                    ah, BLC[nf], acc[mf][nf], 0, 0, 0);                        \
            }                                                                  \
        }                                                                      \
    }

#pragma unroll 1
    for (int g = 0; g < NG; ++g) {
        if (g + 1 < NG) stageA(g + 1, (g + 1) & 1);
        const int abase = (g & 1) * ASZ;
        TAPBODY(0, bh0, bl0, bh2, bl2);
        TAPBODY(1, bh1, bl1, bh0, bl0);
        TAPBODY(2, bh2, bl2, bh1, bl1);
        TAPBODY(3, bh0, bl0, bh2, bl2);
        TAPBODY(4, bh1, bl1, bh0, bl0);
        TAPBODY(5, bh2, bl2, bh1, bl1);
        TAPBODY(6, bh0, bl0, bh2, bl2);
        TAPBODY(7, bh1, bl1, bh0, bl0);
        TAPBODY(8, bh2, bl2, bh1, bl1);
        __builtin_amdgcn_sched_barrier(0);
        asm volatile("s_waitcnt vmcnt(%0)" :: "n"(4*NFR) : "memory");
        __builtin_amdgcn_s_barrier();
        __builtin_amdgcn_sched_barrier(0);
    }
#undef TAPBODY
#undef LOADB
    __syncthreads();

    float biasv[NFR];
#pragma unroll
    for (int nf = 0; nf < NFR; ++nf) biasv[nf] = bias1[wnb + nf*32 + l31];

    if constexpr (MODE == 1) {
#pragma unroll
        for (int mf = 0; mf < MFR; ++mf)
#pragma unroll
            for (int nf = 0; nf < NFR; ++nf)
#pragma unroll
                for (int r = 0; r < 16; ++r) {
                    float rr = fmaxf(acc[mf][nf][r] + biasv[nf], 0.f);
                    ushort_t hi = bf16_of(rr);
                    float lo = rr - f_of_bf16(hi);
                    int crow = (r & 3) + 8*(r >> 2) + 4*hh2;
                    int xx = mf*32 + crow;
                    size_t Pp = (size_t)bidx*PADIMG_
                              + (size_t)(3*br + wm + 1)*PADW_ + xx + 1;
                    size_t o = Pp*COUT + wnb + nf*32 + l31;
                    Oth[o] = hi;
                    Otl[o] = bf16_of(lo);
                }
    } else {
        float (*T)[BM + 1] = (float(*)[BM + 1])ALds;
#pragma unroll
        for (int mf = 0; mf < MFR; ++mf)
#pragma unroll
            for (int r = 0; r < 16; ++r) {
                float rr = fmaxf(acc[mf][0][r] + biasv[0], 0.f);
                int crow = (r & 3) + 8*(r >> 2) + 4*hh2;
                T[l31][wm*96 + mf*32 + crow] = rr;
            }
        __syncthreads();
        for (int i = tid; i < COUT*BM; i += NT) {
            int c = i / BM, m = i - c*BM;
            outf[((size_t)bidx*COUT + c)*HW_ + br*288 + m] = T[c][m];
        }
    }
}

// ---------------------------------------------------------------------------
// Round-10 unified head kernel: all 3 heads, COUT split 2x across blocks.
// grid 4608 = 3 heads x 2 oc-halves x 768 (img-row blocks). 4 waves, NFR=1
// (acc 48 AGPR -> target 4 waves/SIMD, launch_bounds(256,4)), 19.5KB LDS,
// single A-buffer drained per k-group. Fused 1x1 epilogue -> atomicAdd into
// zero-initialized logits (exactly 2 commutative fp32 contributors ->
// deterministic).
// ---------------------------------------------------------------------------
__global__ __launch_bounds__(256, 4)
void conv_sb3_kernel(const ushort_t* __restrict__ Agh, const ushort_t* __restrict__ Agl,
                     const ushort_t* __restrict__ wLh, const ushort_t* __restrict__ wLl,
                     const ushort_t* __restrict__ wRh, const ushort_t* __restrict__ wRl,
                     const ushort_t* __restrict__ wOh, const ushort_t* __restrict__ wOl,
                     const float* __restrict__ bias1all, const float* __restrict__ w2all,
                     const float* __restrict__ b2all, float* __restrict__ out_logits)
{
    constexpr int NG = 16, APAD = 304, ASZ = 2*APAD*16, AGR = 19, MFR = 3;
    __shared__ __align__(16) ushort_t ALds[ASZ];

    const int tid  = threadIdx.x;
    const int lane = tid & 63;
    const int wid  = __builtin_amdgcn_readfirstlane(tid >> 6);
    const int l31  = lane & 31, hh2 = lane >> 5;

    const int cpx = gridDim.x >> 3;                       // 576
    const int bid = (blockIdx.x & 7)*cpx + (blockIdx.x >> 3);
    const int h    = bid / 1536;
    const int rr_  = bid - h*1536;
    const int ocb  = rr_ / 768;
    const int sub  = rr_ - ocb*768;
    const int bidx = sub / 96, prow = sub - bidx*96;
    const int pimg0 = prow * 96;
    const size_t S = (size_t)bidx*PADIMG_ + (size_t)prow*PADW_;

    const ushort_t* Wh = (h == 0) ? wLh : (h == 1) ? wRh : wOh;
    const ushort_t* Wl = (h == 0) ? wLl : (h == 1) ? wRl : wOl;
    const int oc0 = ocb*128 + wid*32;                     // wave's channel base in 256
    const float* bias1 = bias1all + h*256;
    const float* w2    = w2all + (size_t)h*2816;          // [11][256]
    const float* b2    = b2all + h*11;
    const int kklim = (h == 2) ? 11 : 2;
    float* dst = out_logits + ((h == 0) ? 0 : (h == 1) ? 147456 : 294912);

    auto stageA = [&](int g) {
#pragma unroll 1
        for (int c = wid; c < AGR; c += 4) {
            int id = c*64 + lane;
            int split = id / (2*APAD);
            int r2 = id % (2*APAD);
            int row = r2 >> 1, slot = r2 & 1;
            int ch = slot ^ ((row >> 2) & 1);
            const ushort_t* src = (split ? Agl : Agh) + (S + row)*C_ + g*16 + ch*8;
            gl16(src, ALds + (size_t)c*512);
        }
    };

    f32x16 acc[MFR];
#pragma unroll
    for (int i = 0; i < MFR; ++i)
#pragma unroll
        for (int r = 0; r < 16; ++r) acc[i][r] = 0.f;

    bf16x8 bhX, blX, bhY, blY;

#define LOADB(G, T, BH, BL)                                                    \
    {                                                                          \
        size_t o = ((size_t)((T)*NG + (G))*256 + (oc0 + l31))*16 + hh2*8;      \
        BH = *(const bf16x8*)&Wh[o];                                           \
        BL = *(const bf16x8*)&Wl[o];                                           \
    }

#define TAPBODY(G, T, BHC, BLC, BHN, BLN)                                      \
    {                                                                          \
        if ((T) < 8)             LOADB((G), (T)+1, BHN, BLN)                   \
        else if ((G) + 1 < NG)   LOADB((G)+1, 0, BHN, BLN)                     \
        const int tapoff = ((T)/3)*PADW_ + ((T) % 3);                          \
        _Pragma("unroll")                                                      \
        for (int mf = 0; mf < MFR; ++mf) {                                     \
            int row = tapoff + mf*32 + l31;                                    \
            int o = row*16 + ((hh2 ^ ((row >> 2) & 1)) << 3);                  \
            bf16x8 ah = *(const bf16x8*)&ALds[o];                              \
            bf16x8 al = *(const bf16x8*)&ALds[o + APAD*16];                    \
            acc[mf] = __builtin_amdgcn_mfma_f32_32x32x16_bf16(                 \
                ah, BHC, acc[mf], 0, 0, 0);                                    \
            acc[mf] = __builtin_amdgcn_mfma_f32_32x32x16_bf16(                 \
                al, BHC, acc[mf], 0, 0, 0);                                    \
            acc[mf] = __builtin_amdgcn_mfma_f32_32x32x16_bf16(                 \
                ah, BLC, acc[mf], 0, 0, 0);                                    \
        }                                                                      \
    }

#define GROUPBODY(G, S0h, S0l, S1h, S1l)                                       \
    {                                                                          \
        TAPBODY((G), 0, S0h, S0l, S1h, S1l);                                   \
        TAPBODY((G), 1, S1h, S1l, S0h, S0l);                                   \
        TAPBODY((G), 2, S0h, S0l, S1h, S1l);                                   \
        TAPBODY((G), 3, S1h, S1l, S0h, S0l);                                   \
        TAPBODY((G), 4, S0h, S0l, S1h, S1l);                                   \
        TAPBODY((G), 5, S1h, S1l, S0h, S0l);                                   \
        TAPBODY((G), 6, S0h, S0l, S1h, S1l);                                   \
        TAPBODY((G), 7, S1h, S1l, S0h, S0l);                                   \
        TAPBODY((G), 8, S0h, S0l, S1h, S1l);                                   \
    }

#define STAGEWAIT(G)                                                           \
    __builtin_amdgcn_s_barrier();                                              \
    stageA(G);                                                                 \
    __builtin_amdgcn_sched_barrier(0);                                         \
    asm volatile("s_waitcnt vmcnt(0)" ::: "memory");                           \
    __builtin_amdgcn_s_barrier();                                              \
    __builtin_amdgcn_sched_barrier(0);

    LOADB(0, 0, bhX, blX);

#pragma unroll 1
    for (int g = 0; g < NG; g += 2) {
        STAGEWAIT(g)
        GROUPBODY(g,     bhX, blX, bhY, blY);
        STAGEWAIT(g + 1)
        GROUPBODY(g + 1, bhY, blY, bhX, blX);
    }
#undef STAGEWAIT
#undef GROUPBODY
#undef TAPBODY
#undef LOADB
    __syncthreads();

    // ---- fused 1x1 epilogue: partial over this block's 128 channels ----
    float biasv = bias1[oc0 + l31];
    float w2v[11];
#pragma unroll
    for (int k = 0; k < 11; ++k) w2v[k] = w2[k*256 + oc0 + l31];

    float* Lacc = (float*)ALds;               // [4][96][11] = 16.9KB
#pragma unroll
    for (int mf = 0; mf < MFR; ++mf) {
#pragma unroll
        for (int r = 0; r < 16; ++r) {
            float rr2 = fmaxf(acc[mf][r] + biasv, 0.f);
            float v[11];
#pragma unroll
            for (int k = 0; k < 11; ++k) {
                if (k < kklim) {              // uniform branch, static index
                    v[k] = rr2 * w2v[k];
                    v[k] += __shfl_xor(v[k], 1);
                    v[k] += __shfl_xor(v[k], 2);
                    v[k] += __shfl_xor(v[k], 4);
                    v[k] += __shfl_xor(v[k], 8);
                    v[k] += __shfl_xor(v[k], 16);
                } else v[k] = 0.f;
            }
            if (l31 == 0) {
                int crow = (r & 3) + 8*(r >> 2) + 4*hh2;
                int row96 = mf*32 + crow;
#pragma unroll
                for (int k = 0; k < 11; ++k)
                    if (k < kklim)
                        Lacc[((size_t)wid*96 + row96)*11 + k] = v[k];
            }
        }
    }
    __syncthreads();
    for (int i = tid; i < 96*kklim; i += 256) {
        int row96 = i / kklim, k = i - row96*kklim;
        float s = (ocb == 0) ? b2[k] : 0.f;
#pragma unroll
        for (int w = 0; w < 4; ++w) s += Lacc[((size_t)w*96 + row96)*11 + k];
        atomicAdd(&dst[((size_t)bidx*kklim + k)*HW_ + pimg0 + row96], s);
    }
}

// ---------------------------------------------------------------------------
// Softmax / mask / NMS-score kernels. L/R heads batched over blockIdx.y.
// ---------------------------------------------------------------------------
__global__ __launch_bounds__(256)
void prob2b_kernel(const float* __restrict__ l2, const float* __restrict__ l3,
                   float* __restrict__ pL, float* __restrict__ pR)
{
    const float* logits = blockIdx.y ? l3 : l2;
    float* p0 = blockIdx.y ? pR : pL;
    int i = blockIdx.x * 256 + threadIdx.x;
    if (i >= B_ * HW_) return;
    int b = i / HW_, pix = i - b * HW_;
    float l0 = logits[(size_t)b * 2 * HW_ + pix];
    float l1 = logits[(size_t)b * 2 * HW_ + HW_ + pix];
    float m = fmaxf(l0, l1);
    float e0 = expf(l0 - m), e1 = expf(l1 - m);
    p0[i] = e0 / (e0 + e1);
}

__global__ __launch_bounds__(256)
void score2b_kernel(const float* __restrict__ pL, const float* __restrict__ pR,
                    float* __restrict__ sL, float* __restrict__ sR)
{
    const float* p = blockIdx.y ? pR : pL;
    float* sc = blockIdx.y ? sR : sL;
    int i = blockIdx.x * 256 + threadIdx.x;
    if (i >= B_ * HW_) return;
    int pix = i % HW_;
    int yy = pix / W_, xx = pix - (pix / W_) * W_;
    float c = p[i];
    bool ok = (c >= EPS_);
    const float* pb = p + (i - pix);
#pragma unroll
    for (int dy = -1; dy <= 1; ++dy)
#pragma unroll
        for (int dx = -1; dx <= 1; ++dx) {
            if (dy == 0 && dx == 0) continue;
            int ny = yy + dy, nx = xx + dx;
            float v = 0.f;
            if (ny >= 0 && ny < H_ && nx >= 0 && nx < W_) v = pb[ny * W_ + nx];
            ok = ok && (c >= v);
        }
    sc[i] = c + (ok ? 1.f : 0.f);
}

__global__ __launch_bounds__(256)
void probobj_kernel(const float* __restrict__ logits, float* __restrict__ pval,
                    int* __restrict__ cstar)
{
    int i = blockIdx.x * 256 + threadIdx.x;
    if (i >= B_ * HW_) return;
    int b = i / HW_, pix = i - b * HW_;
    const float* lb = logits + (size_t)b * 11 * HW_ + pix;
    float l[11];
#pragma unroll
    for (int c2 = 0; c2 < 11; ++c2) l[c2] = lb[(size_t)c2 * HW_];
    float m = l[0];
#pragma unroll
    for (int c2 = 1; c2 < 11; ++c2) m = fmaxf(m, l[c2]);
    float sum = 0.f;
#pragma unroll
    for (int c2 = 0; c2 < 11; ++c2) sum += expf(l[c2] - m);
    int a = 0; float bestl = l[0];
#pragma unroll
    for (int c2 = 1; c2 < 10; ++c2)
        if (l[c2] > bestl) { bestl = l[c2]; a = c2; }
    pval[i] = expf(bestl - m) / sum;
    cstar[i] = a;
}

__global__ __launch_bounds__(256)
void score11_kernel(const float* __restrict__ p, const int* __restrict__ cs,
                    float* __restrict__ sc)
{
    int i = blockIdx.x * 256 + threadIdx.x;
    if (i >= B_ * HW_) return;
    int pix = i % HW_;
    int yy = pix / W_, xx = pix - (pix / W_) * W_;
    float c = p[i];
    int cc = cs[i];
    bool ok = (c >= EPS_);
    int base = i - pix;
#pragma unroll
    for (int dy = -1; dy <= 1; ++dy)
#pragma unroll
        for (int dx = -1; dx <= 1; ++dx) {
            if (dy == 0 && dx == 0) continue;
            int ny = yy + dy, nx = xx + dx;
            float v = 0.f;
            if (ny >= 0 && ny < H_ && nx >= 0 && nx < W_) {
                int n = base + ny * W_ + nx;
                v = (cs[n] == cc) ? p[n] : 0.f;
            }
            ok = ok && (c >= v);
        }
    sc[i] = c + (ok ? 1.f : 0.f);
}

// ---------------------------------------------------------------------------
// top-k by iterative argmax (matches jax.lax.top_k ordering)
// ---------------------------------------------------------------------------
__global__ __launch_bounds__(256)
void topk_kernel(const float* __restrict__ scL, const float* __restrict__ scR,
                 const float* __restrict__ scO, int* __restrict__ idx)
{
    __shared__ float sv[HW_];
    __shared__ float rv[256];
    __shared__ int   ri[256];
    const int h = blockIdx.x, b = blockIdx.y;
    const float* src = (h == 0) ? scL : (h == 1) ? scR : scO;
    const int k = (h == 2) ? 20 : 40;
    const int off = b * NQ_ + ((h == 0) ? 0 : (h == 1) ? 40 : 80);

    for (int t = threadIdx.x; t < HW_; t += 256) sv[t] = src[(size_t)b * HW_ + t];
    __syncthreads();

    for (int kk = 0; kk < k; ++kk) {
        float bestv = -FLT_MAX; int besti = HW_;
        for (int t = threadIdx.x; t < HW_; t += 256) {
            float v = sv[t];
            if (v > bestv) { bestv = v; besti = t; }
        }
        rv[threadIdx.x] = bestv; ri[threadIdx.x] = besti;
        __syncthreads();
        for (int s = 128; s > 0; s >>= 1) {
            if (threadIdx.x < s) {
                float v2 = rv[threadIdx.x + s]; int i2 = ri[threadIdx.x + s];
                if (v2 > rv[threadIdx.x] ||
                    (v2 == rv[threadIdx.x] && i2 < ri[threadIdx.x])) {
                    rv[threadIdx.x] = v2; ri[threadIdx.x] = i2;
                }
            }
            __syncthreads();
        }
        if (threadIdx.x == 0) { idx[off + kk] = ri[0]; sv[ri[0]] = -FLT_MAX; }
        __syncthreads();
    }
}

// ---------------------------------------------------------------------------
// Contact branch tail (unchanged)
// ---------------------------------------------------------------------------
__global__ __launch_bounds__(128)
void pool_kernel(const float* __restrict__ h2, float* __restrict__ pooled)
{
    int bc = blockIdx.x;
    __shared__ float row[96];
    for (int hh = threadIdx.x; hh < 96; hh += 128) {
        const float* p = h2 + (size_t)bc * HW_ + hh * W_;
        float s = 0.f;
        for (int ww = 0; ww < 96; ++ww) s += p[ww];
        row[hh] = s * (1.f / 96.f);
    }
    __syncthreads();
    for (int i = threadIdx.x; i < 778; i += 128) {
        int s0 = (i * 96) / 778;
        int e0 = ((i + 1) * 96 + 777) / 778;
        float s = 0.f;
        for (int t = s0; t < e0; ++t) s += row[t];
        pooled[(size_t)bc * 778 + i] = s / (float)(e0 - s0);
    }
}

__global__ __launch_bounds__(256)
void cm_kernel(const float* __restrict__ pooled, const float* __restrict__ cm_lw,
               const float* __restrict__ cm_lb, float* __restrict__ out5)
{
    const int j = blockIdx.x;
    const float* wr = cm_lw + (size_t)j * 24896;
    float acc[8];
#pragma unroll
    for (int b = 0; b < 8; ++b) acc[b] = 0.f;
    for (int t = threadIdx.x; t < 24896; t += 256) {
        float w = wr[t];
#pragma unroll
        for (int b = 0; b < 8; ++b) acc[b] += w * pooled[(size_t)b * 24896 + t];
    }
    __shared__ float red[8][256];
#pragma unroll
    for (int b = 0; b < 8; ++b) red[b][threadIdx.x] = acc[b];
    __syncthreads();
    for (int s = 128; s > 0; s >>= 1) {
        if (threadIdx.x < s) {
#pragma unroll
            for (int b = 0; b < 8; ++b) red[b][threadIdx.x] += red[b][threadIdx.x + s];
        }
        __syncthreads();
    }
    if (threadIdx.x < 8)
        out5[(size_t)threadIdx.x * 1556 + j] = red[threadIdx.x][0] + cm_lb[j];
}

__global__ __launch_bounds__(256)
void c1d_kernel(const float* __restrict__ cmap, const float* __restrict__ w,
                const float* __restrict__ bias, float* __restrict__ ccmean)
{
    int b = blockIdx.x;
    __shared__ float r[2][778];
    __shared__ float T[2][3];
    for (int t = threadIdx.x; t < 1556; t += 256)
        r[t / 778][t % 778] = cmap[(size_t)b * 1556 + t];
    __syncthreads();
    if (threadIdx.x < 2) {
        int ic = threadIdx.x;
        float s = 0.f;
        for (int i2 = 0; i2 < 778; ++i2) s += r[ic][i2];
        T[ic][0] = s - r[ic][776] - r[ic][777];
        T[ic][1] = s - r[ic][0]   - r[ic][777];
        T[ic][2] = s - r[ic][0]   - r[ic][1];
    }
    __syncthreads();
    int oc = threadIdx.x;
    float a = 0.f;
#pragma unroll
    for (int ic = 0; ic < 2; ++ic)
#pragma unroll
        for (int k = 0; k < 3; ++k)
            a += w[oc * 6 + ic * 3 + k] * T[ic][k];
    ccmean[b * 256 + oc] = a / 776.f + bias[oc];
}

__global__ __launch_bounds__(256)
void feat_kernel(const float* __restrict__ ccmean, const float* __restrict__ q_lw,
                 const float* __restrict__ q_lb, float* __restrict__ feat)
{
    __shared__ float cc[8][256];
    for (int t = threadIdx.x; t < 2048; t += 256) cc[t >> 8][t & 255] = ccmean[t];
    __syncthreads();
    int j = blockIdx.x * 256 + threadIdx.x;
    const float* wr = q_lw + (size_t)j * 256;
    float acc[8];
#pragma unroll
    for (int b = 0; b < 8; ++b) acc[b] = 0.f;
    for (int c = 0; c < 256; ++c) {
        float wv = wr[c];
#pragma unroll
        for (int b = 0; b < 8; ++b) acc[b] += wv * cc[b][c];
    }
    float qb = q_lb[j];
#pragma unroll
    for (int b = 0; b < 8; ++b) feat[(size_t)b * 25600 + j] = acc[b] + qb;
}

__global__ __launch_bounds__(256)
void gather_kernel(const float* __restrict__ x, const float* __restrict__ pos,
                   const float* __restrict__ feat, const int* __restrict__ idx,
                   float* __restrict__ out0, float* __restrict__ out1)
{
    int t = blockIdx.x * 256 + threadIdx.x;
    if (t >= B_ * C_ * NQ_) return;
    int q = t % NQ_;
    int c2 = (t / NQ_) % C_;
    int b = t / (C_ * NQ_);
    int p = idx[b * NQ_ + q];
    out0[t] = x[((size_t)b * C_ + c2) * HW_ + p] + feat[(size_t)b * 25600 + c2 * NQ_ + q];
    out1[t] = pos[(size_t)c2 * HW_ + p];
}

// ---------------------------------------------------------------------------
extern "C" void kernel_launch(void* const* d_in, const int* in_sizes, int n_in,
                              void* d_out, int out_size, void* d_ws, size_t ws_size,
                              hipStream_t stream) {
    const float* x    = (const float*)d_in[0];
    const float* y    = (const float*)d_in[1];
    const float* pos  = (const float*)d_in[2];
    const float* lw1  = (const float*)d_in[3];  const float* lb1 = (const float*)d_in[4];
    const float* lw2  = (const float*)d_in[5];  const float* lb2 = (const float*)d_in[6];
    const float* rw1  = (const float*)d_in[7];  const float* rb1 = (const float*)d_in[8];
    const float* rw2  = (const float*)d_in[9];  const float* rb2 = (const float*)d_in[10];
    const float* ow1  = (const float*)d_in[11]; const float* ob1 = (const float*)d_in[12];
    const float* ow2  = (const float*)d_in[13]; const float* ob2 = (const float*)d_in[14];
    const float* cw1  = (const float*)d_in[15]; const float* cb1 = (const float*)d_in[16];
    const float* cw2  = (const float*)d_in[17]; const float* cb2 = (const float*)d_in[18];
    const float* cmlw = (const float*)d_in[19]; const float* cmlb = (const float*)d_in[20];
    const float* c1dw = (const float*)d_in[21]; const float* c1db = (const float*)d_in[22];
    const float* qlw  = (const float*)d_in[23]; const float* qlb  = (const float*)d_in[24];

    float* out  = (float*)d_out;
    float* out0 = out;                 // topk_proposals [8,256,100]
    float* out1 = out + 204800;        // topk_pos       [8,256,100]
    float* out2 = out + 409600;        // left_logits    [8,2,96,96]
    float* out3 = out + 557056;        // right_logits   [8,2,96,96]
    float* out4 = out + 704512;        // obj_logits     [8,11,96,96]
    float* out5 = out + 1515520;       // contact_map    [8,2,778,1]

    float* ws = (float*)d_ws;
    ushort_t* Rh   = (ushort_t*)(ws);                       // 76880*256 ush
    ushort_t* Rl   = (ushort_t*)(ws + 9840640);
    ushort_t* h1h  = (ushort_t*)(ws + 19681280);            // 76880*64 ush
    ushort_t* h1l  = (ushort_t*)(ws + 22141440);
    float*    h2   = ws + 24601600;                         // 8*32*9216 fp32
    ushort_t* wLh  = (ushort_t*)(ws + 26960896);            // 9*256*256 ush each
    ushort_t* wLl  = (ushort_t*)(ws + 27255808);
    ushort_t* wRh  = (ushort_t*)(ws + 27550720);
    ushort_t* wRl  = (ushort_t*)(ws + 27845632);
    ushort_t* wOh  = (ushort_t*)(ws + 28140544);
    ushort_t* wOl  = (ushort_t*)(ws + 28435456);
    ushort_t* wc1h = (ushort_t*)(ws + 28730368);            // 9*64*256
    ushort_t* wc1l = (ushort_t*)(ws + 28804096);
    ushort_t* wc2h = (ushort_t*)(ws + 28877824);            // 9*32*64
    ushort_t* wc2l = (ushort_t*)(ws + 28887040);
    float* pooled  = ws + 28896256;                         // 8*32*778
    float* ccmean  = ws + 29095424;                         // 2048
    float* feat    = ws + 29097472;                         // 204800
    float* pmapL   = ws + 29302272;                         // 73728
    int*   csmap   = (int*)(ws + 29376000);                 // 73728
    float* scL     = ws + 29449728;
    float* scR     = ws + 29523456;
    float* scO     = ws + 29597184;
    int*   idxb    = (int*)(ws + 29670912);                 // 800
    float* bias1all= ws + 29671712;                         // 768
    float* w2all   = ws + 29672480;                         // 8448
    float* b2all   = ws + 29680928;                         // 48
    float* pmapR   = ws + 29680976;                         // 73728
    float* pmapO   = ws + 29754704;                         // 73728
    (void)in_sizes; (void)n_in; (void)out_size; (void)ws_size; (void)pos;

    // ---- one-time zeroing of padded borders + weight/param packing ----
    zero_border_kernel<<<388, 256, 0, stream>>>(Rh, Rl, 256);
    zero_border_kernel<<<97,  256, 0, stream>>>(h1h, h1l, 64);
    repack_kernel<<<(9*256*256+255)/256, 256, 0, stream>>>(lw1, wLh, wLl, 256, 256);
    repack_kernel<<<(9*256*256+255)/256, 256, 0, stream>>>(rw1, wRh, wRl, 256, 256);
    repack_kernel<<<(9*256*256+255)/256, 256, 0, stream>>>(ow1, wOh, wOl, 256, 256);
    repack_kernel<<<(9*64*256+255)/256,  256, 0, stream>>>(cw1, wc1h, wc1l, 64, 256);
    repack_kernel<<<(9*32*64+255)/256,   256, 0, stream>>>(cw2, wc2h, wc2l, 32, 64);
    pack_heads3_kernel<<<33, 256, 0, stream>>>(lb1, rb1, ob1, lw2, rw2, ow2,
                                               lb2, rb2, ob2, bias1all, w2all, b2all);

    // ---- contact branch (R holds padded yt; freed after conv1) ----
    tsplit_kernel<<<dim3(288, 8, 8), 256, 0, stream>>>(y, Rh, Rl, 256);
    conv_gemm_kernel<3,2,3,1,256,1><<<256, 384, 0, stream>>>(
        Rh, Rl, wc1h, wc1l, cb1, h1h, h1l, nullptr);
    conv_gemm_kernel<3,1,3,1,64,2><<<256, 192, 0, stream>>>(
        h1h, h1l, wc2h, wc2l, cb2, nullptr, nullptr, h2);
    pool_kernel<<<256, 128, 0, stream>>>(h2, pooled);
    cm_kernel<<<1556, 256, 0, stream>>>(pooled, cmlw, cmlb, out5);
    c1d_kernel<<<8, 256, 0, stream>>>(out5, c1dw, c1db, ccmean);
    feat_kernel<<<100, 256, 0, stream>>>(ccmean, qlw, qlb, feat);

    // ---- unified heads: one launch, 4608 small blocks, atomic combine ----
    tsplit_kernel<<<dim3(288, 8, 8), 256, 0, stream>>>(x, Rh, Rl, 256);
    zero_logits_kernel<<<1080, 256, 0, stream>>>(out2);
    conv_sb3_kernel<<<4608, 256, 0, stream>>>(
        Rh, Rl, wLh, wLl, wRh, wRl, wOh, wOl, bias1all, w2all, b2all, out2);

    // ---- probs / NMS scores (L/R batched) ----
    prob2b_kernel<<<dim3(288, 2), 256, 0, stream>>>(out2, out3, pmapL, pmapR);
    score2b_kernel<<<dim3(288, 2), 256, 0, stream>>>(pmapL, pmapR, scL, scR);
    probobj_kernel<<<288, 256, 0, stream>>>(out4, pmapO, csmap);
    score11_kernel<<<288, 256, 0, stream>>>(pmapO, csmap, scO);

    // ---- topk + gathers ----
    topk_kernel<<<dim3(3, 8), 256, 0, stream>>>(scL, scR, scO, idxb);
    gather_kernel<<<800, 256, 0, stream>>>(x, pos, feat, idxb, out0, out1);
}

// Round 12
// 1323.374 us; speedup vs baseline: 1.1108x; 1.1108x over previous
//
#include <hip/hip_runtime.h>
#include <float.h>
#include <math.h>

#define B_ 8
#define C_ 256
#define H_ 96
#define W_ 96
#define HW_ 9216
#define NQ_ 100
#define EPS_ 1e-6f
#define PADW_ 98
#define PADIMG_ 9604          // 98*98 padded image
#define PALLOC_ 76880         // 8*9604 + slack rows for A-stage overrun

typedef unsigned short ushort_t;
typedef __attribute__((ext_vector_type(8))) short bf16x8;
typedef __attribute__((ext_vector_type(16))) float f32x16;

typedef __attribute__((address_space(3))) unsigned int as3_u32;
typedef __attribute__((address_space(1))) unsigned int as1_u32;

__device__ __forceinline__ void gl16(const void* g, void* l) {
    __builtin_amdgcn_global_load_lds(
        (const as1_u32*)(unsigned long long)g,
        (as3_u32*)(unsigned int)(unsigned long long)l, 16, 0, 0);
}

__device__ __forceinline__ ushort_t bf16_of(float v) {
    unsigned u = __float_as_uint(v);
    u += 0x7fffu + ((u >> 16) & 1u);
    return (ushort_t)(u >> 16);
}
__device__ __forceinline__ float f_of_bf16(ushort_t h) {
    return __uint_as_float((unsigned)h << 16);
}

// ---------------------------------------------------------------------------
// Zero the 1-px border of each padded image (388 px/img), both splits.
// ---------------------------------------------------------------------------
__global__ __launch_bounds__(256)
void zero_border_kernel(ushort_t* __restrict__ bh, ushort_t* __restrict__ bl, int Cch)
{
    int per = 388 * Cch / 8;
    int id = blockIdx.x * 256 + threadIdx.x;
    if (id >= 8 * per) return;
    int b = id / per, i = id - b * per;
    int pi = (i * 8) / Cch, c8 = (i * 8) % Cch;
    int yy, xx;
    if (pi < 98)      { yy = 0;            xx = pi; }
    else if (pi < 196){ yy = 97;           xx = pi - 98; }
    else if (pi < 292){ yy = pi - 195;     xx = 0; }
    else              { yy = pi - 291;     xx = 97; }
    size_t base = ((size_t)b * PADIMG_ + yy * PADW_ + xx) * Cch + c8;
    *(bf16x8*)&bh[base] = (bf16x8)(short)0;
    *(bf16x8*)&bl[base] = (bf16x8)(short)0;
}

// ---------------------------------------------------------------------------
// Transpose+split into padded layout: in [b][C][96*96] fp32 ->
// oh/ol [b*PADIMG + (y+1)*98 + x+1][C] bf16 hi/lo (interior only)
// ---------------------------------------------------------------------------
__global__ __launch_bounds__(256)
void tsplit_kernel(const float* __restrict__ in, ushort_t* __restrict__ oh,
                   ushort_t* __restrict__ ol, int Cch)
{
    __shared__ float T[32][33];
    const int tx = threadIdx.x & 31, ty = threadIdx.x >> 5;
    const int p0 = blockIdx.x * 32, ci0 = blockIdx.y * 32, b = blockIdx.z;
#pragma unroll
    for (int i = 0; i < 4; ++i)
        T[ty + 8*i][tx] = in[((size_t)b*Cch + ci0 + ty + 8*i)*HW_ + p0 + tx];
    __syncthreads();
    const int y = p0 / 96, x0 = p0 - y * 96;
    const size_t Pp = (size_t)b*PADIMG_ + (size_t)(y + 1)*PADW_ + x0 + 1;
#pragma unroll
    for (int i = 0; i < 4; ++i) {
        float v = T[tx][ty + 8*i];
        ushort_t hi = bf16_of(v);
        float lo = v - f_of_bf16(hi);
        size_t o = (Pp + ty + 8*i)*Cch + ci0 + tx;
        oh[o] = hi;
        ol[o] = bf16_of(lo);
    }
}

// ---------------------------------------------------------------------------
// Weight repack: w [oc][ci][3][3] fp32 -> wh/wl [tap][g][oc][ci16] bf16 hi/lo
// ---------------------------------------------------------------------------
__global__ __launch_bounds__(256)
void repack_kernel(const float* __restrict__ w, ushort_t* __restrict__ wh,
                   ushort_t* __restrict__ wl, int Cout, int Cin)
{
    int id = blockIdx.x*256 + threadIdx.x;
    int tot = 9*Cout*Cin;
    if (id >= tot) return;
    int tap = id / (Cout*Cin);
    int r   = id - tap*(Cout*Cin);
    int g   = r / (Cout*16);
    int r2  = r - g*(Cout*16);
    int oc  = r2 >> 4, cr = r2 & 15;
    int ci  = g*16 + cr;
    float v = w[((size_t)oc*Cin + ci)*9 + tap];
    ushort_t hi = bf16_of(v);
    wh[id] = hi;
    wl[id] = bf16_of(v - f_of_bf16(hi));
}

// ---------------------------------------------------------------------------
// Pack per-head params: bias1all[3][256]; w2all[3][11][256] (zero-padded for
// L/R); b2all[3][11] (zero-padded).
// ---------------------------------------------------------------------------
__global__ __launch_bounds__(256)
void pack_heads3_kernel(const float* lb1, const float* rb1, const float* ob1,
                        const float* lw2, const float* rw2, const float* ow2,
                        const float* lb2, const float* rb2, const float* ob2,
                        float* __restrict__ bias1all, float* __restrict__ w2all,
                        float* __restrict__ b2all)
{
    int i = blockIdx.x * 256 + threadIdx.x;
    if (i < 768) bias1all[i] = (i < 256) ? lb1[i] : (i < 512) ? rb1[i-256] : ob1[i-512];
    if (i < 33) {
        int h = i / 11, k = i - h*11;
        b2all[i] = (h == 0) ? (k < 2 ? lb2[k] : 0.f)
                 : (h == 1) ? (k < 2 ? rb2[k] : 0.f)
                 : ob2[k];
    }
    if (i < 3*11*256) {
        int h = i / 2816, r = i - h*2816;
        int k = r / 256, oc = r - k*256;
        float v = 0.f;
        if (h == 0)      { if (k < 2) v = lw2[k*256 + oc]; }
        else if (h == 1) { if (k < 2) v = rw2[k*256 + oc]; }
        else             v = ow2[k*256 + oc];
        w2all[i] = v;
    }
}

// ---------------------------------------------------------------------------
// Implicit-GEMM conv3x3 (round-6 structure, contact branch only).
// HARDENED: lgkmcnt(0) before the group-end barrier so all ds_read data is
// in registers before any wave can overwrite the (g-1)-parity LDS buffer.
//   MODE 1: bias+relu -> Oth/Otl padded-transposed [P'][COUT] bf16 hi/lo
//   MODE 2: bias+relu -> outf [b][COUT][HW] fp32 (LDS transpose)
// ---------------------------------------------------------------------------
template<int WM, int WN, int MFR, int NFR, int CIN, int MODE>
__global__ __launch_bounds__(WM*WN*64, (WM*WN + 3) / 4)
void conv_gemm_kernel(const ushort_t* __restrict__ Agh, const ushort_t* __restrict__ Agl,
                      const ushort_t* __restrict__ Wgh, const ushort_t* __restrict__ Wgl,
                      const float* __restrict__ bias1,
                      ushort_t* __restrict__ Oth, ushort_t* __restrict__ Otl,
                      float* __restrict__ outf)
{
    constexpr int NW    = WM*WN;
    constexpr int NT    = NW*64;
    constexpr int BM    = WM*MFR*32;      // 288
    constexpr int COUT  = WN*NFR*32;
    constexpr int NG    = CIN/16;
    constexpr int APAD  = 512;
    constexpr int ASZ   = 2*APAD*16;
    constexpr int AROUNDS = 32;
    static_assert(BM == 288, "BM must be 288");

    __shared__ __align__(16) ushort_t ALds[2*ASZ];

    const int tid  = threadIdx.x;
    const int lane = tid & 63;
    const int wid  = __builtin_amdgcn_readfirstlane(tid >> 6);
    const int wm   = wid / WN, wn = wid % WN;
    const int l31  = lane & 31, hh2 = lane >> 5;
    const int wnb  = wn * NFR * 32;

    const int cpx = gridDim.x >> 3;
    const int bid = (blockIdx.x & 7)*cpx + (blockIdx.x >> 3);
    const int bidx = bid >> 5;
    const int br   = bid & 31;
    const size_t S = (size_t)bidx*PADIMG_ + (size_t)(3*br)*PADW_;

    auto stageA = [&](int g, int sel) {
        ushort_t* dst = ALds + sel*ASZ;
#pragma unroll 1
        for (int c = wid; c < AROUNDS; c += NW) {
            int id = c*64 + lane;
            int split = id >> 10;
            int r2 = id & 1023;
            int row = r2 >> 1, slot = r2 & 1;
            int ch = slot ^ ((row >> 2) & 1);
            const ushort_t* src = (split ? Agl : Agh) + (S + row)*CIN + g*16 + ch*8;
            gl16(src, dst + (size_t)c*512);
        }
    };

    f32x16 acc[MFR][NFR];
#pragma unroll
    for (int i = 0; i < MFR; ++i)
#pragma unroll
        for (int j = 0; j < NFR; ++j)
#pragma unroll
            for (int r = 0; r < 16; ++r) acc[i][j][r] = 0.f;

    bf16x8 bh0[NFR], bl0[NFR], bh1[NFR], bl1[NFR], bh2[NFR], bl2[NFR];

#define LOADB(G, T, BH, BL)                                                    \
    {                                                                          \
        _Pragma("unroll")                                                      \
        for (int nf = 0; nf < NFR; ++nf) {                                     \
            size_t o = ((size_t)((T)*NG + (G))*COUT + (wnb + nf*32 + l31))*16  \
                       + hh2*8;                                                \
            BH[nf] = *(const bf16x8*)&Wgh[o];                                  \
            BL[nf] = *(const bf16x8*)&Wgl[o];                                  \
        }                                                                      \
    }

    stageA(0, 0);
    LOADB(0, 0, bh0, bl0);
    LOADB(0, 1, bh1, bl1);
    __builtin_amdgcn_sched_barrier(0);
    asm volatile("s_waitcnt vmcnt(%0)" :: "n"(4*NFR) : "memory");
    __builtin_amdgcn_s_barrier();
    __builtin_amdgcn_sched_barrier(0);

#define TAPBODY(T, BHC, BLC, BHN, BLN)                                         \
    {                                                                          \
        if ((T) <= 6)            LOADB(g,     (T)+2, BHN, BLN)                 \
        else if (g + 1 < NG)     LOADB(g+1,   (T)-7, BHN, BLN)                 \
        const int tapoff = ((T)/3)*PADW_ + ((T) % 3);                          \
        _Pragma("unroll")                                                      \
        for (int mf = 0; mf < MFR; ++mf) {                                     \
            int row = wm*PADW_ + tapoff + mf*32 + l31;                         \
            int o = abase + row*16 + ((hh2 ^ ((row >> 2) & 1)) << 3);          \
            bf16x8 ah = *(const bf16x8*)&ALds[o];                              \
            bf16x8 al = *(const bf16x8*)&ALds[o + APAD*16];                    \
            _Pragma("unroll")                                                  \
            for (int nf = 0; nf < NFR; ++nf) {                                 \
                acc[mf][nf] = __builtin_amdgcn_mfma_f32_32x32x16_bf16(         \
                    ah, BHC[nf], acc[mf][nf], 0, 0, 0);                        \
                acc[mf][nf] = __builtin_amdgcn_mfma_f32_32x32x16_bf16(         \
                    al, BHC[nf], acc[mf][nf], 0, 0, 0);                        \
                acc[mf][nf] = __builtin_amdgcn_mfma_f32_32x32x16_bf16(         \
                    ah, BLC[nf], acc[mf][nf], 0, 0, 0);                        \
            }                                                                  \
        }                                                                      \
    }

#pragma unroll 1
    for (int g = 0; g < NG; ++g) {
        if (g + 1 < NG) stageA(g + 1, (g + 1) & 1);
        const int abase = (g & 1) * ASZ;
        TAPBODY(0, bh0, bl0, bh2, bl2);
        TAPBODY(1, bh1, bl1, bh0, bl0);
        TAPBODY(2, bh2, bl2, bh1, bl1);
        TAPBODY(3, bh0, bl0, bh2, bl2);
        TAPBODY(4, bh1, bl1, bh0, bl0);
        TAPBODY(5, bh2, bl2, bh1, bl1);
        TAPBODY(6, bh0, bl0, bh2, bl2);
        TAPBODY(7, bh1, bl1, bh0, bl0);
        TAPBODY(8, bh2, bl2, bh1, bl1);
        __builtin_amdgcn_sched_barrier(0);
        asm volatile("s_waitcnt lgkmcnt(0)" ::: "memory");   // ds_read data home
        asm volatile("s_waitcnt vmcnt(%0)" :: "n"(4*NFR) : "memory");
        __builtin_amdgcn_s_barrier();
        __builtin_amdgcn_sched_barrier(0);
    }
#undef TAPBODY
#undef LOADB
    __syncthreads();

    float biasv[NFR];
#pragma unroll
    for (int nf = 0; nf < NFR; ++nf) biasv[nf] = bias1[wnb + nf*32 + l31];

    if constexpr (MODE == 1) {
#pragma unroll
        for (int mf = 0; mf < MFR; ++mf)
#pragma unroll
            for (int nf = 0; nf < NFR; ++nf)
#pragma unroll
                for (int r = 0; r < 16; ++r) {
                    float rr = fmaxf(acc[mf][nf][r] + biasv[nf], 0.f);
                    ushort_t hi = bf16_of(rr);
                    float lo = rr - f_of_bf16(hi);
                    int crow = (r & 3) + 8*(r >> 2) + 4*hh2;
                    int xx = mf*32 + crow;
                    size_t Pp = (size_t)bidx*PADIMG_
                              + (size_t)(3*br + wm + 1)*PADW_ + xx + 1;
                    size_t o = Pp*COUT + wnb + nf*32 + l31;
                    Oth[o] = hi;
                    Otl[o] = bf16_of(lo);
                }
    } else {
        float (*T)[BM + 1] = (float(*)[BM + 1])ALds;
#pragma unroll
        for (int mf = 0; mf < MFR; ++mf)
#pragma unroll
            for (int r = 0; r < 16; ++r) {
                float rr = fmaxf(acc[mf][0][r] + biasv[0], 0.f);
                int crow = (r & 3) + 8*(r >> 2) + 4*hh2;
                T[l31][wm*96 + mf*32 + crow] = rr;
            }
        __syncthreads();
        for (int i = tid; i < COUT*BM; i += NT) {
            int c = i / BM, m = i - c*BM;
            outf[((size_t)bidx*COUT + c)*HW_ + br*288 + m] = T[c][m];
        }
    }
}

// ---------------------------------------------------------------------------
// Round-12 unified head kernel (r11 structure + race hardening): 4 waves,
// NFR=2, 19.5KB single A-buffer (3 blocks/CU), depth-2 B prefetch (3 sets),
// 3 heads in one launch (grid 2304). STAGEWAIT now drains lgkmcnt(0) BEFORE
// the overwrite barrier: all ds_read data is in registers before any wave's
// gl16 can overwrite the single buffer (the r11 replay-divergence race).
// ---------------------------------------------------------------------------
__global__ __launch_bounds__(256, 3)
void conv_sbu_kernel(const ushort_t* __restrict__ Agh, const ushort_t* __restrict__ Agl,
                     const ushort_t* __restrict__ wLh, const ushort_t* __restrict__ wLl,
                     const ushort_t* __restrict__ wRh, const ushort_t* __restrict__ wRl,
                     const ushort_t* __restrict__ wOh, const ushort_t* __restrict__ wOl,
                     const float* __restrict__ bias1all, const float* __restrict__ w2all,
                     const float* __restrict__ b2all, float* __restrict__ out_logits)
{
    constexpr int NG = 16, APAD = 304, ASZ = 2*APAD*16, AGR = 19, MFR = 3, NFR = 2;
    __shared__ __align__(16) ushort_t ALds[ASZ];

    const int tid  = threadIdx.x;
    const int lane = tid & 63;
    const int wid  = __builtin_amdgcn_readfirstlane(tid >> 6);
    const int l31  = lane & 31, hh2 = lane >> 5;
    const int wnb  = wid * 64;                 // wave's 64-channel column base

    const int cpx = gridDim.x >> 3;            // 288
    const int bid = (blockIdx.x & 7)*cpx + (blockIdx.x >> 3);
    const int h    = bid / 768;
    const int sub  = bid - h*768;
    const int bidx = sub / 96, prow = sub - bidx*96;
    const int pimg0 = prow * 96;
    const size_t S = (size_t)bidx*PADIMG_ + (size_t)prow*PADW_;

    const ushort_t* Wh = (h == 0) ? wLh : (h == 1) ? wRh : wOh;
    const ushort_t* Wl = (h == 0) ? wLl : (h == 1) ? wRl : wOl;
    const float* bias1 = bias1all + h*256;
    const float* w2    = w2all + (size_t)h*2816;      // [11][256]
    const float* b2    = b2all + h*11;
    const int kklim = (h == 2) ? 11 : 2;
    float* dst = out_logits + ((h == 0) ? 0 : (h == 1) ? 147456 : 294912);

    auto stageA = [&](int g) {
#pragma unroll 1
        for (int c = wid; c < AGR; c += 4) {
            int id = c*64 + lane;
            int split = id / (2*APAD);
            int r2 = id % (2*APAD);
            int row = r2 >> 1, slot = r2 & 1;
            int ch = slot ^ ((row >> 2) & 1);     // inverse of read swizzle
            const ushort_t* src = (split ? Agl : Agh) + (S + row)*C_ + g*16 + ch*8;
            gl16(src, ALds + (size_t)c*512);
        }
    };

    f32x16 acc[MFR][NFR];
#pragma unroll
    for (int i = 0; i < MFR; ++i)
#pragma unroll
        for (int j = 0; j < NFR; ++j)
#pragma unroll
            for (int r = 0; r < 16; ++r) acc[i][j][r] = 0.f;

    // 3 named B register sets (tap%3 rotation, depth-2 prefetch)
    bf16x8 bh0[NFR], bl0[NFR], bh1[NFR], bl1[NFR], bh2[NFR], bl2[NFR];

#define LOADB(G, T, BH, BL)                                                    \
    {                                                                          \
        _Pragma("unroll")                                                      \
        for (int nf = 0; nf < NFR; ++nf) {                                     \
            size_t o = ((size_t)((T)*NG + (G))*256 + (wnb + nf*32 + l31))*16   \
                       + hh2*8;                                                \
            BH[nf] = *(const bf16x8*)&Wh[o];                                   \
            BL[nf] = *(const bf16x8*)&Wl[o];                                   \
        }                                                                      \
    }

#define TAPBODY(G, T, BHC, BLC, BHN, BLN)                                      \
    {                                                                          \
        if ((T) <= 6)            LOADB((G), (T)+2, BHN, BLN)                   \
        else if ((G) + 1 < NG)   LOADB((G)+1, (T)-7, BHN, BLN)                 \
        const int tapoff = ((T)/3)*PADW_ + ((T) % 3);                          \
        _Pragma("unroll")                                                      \
        for (int mf = 0; mf < MFR; ++mf) {                                     \
            int row = tapoff + mf*32 + l31;                                    \
            int o = row*16 + ((hh2 ^ ((row >> 2) & 1)) << 3);                  \
            bf16x8 ah = *(const bf16x8*)&ALds[o];                              \
            bf16x8 al = *(const bf16x8*)&ALds[o + APAD*16];                    \
            _Pragma("unroll")                                                  \
            for (int nf = 0; nf < NFR; ++nf) {                                 \
                acc[mf][nf] = __builtin_amdgcn_mfma_f32_32x32x16_bf16(         \
                    ah, BHC[nf], acc[mf][nf], 0, 0, 0);                        \
                acc[mf][nf] = __builtin_amdgcn_mfma_f32_32x32x16_bf16(         \
                    al, BHC[nf], acc[mf][nf], 0, 0, 0);                        \
                acc[mf][nf] = __builtin_amdgcn_mfma_f32_32x32x16_bf16(         \
                    ah, BLC[nf], acc[mf][nf], 0, 0, 0);                        \
            }                                                                  \
        }                                                                      \
    }

// HARDENED: lgkmcnt(0)+sched_barrier BEFORE the overwrite barrier.
#define STAGEWAIT(G)                                                           \
    __builtin_amdgcn_sched_barrier(0);                                         \
    asm volatile("s_waitcnt lgkmcnt(0)" ::: "memory");                         \
    __builtin_amdgcn_sched_barrier(0);                                         \
    __builtin_amdgcn_s_barrier();        /* prior group's reads in regs */     \
    stageA(G);                                                                 \
    __builtin_amdgcn_sched_barrier(0);                                         \
    asm volatile("s_waitcnt vmcnt(0)" ::: "memory");                           \
    __builtin_amdgcn_s_barrier();                                              \
    __builtin_amdgcn_sched_barrier(0);

    LOADB(0, 0, bh0, bl0);
    LOADB(0, 1, bh1, bl1);

#pragma unroll 1
    for (int g = 0; g < NG; ++g) {
        STAGEWAIT(g)
        TAPBODY(g, 0, bh0, bl0, bh2, bl2);
        TAPBODY(g, 1, bh1, bl1, bh0, bl0);
        TAPBODY(g, 2, bh2, bl2, bh1, bl1);
        TAPBODY(g, 3, bh0, bl0, bh2, bl2);
        TAPBODY(g, 4, bh1, bl1, bh0, bl0);
        TAPBODY(g, 5, bh2, bl2, bh1, bl1);
        TAPBODY(g, 6, bh0, bl0, bh2, bl2);
        TAPBODY(g, 7, bh1, bl1, bh0, bl0);   // prefetch (g+1, 0)
        TAPBODY(g, 8, bh2, bl2, bh1, bl1);   // prefetch (g+1, 1)
    }
#undef STAGEWAIT
#undef TAPBODY
#undef LOADB
    __syncthreads();

    // ---- fused 1x1 epilogue: full COT in this block -> direct write ----
    float biasv[NFR];
#pragma unroll
    for (int nf = 0; nf < NFR; ++nf) biasv[nf] = bias1[wnb + nf*32 + l31];
    float w2v[NFR][11];
#pragma unroll
    for (int nf = 0; nf < NFR; ++nf)
#pragma unroll
        for (int k = 0; k < 11; ++k) w2v[nf][k] = w2[k*256 + wnb + nf*32 + l31];

    float* Lacc = (float*)ALds;               // [4][96][11] = 16.9KB
#pragma unroll
    for (int mf = 0; mf < MFR; ++mf) {
#pragma unroll
        for (int r = 0; r < 16; ++r) {
            float v[11];
#pragma unroll
            for (int k = 0; k < 11; ++k) v[k] = 0.f;
#pragma unroll
            for (int nf = 0; nf < NFR; ++nf) {
                float rr = fmaxf(acc[mf][nf][r] + biasv[nf], 0.f);
#pragma unroll
                for (int k = 0; k < 11; ++k)
                    if (k < kklim) v[k] += rr * w2v[nf][k];
            }
#pragma unroll
            for (int k = 0; k < 11; ++k) {
                if (k < kklim) {
                    v[k] += __shfl_xor(v[k], 1);
                    v[k] += __shfl_xor(v[k], 2);
                    v[k] += __shfl_xor(v[k], 4);
                    v[k] += __shfl_xor(v[k], 8);
                    v[k] += __shfl_xor(v[k], 16);
                }
            }
            if (l31 == 0) {
                int crow = (r & 3) + 8*(r >> 2) + 4*hh2;
                int row96 = mf*32 + crow;
#pragma unroll
                for (int k = 0; k < 11; ++k)
                    if (k < kklim)
                        Lacc[((size_t)wid*96 + row96)*11 + k] = v[k];
            }
        }
    }
    __syncthreads();
    for (int i = tid; i < 96*kklim; i += 256) {
        int row96 = i / kklim, k = i - row96*kklim;
        float s = b2[k];
#pragma unroll
        for (int w = 0; w < 4; ++w) s += Lacc[((size_t)w*96 + row96)*11 + k];
        dst[((size_t)bidx*kklim + k)*HW_ + pimg0 + row96] = s;
    }
}

// ---------------------------------------------------------------------------
// Softmax / mask / NMS-score kernels. L/R heads batched over blockIdx.y.
// ---------------------------------------------------------------------------
__global__ __launch_bounds__(256)
void prob2b_kernel(const float* __restrict__ l2, const float* __restrict__ l3,
                   float* __restrict__ pL, float* __restrict__ pR)
{
    const float* logits = blockIdx.y ? l3 : l2;
    float* p0 = blockIdx.y ? pR : pL;
    int i = blockIdx.x * 256 + threadIdx.x;
    if (i >= B_ * HW_) return;
    int b = i / HW_, pix = i - b * HW_;
    float l0 = logits[(size_t)b * 2 * HW_ + pix];
    float l1 = logits[(size_t)b * 2 * HW_ + HW_ + pix];
    float m = fmaxf(l0, l1);
    float e0 = expf(l0 - m), e1 = expf(l1 - m);
    p0[i] = e0 / (e0 + e1);
}

__global__ __launch_bounds__(256)
void score2b_kernel(const float* __restrict__ pL, const float* __restrict__ pR,
                    float* __restrict__ sL, float* __restrict__ sR)
{
    const float* p = blockIdx.y ? pR : pL;
    float* sc = blockIdx.y ? sR : sL;
    int i = blockIdx.x * 256 + threadIdx.x;
    if (i >= B_ * HW_) return;
    int pix = i % HW_;
    int yy = pix / W_, xx = pix - (pix / W_) * W_;
    float c = p[i];
    bool ok = (c >= EPS_);
    const float* pb = p + (i - pix);
#pragma unroll
    for (int dy = -1; dy <= 1; ++dy)
#pragma unroll
        for (int dx = -1; dx <= 1; ++dx) {
            if (dy == 0 && dx == 0) continue;
            int ny = yy + dy, nx = xx + dx;
            float v = 0.f;
            if (ny >= 0 && ny < H_ && nx >= 0 && nx < W_) v = pb[ny * W_ + nx];
            ok = ok && (c >= v);
        }
    sc[i] = c + (ok ? 1.f : 0.f);
}

__global__ __launch_bounds__(256)
void probobj_kernel(const float* __restrict__ logits, float* __restrict__ pval,
                    int* __restrict__ cstar)
{
    int i = blockIdx.x * 256 + threadIdx.x;
    if (i >= B_ * HW_) return;
    int b = i / HW_, pix = i - b * HW_;
    const float* lb = logits + (size_t)b * 11 * HW_ + pix;
    float l[11];
#pragma unroll
    for (int c2 = 0; c2 < 11; ++c2) l[c2] = lb[(size_t)c2 * HW_];
    float m = l[0];
#pragma unroll
    for (int c2 = 1; c2 < 11; ++c2) m = fmaxf(m, l[c2]);
    float sum = 0.f;
#pragma unroll
    for (int c2 = 0; c2 < 11; ++c2) sum += expf(l[c2] - m);
    int a = 0; float bestl = l[0];
#pragma unroll
    for (int c2 = 1; c2 < 10; ++c2)
        if (l[c2] > bestl) { bestl = l[c2]; a = c2; }
    pval[i] = expf(bestl - m) / sum;
    cstar[i] = a;
}

__global__ __launch_bounds__(256)
void score11_kernel(const float* __restrict__ p, const int* __restrict__ cs,
                    float* __restrict__ sc)
{
    int i = blockIdx.x * 256 + threadIdx.x;
    if (i >= B_ * HW_) return;
    int pix = i % HW_;
    int yy = pix / W_, xx = pix - (pix / W_) * W_;
    float c = p[i];
    int cc = cs[i];
    bool ok = (c >= EPS_);
    int base = i - pix;
#pragma unroll
    for (int dy = -1; dy <= 1; ++dy)
#pragma unroll
        for (int dx = -1; dx <= 1; ++dx) {
            if (dy == 0 && dx == 0) continue;
            int ny = yy + dy, nx = xx + dx;
            float v = 0.f;
            if (ny >= 0 && ny < H_ && nx >= 0 && nx < W_) {
                int n = base + ny * W_ + nx;
                v = (cs[n] == cc) ? p[n] : 0.f;
            }
            ok = ok && (c >= v);
        }
    sc[i] = c + (ok ? 1.f : 0.f);
}

// ---------------------------------------------------------------------------
// top-k by iterative argmax (matches jax.lax.top_k ordering)
// ---------------------------------------------------------------------------
__global__ __launch_bounds__(256)
void topk_kernel(const float* __restrict__ scL, const float* __restrict__ scR,
                 const float* __restrict__ scO, int* __restrict__ idx)
{
    __shared__ float sv[HW_];
    __shared__ float rv[256];
    __shared__ int   ri[256];
    const int h = blockIdx.x, b = blockIdx.y;
    const float* src = (h == 0) ? scL : (h == 1) ? scR : scO;
    const int k = (h == 2) ? 20 : 40;
    const int off = b * NQ_ + ((h == 0) ? 0 : (h == 1) ? 40 : 80);

    for (int t = threadIdx.x; t < HW_; t += 256) sv[t] = src[(size_t)b * HW_ + t];
    __syncthreads();

    for (int kk = 0; kk < k; ++kk) {
        float bestv = -FLT_MAX; int besti = HW_;
        for (int t = threadIdx.x; t < HW_; t += 256) {
            float v = sv[t];
            if (v > bestv) { bestv = v; besti = t; }
        }
        rv[threadIdx.x] = bestv; ri[threadIdx.x] = besti;
        __syncthreads();
        for (int s = 128; s > 0; s >>= 1) {
            if (threadIdx.x < s) {
                float v2 = rv[threadIdx.x + s]; int i2 = ri[threadIdx.x + s];
                if (v2 > rv[threadIdx.x] ||
                    (v2 == rv[threadIdx.x] && i2 < ri[threadIdx.x])) {
                    rv[threadIdx.x] = v2; ri[threadIdx.x] = i2;
                }
            }
            __syncthreads();
        }
        if (threadIdx.x == 0) { idx[off + kk] = ri[0]; sv[ri[0]] = -FLT_MAX; }
        __syncthreads();
    }
}

// ---------------------------------------------------------------------------
// Contact branch tail (unchanged)
// ---------------------------------------------------------------------------
__global__ __launch_bounds__(128)
void pool_kernel(const float* __restrict__ h2, float* __restrict__ pooled)
{
    int bc = blockIdx.x;
    __shared__ float row[96];
    for (int hh = threadIdx.x; hh < 96; hh += 128) {
        const float* p = h2 + (size_t)bc * HW_ + hh * W_;
        float s = 0.f;
        for (int ww = 0; ww < 96; ++ww) s += p[ww];
        row[hh] = s * (1.f / 96.f);
    }
    __syncthreads();
    for (int i = threadIdx.x; i < 778; i += 128) {
        int s0 = (i * 96) / 778;
        int e0 = ((i + 1) * 96 + 777) / 778;
        float s = 0.f;
        for (int t = s0; t < e0; ++t) s += row[t];
        pooled[(size_t)bc * 778 + i] = s / (float)(e0 - s0);
    }
}

__global__ __launch_bounds__(256)
void cm_kernel(const float* __restrict__ pooled, const float* __restrict__ cm_lw,
               const float* __restrict__ cm_lb, float* __restrict__ out5)
{
    const int j = blockIdx.x;
    const float* wr = cm_lw + (size_t)j * 24896;
    float acc[8];
#pragma unroll
    for (int b = 0; b < 8; ++b) acc[b] = 0.f;
    for (int t = threadIdx.x; t < 24896; t += 256) {
        float w = wr[t];
#pragma unroll
        for (int b = 0; b < 8; ++b) acc[b] += w * pooled[(size_t)b * 24896 + t];
    }
    __shared__ float red[8][256];
#pragma unroll
    for (int b = 0; b < 8; ++b) red[b][threadIdx.x] = acc[b];
    __syncthreads();
    for (int s = 128; s > 0; s >>= 1) {
        if (threadIdx.x < s) {
#pragma unroll
            for (int b = 0; b < 8; ++b) red[b][threadIdx.x] += red[b][threadIdx.x + s];
        }
        __syncthreads();
    }
    if (threadIdx.x < 8)
        out5[(size_t)threadIdx.x * 1556 + j] = red[threadIdx.x][0] + cm_lb[j];
}

__global__ __launch_bounds__(256)
void c1d_kernel(const float* __restrict__ cmap, const float* __restrict__ w,
                const float* __restrict__ bias, float* __restrict__ ccmean)
{
    int b = blockIdx.x;
    __shared__ float r[2][778];
    __shared__ float T[2][3];
    for (int t = threadIdx.x; t < 1556; t += 256)
        r[t / 778][t % 778] = cmap[(size_t)b * 1556 + t];
    __syncthreads();
    if (threadIdx.x < 2) {
        int ic = threadIdx.x;
        float s = 0.f;
        for (int i2 = 0; i2 < 778; ++i2) s += r[ic][i2];
        T[ic][0] = s - r[ic][776] - r[ic][777];
        T[ic][1] = s - r[ic][0]   - r[ic][777];
        T[ic][2] = s - r[ic][0]   - r[ic][1];
    }
    __syncthreads();
    int oc = threadIdx.x;
    float a = 0.f;
#pragma unroll
    for (int ic = 0; ic < 2; ++ic)
#pragma unroll
        for (int k = 0; k < 3; ++k)
            a += w[oc * 6 + ic * 3 + k] * T[ic][k];
    ccmean[b * 256 + oc] = a / 776.f + bias[oc];
}

__global__ __launch_bounds__(256)
void feat_kernel(const float* __restrict__ ccmean, const float* __restrict__ q_lw,
                 const float* __restrict__ q_lb, float* __restrict__ feat)
{
    __shared__ float cc[8][256];
    for (int t = threadIdx.x; t < 2048; t += 256) cc[t >> 8][t & 255] = ccmean[t];
    __syncthreads();
    int j = blockIdx.x * 256 + threadIdx.x;
    const float* wr = q_lw + (size_t)j * 256;
    float acc[8];
#pragma unroll
    for (int b = 0; b < 8; ++b) acc[b] = 0.f;
    for (int c = 0; c < 256; ++c) {
        float wv = wr[c];
#pragma unroll
        for (int b = 0; b < 8; ++b) acc[b] += wv * cc[b][c];
    }
    float qb = q_lb[j];
#pragma unroll
    for (int b = 0; b < 8; ++b) feat[(size_t)b * 25600 + j] = acc[b] + qb;
}

__global__ __launch_bounds__(256)
void gather_kernel(const float* __restrict__ x, const float* __restrict__ pos,
                   const float* __restrict__ feat, const int* __restrict__ idx,
                   float* __restrict__ out0, float* __restrict__ out1)
{
    int t = blockIdx.x * 256 + threadIdx.x;
    if (t >= B_ * C_ * NQ_) return;
    int q = t % NQ_;
    int c2 = (t / NQ_) % C_;
    int b = t / (C_ * NQ_);
    int p = idx[b * NQ_ + q];
    out0[t] = x[((size_t)b * C_ + c2) * HW_ + p] + feat[(size_t)b * 25600 + c2 * NQ_ + q];
    out1[t] = pos[(size_t)c2 * HW_ + p];
}

// ---------------------------------------------------------------------------
extern "C" void kernel_launch(void* const* d_in, const int* in_sizes, int n_in,
                              void* d_out, int out_size, void* d_ws, size_t ws_size,
                              hipStream_t stream) {
    const float* x    = (const float*)d_in[0];
    const float* y    = (const float*)d_in[1];
    const float* pos  = (const float*)d_in[2];
    const float* lw1  = (const float*)d_in[3];  const float* lb1 = (const float*)d_in[4];
    const float* lw2  = (const float*)d_in[5];  const float* lb2 = (const float*)d_in[6];
    const float* rw1  = (const float*)d_in[7];  const float* rb1 = (const float*)d_in[8];
    const float* rw2  = (const float*)d_in[9];  const float* rb2 = (const float*)d_in[10];
    const float* ow1  = (const float*)d_in[11]; const float* ob1 = (const float*)d_in[12];
    const float* ow2  = (const float*)d_in[13]; const float* ob2 = (const float*)d_in[14];
    const float* cw1  = (const float*)d_in[15]; const float* cb1 = (const float*)d_in[16];
    const float* cw2  = (const float*)d_in[17]; const float* cb2 = (const float*)d_in[18];
    const float* cmlw = (const float*)d_in[19]; const float* cmlb = (const float*)d_in[20];
    const float* c1dw = (const float*)d_in[21]; const float* c1db = (const float*)d_in[22];
    const float* qlw  = (const float*)d_in[23]; const float* qlb  = (const float*)d_in[24];

    float* out  = (float*)d_out;
    float* out0 = out;                 // topk_proposals [8,256,100]
    float* out1 = out + 204800;        // topk_pos       [8,256,100]
    float* out2 = out + 409600;        // left_logits    [8,2,96,96]
    float* out3 = out + 557056;        // right_logits   [8,2,96,96]
    float* out4 = out + 704512;        // obj_logits     [8,11,96,96]
    float* out5 = out + 1515520;       // contact_map    [8,2,778,1]

    float* ws = (float*)d_ws;
    ushort_t* Rh   = (ushort_t*)(ws);                       // 76880*256 ush
    ushort_t* Rl   = (ushort_t*)(ws + 9840640);
    ushort_t* h1h  = (ushort_t*)(ws + 19681280);            // 76880*64 ush
    ushort_t* h1l  = (ushort_t*)(ws + 22141440);
    float*    h2   = ws + 24601600;                         // 8*32*9216 fp32
    ushort_t* wLh  = (ushort_t*)(ws + 26960896);            // 9*256*256 ush each
    ushort_t* wLl  = (ushort_t*)(ws + 27255808);
    ushort_t* wRh  = (ushort_t*)(ws + 27550720);
    ushort_t* wRl  = (ushort_t*)(ws + 27845632);
    ushort_t* wOh  = (ushort_t*)(ws + 28140544);
    ushort_t* wOl  = (ushort_t*)(ws + 28435456);
    ushort_t* wc1h = (ushort_t*)(ws + 28730368);            // 9*64*256
    ushort_t* wc1l = (ushort_t*)(ws + 28804096);
    ushort_t* wc2h = (ushort_t*)(ws + 28877824);            // 9*32*64
    ushort_t* wc2l = (ushort_t*)(ws + 28887040);
    float* pooled  = ws + 28896256;                         // 8*32*778
    float* ccmean  = ws + 29095424;                         // 2048
    float* feat    = ws + 29097472;                         // 204800
    float* pmapL   = ws + 29302272;                         // 73728
    int*   csmap   = (int*)(ws + 29376000);                 // 73728
    float* scL     = ws + 29449728;
    float* scR     = ws + 29523456;
    float* scO     = ws + 29597184;
    int*   idxb    = (int*)(ws + 29670912);                 // 800
    float* bias1all= ws + 29671712;                         // 768
    float* w2all   = ws + 29672480;                         // 8448
    float* b2all   = ws + 29680928;                         // 48
    float* pmapR   = ws + 29680976;                         // 73728
    float* pmapO   = ws + 29754704;                         // 73728
    (void)in_sizes; (void)n_in; (void)out_size; (void)ws_size; (void)pos;

    // ---- one-time zeroing of padded borders + weight/param packing ----
    zero_border_kernel<<<388, 256, 0, stream>>>(Rh, Rl, 256);
    zero_border_kernel<<<97,  256, 0, stream>>>(h1h, h1l, 64);
    repack_kernel<<<(9*256*256+255)/256, 256, 0, stream>>>(lw1, wLh, wLl, 256, 256);
    repack_kernel<<<(9*256*256+255)/256, 256, 0, stream>>>(rw1, wRh, wRl, 256, 256);
    repack_kernel<<<(9*256*256+255)/256, 256, 0, stream>>>(ow1, wOh, wOl, 256, 256);
    repack_kernel<<<(9*64*256+255)/256,  256, 0, stream>>>(cw1, wc1h, wc1l, 64, 256);
    repack_kernel<<<(9*32*64+255)/256,   256, 0, stream>>>(cw2, wc2h, wc2l, 32, 64);
    pack_heads3_kernel<<<33, 256, 0, stream>>>(lb1, rb1, ob1, lw2, rw2, ow2,
                                               lb2, rb2, ob2, bias1all, w2all, b2all);

    // ---- contact branch (R holds padded yt; freed after conv1) ----
    tsplit_kernel<<<dim3(288, 8, 8), 256, 0, stream>>>(y, Rh, Rl, 256);
    conv_gemm_kernel<3,2,3,1,256,1><<<256, 384, 0, stream>>>(
        Rh, Rl, wc1h, wc1l, cb1, h1h, h1l, nullptr);
    conv_gemm_kernel<3,1,3,1,64,2><<<256, 192, 0, stream>>>(
        h1h, h1l, wc2h, wc2l, cb2, nullptr, nullptr, h2);
    pool_kernel<<<256, 128, 0, stream>>>(h2, pooled);
    cm_kernel<<<1556, 256, 0, stream>>>(pooled, cmlw, cmlb, out5);
    c1d_kernel<<<8, 256, 0, stream>>>(out5, c1dw, c1db, ccmean);
    feat_kernel<<<100, 256, 0, stream>>>(ccmean, qlw, qlb, feat);

    // ---- unified heads: one launch, direct writes, depth-2 B prefetch ----
    tsplit_kernel<<<dim3(288, 8, 8), 256, 0, stream>>>(x, Rh, Rl, 256);
    conv_sbu_kernel<<<2304, 256, 0, stream>>>(
        Rh, Rl, wLh, wLl, wRh, wRl, wOh, wOl, bias1all, w2all, b2all, out2);

    // ---- probs / NMS scores (L/R batched) ----
    prob2b_kernel<<<dim3(288, 2), 256, 0, stream>>>(out2, out3, pmapL, pmapR);
    score2b_kernel<<<dim3(288, 2), 256, 0, stream>>>(pmapL, pmapR, scL, scR);
    probobj_kernel<<<288, 256, 0, stream>>>(out4, pmapO, csmap);
    score11_kernel<<<288, 256, 0, stream>>>(pmapO, csmap, scO);

    // ---- topk + gathers ----
    topk_kernel<<<dim3(3, 8), 256, 0, stream>>>(scL, scR, scO, idxb);
    gather_kernel<<<800, 256, 0, stream>>>(x, pos, feat, idxb, out0, out1);
}

// Round 13
// 1239.249 us; speedup vs baseline: 1.1862x; 1.0679x over previous
//
#include <hip/hip_runtime.h>
#include <float.h>
#include <math.h>

#define B_ 8
#define C_ 256
#define H_ 96
#define W_ 96
#define HW_ 9216
#define NQ_ 100
#define EPS_ 1e-6f
#define PADW_ 98
#define PADIMG_ 9604          // 98*98 padded image
#define PALLOC_ 76880         // 8*9604 + slack rows for A-stage overrun

typedef unsigned short ushort_t;
typedef __attribute__((ext_vector_type(8))) short bf16x8;
typedef __attribute__((ext_vector_type(16))) float f32x16;

typedef __attribute__((address_space(3))) unsigned int as3_u32;
typedef __attribute__((address_space(1))) unsigned int as1_u32;

__device__ __forceinline__ void gl16(const void* g, void* l) {
    __builtin_amdgcn_global_load_lds(
        (const as1_u32*)(unsigned long long)g,
        (as3_u32*)(unsigned int)(unsigned long long)l, 16, 0, 0);
}

__device__ __forceinline__ ushort_t bf16_of(float v) {
    unsigned u = __float_as_uint(v);
    u += 0x7fffu + ((u >> 16) & 1u);
    return (ushort_t)(u >> 16);
}
__device__ __forceinline__ float f_of_bf16(ushort_t h) {
    return __uint_as_float((unsigned)h << 16);
}

// ---------------------------------------------------------------------------
// Zero the 1-px border of each padded image (388 px/img), both splits.
// ---------------------------------------------------------------------------
__global__ __launch_bounds__(256)
void zero_border_kernel(ushort_t* __restrict__ bh, ushort_t* __restrict__ bl, int Cch)
{
    int per = 388 * Cch / 8;
    int id = blockIdx.x * 256 + threadIdx.x;
    if (id >= 8 * per) return;
    int b = id / per, i = id - b * per;
    int pi = (i * 8) / Cch, c8 = (i * 8) % Cch;
    int yy, xx;
    if (pi < 98)      { yy = 0;            xx = pi; }
    else if (pi < 196){ yy = 97;           xx = pi - 98; }
    else if (pi < 292){ yy = pi - 195;     xx = 0; }
    else              { yy = pi - 291;     xx = 97; }
    size_t base = ((size_t)b * PADIMG_ + yy * PADW_ + xx) * Cch + c8;
    *(bf16x8*)&bh[base] = (bf16x8)(short)0;
    *(bf16x8*)&bl[base] = (bf16x8)(short)0;
}

// ---------------------------------------------------------------------------
// Transpose+split into padded layout: in [b][C][96*96] fp32 ->
// oh/ol [b*PADIMG + (y+1)*98 + x+1][C] bf16 hi/lo (interior only)
// ---------------------------------------------------------------------------
__global__ __launch_bounds__(256)
void tsplit_kernel(const float* __restrict__ in, ushort_t* __restrict__ oh,
                   ushort_t* __restrict__ ol, int Cch)
{
    __shared__ float T[32][33];
    const int tx = threadIdx.x & 31, ty = threadIdx.x >> 5;
    const int p0 = blockIdx.x * 32, ci0 = blockIdx.y * 32, b = blockIdx.z;
#pragma unroll
    for (int i = 0; i < 4; ++i)
        T[ty + 8*i][tx] = in[((size_t)b*Cch + ci0 + ty + 8*i)*HW_ + p0 + tx];
    __syncthreads();
    const int y = p0 / 96, x0 = p0 - y * 96;
    const size_t Pp = (size_t)b*PADIMG_ + (size_t)(y + 1)*PADW_ + x0 + 1;
#pragma unroll
    for (int i = 0; i < 4; ++i) {
        float v = T[tx][ty + 8*i];
        ushort_t hi = bf16_of(v);
        float lo = v - f_of_bf16(hi);
        size_t o = (Pp + ty + 8*i)*Cch + ci0 + tx;
        oh[o] = hi;
        ol[o] = bf16_of(lo);
    }
}

// ---------------------------------------------------------------------------
// Weight repack: w [oc][ci][3][3] fp32 -> wh/wl [tap][g][oc][ci16] bf16 hi/lo
// ---------------------------------------------------------------------------
__global__ __launch_bounds__(256)
void repack_kernel(const float* __restrict__ w, ushort_t* __restrict__ wh,
                   ushort_t* __restrict__ wl, int Cout, int Cin)
{
    int id = blockIdx.x*256 + threadIdx.x;
    int tot = 9*Cout*Cin;
    if (id >= tot) return;
    int tap = id / (Cout*Cin);
    int r   = id - tap*(Cout*Cin);
    int g   = r / (Cout*16);
    int r2  = r - g*(Cout*16);
    int oc  = r2 >> 4, cr = r2 & 15;
    int ci  = g*16 + cr;
    float v = w[((size_t)oc*Cin + ci)*9 + tap];
    ushort_t hi = bf16_of(v);
    wh[id] = hi;
    wl[id] = bf16_of(v - f_of_bf16(hi));
}

// ---------------------------------------------------------------------------
// Pack per-head params: bias1all[3][256]; w2all[3][11][256] (zero-padded for
// L/R); b2all[3][11] (zero-padded).
// ---------------------------------------------------------------------------
__global__ __launch_bounds__(256)
void pack_heads3_kernel(const float* lb1, const float* rb1, const float* ob1,
                        const float* lw2, const float* rw2, const float* ow2,
                        const float* lb2, const float* rb2, const float* ob2,
                        float* __restrict__ bias1all, float* __restrict__ w2all,
                        float* __restrict__ b2all)
{
    int i = blockIdx.x * 256 + threadIdx.x;
    if (i < 768) bias1all[i] = (i < 256) ? lb1[i] : (i < 512) ? rb1[i-256] : ob1[i-512];
    if (i < 33) {
        int h = i / 11, k = i - h*11;
        b2all[i] = (h == 0) ? (k < 2 ? lb2[k] : 0.f)
                 : (h == 1) ? (k < 2 ? rb2[k] : 0.f)
                 : ob2[k];
    }
    if (i < 3*11*256) {
        int h = i / 2816, r = i - h*2816;
        int k = r / 256, oc = r - k*256;
        float v = 0.f;
        if (h == 0)      { if (k < 2) v = lw2[k*256 + oc]; }
        else if (h == 1) { if (k < 2) v = rw2[k*256 + oc]; }
        else             v = ow2[k*256 + oc];
        w2all[i] = v;
    }
}

// ---------------------------------------------------------------------------
// Implicit-GEMM conv3x3 (round-6 structure, contact branch only), hardened.
//   MODE 1: bias+relu -> Oth/Otl padded-transposed [P'][COUT] bf16 hi/lo
//   MODE 2: bias+relu -> outf [b][COUT][HW] fp32 (LDS transpose)
// ---------------------------------------------------------------------------
template<int WM, int WN, int MFR, int NFR, int CIN, int MODE>
__global__ __launch_bounds__(WM*WN*64, (WM*WN + 3) / 4)
void conv_gemm_kernel(const ushort_t* __restrict__ Agh, const ushort_t* __restrict__ Agl,
                      const ushort_t* __restrict__ Wgh, const ushort_t* __restrict__ Wgl,
                      const float* __restrict__ bias1,
                      ushort_t* __restrict__ Oth, ushort_t* __restrict__ Otl,
                      float* __restrict__ outf)
{
    constexpr int NW    = WM*WN;
    constexpr int NT    = NW*64;
    constexpr int BM    = WM*MFR*32;      // 288
    constexpr int COUT  = WN*NFR*32;
    constexpr int NG    = CIN/16;
    constexpr int APAD  = 512;
    constexpr int ASZ   = 2*APAD*16;
    constexpr int AROUNDS = 32;
    static_assert(BM == 288, "BM must be 288");

    __shared__ __align__(16) ushort_t ALds[2*ASZ];

    const int tid  = threadIdx.x;
    const int lane = tid & 63;
    const int wid  = __builtin_amdgcn_readfirstlane(tid >> 6);
    const int wm   = wid / WN, wn = wid % WN;
    const int l31  = lane & 31, hh2 = lane >> 5;
    const int wnb  = wn * NFR * 32;

    const int cpx = gridDim.x >> 3;
    const int bid = (blockIdx.x & 7)*cpx + (blockIdx.x >> 3);
    const int bidx = bid >> 5;
    const int br   = bid & 31;
    const size_t S = (size_t)bidx*PADIMG_ + (size_t)(3*br)*PADW_;

    auto stageA = [&](int g, int sel) {
        ushort_t* dst = ALds + sel*ASZ;
#pragma unroll 1
        for (int c = wid; c < AROUNDS; c += NW) {
            int id = c*64 + lane;
            int split = id >> 10;
            int r2 = id & 1023;
            int row = r2 >> 1, slot = r2 & 1;
            int ch = slot ^ ((row >> 2) & 1);
            const ushort_t* src = (split ? Agl : Agh) + (S + row)*CIN + g*16 + ch*8;
            gl16(src, dst + (size_t)c*512);
        }
    };

    f32x16 acc[MFR][NFR];
#pragma unroll
    for (int i = 0; i < MFR; ++i)
#pragma unroll
        for (int j = 0; j < NFR; ++j)
#pragma unroll
            for (int r = 0; r < 16; ++r) acc[i][j][r] = 0.f;

    bf16x8 bh0[NFR], bl0[NFR], bh1[NFR], bl1[NFR], bh2[NFR], bl2[NFR];

#define LOADB(G, T, BH, BL)                                                    \
    {                                                                          \
        _Pragma("unroll")                                                      \
        for (int nf = 0; nf < NFR; ++nf) {                                     \
            size_t o = ((size_t)((T)*NG + (G))*COUT + (wnb + nf*32 + l31))*16  \
                       + hh2*8;                                                \
            BH[nf] = *(const bf16x8*)&Wgh[o];                                  \
            BL[nf] = *(const bf16x8*)&Wgl[o];                                  \
        }                                                                      \
    }

    stageA(0, 0);
    LOADB(0, 0, bh0, bl0);
    LOADB(0, 1, bh1, bl1);
    __builtin_amdgcn_sched_barrier(0);
    asm volatile("s_waitcnt vmcnt(%0)" :: "n"(4*NFR) : "memory");
    __builtin_amdgcn_s_barrier();
    __builtin_amdgcn_sched_barrier(0);

#define TAPBODY(T, BHC, BLC, BHN, BLN)                                         \
    {                                                                          \
        if ((T) <= 6)            LOADB(g,     (T)+2, BHN, BLN)                 \
        else if (g + 1 < NG)     LOADB(g+1,   (T)-7, BHN, BLN)                 \
        const int tapoff = ((T)/3)*PADW_ + ((T) % 3);                          \
        _Pragma("unroll")                                                      \
        for (int mf = 0; mf < MFR; ++mf) {                                     \
            int row = wm*PADW_ + tapoff + mf*32 + l31;                         \
            int o = abase + row*16 + ((hh2 ^ ((row >> 2) & 1)) << 3);          \
            bf16x8 ah = *(const bf16x8*)&ALds[o];                              \
            bf16x8 al = *(const bf16x8*)&ALds[o + APAD*16];                    \
            _Pragma("unroll")                                                  \
            for (int nf = 0; nf < NFR; ++nf) {                                 \
                acc[mf][nf] = __builtin_amdgcn_mfma_f32_32x32x16_bf16(         \
                    ah, BHC[nf], acc[mf][nf], 0, 0, 0);                        \
                acc[mf][nf] = __builtin_amdgcn_mfma_f32_32x32x16_bf16(         \
                    al, BHC[nf], acc[mf][nf], 0, 0, 0);                        \
                acc[mf][nf] = __builtin_amdgcn_mfma_f32_32x32x16_bf16(         \
                    ah, BLC[nf], acc[mf][nf], 0, 0, 0);                        \
            }                                                                  \
        }                                                                      \
    }

#pragma unroll 1
    for (int g = 0; g < NG; ++g) {
        if (g + 1 < NG) stageA(g + 1, (g + 1) & 1);
        const int abase = (g & 1) * ASZ;
        TAPBODY(0, bh0, bl0, bh2, bl2);
        TAPBODY(1, bh1, bl1, bh0, bl0);
        TAPBODY(2, bh2, bl2, bh1, bl1);
        TAPBODY(3, bh0, bl0, bh2, bl2);
        TAPBODY(4, bh1, bl1, bh0, bl0);
        TAPBODY(5, bh2, bl2, bh1, bl1);
        TAPBODY(6, bh0, bl0, bh2, bl2);
        TAPBODY(7, bh1, bl1, bh0, bl0);
        TAPBODY(8, bh2, bl2, bh1, bl1);
        __builtin_amdgcn_sched_barrier(0);
        asm volatile("s_waitcnt lgkmcnt(0)" ::: "memory");   // ds_read data home
        asm volatile("s_waitcnt vmcnt(%0)" :: "n"(4*NFR) : "memory");
        __builtin_amdgcn_s_barrier();
        __builtin_amdgcn_sched_barrier(0);
    }
#undef TAPBODY
#undef LOADB
    __syncthreads();

    float biasv[NFR];
#pragma unroll
    for (int nf = 0; nf < NFR; ++nf) biasv[nf] = bias1[wnb + nf*32 + l31];

    if constexpr (MODE == 1) {
#pragma unroll
        for (int mf = 0; mf < MFR; ++mf)
#pragma unroll
            for (int nf = 0; nf < NFR; ++nf)
#pragma unroll
                for (int r = 0; r < 16; ++r) {
                    float rr = fmaxf(acc[mf][nf][r] + biasv[nf], 0.f);
                    ushort_t hi = bf16_of(rr);
                    float lo = rr - f_of_bf16(hi);
                    int crow = (r & 3) + 8*(r >> 2) + 4*hh2;
                    int xx = mf*32 + crow;
                    size_t Pp = (size_t)bidx*PADIMG_
                              + (size_t)(3*br + wm + 1)*PADW_ + xx + 1;
                    size_t o = Pp*COUT + wnb + nf*32 + l31;
                    Oth[o] = hi;
                    Otl[o] = bf16_of(lo);
                }
    } else {
        float (*T)[BM + 1] = (float(*)[BM + 1])ALds;
#pragma unroll
        for (int mf = 0; mf < MFR; ++mf)
#pragma unroll
            for (int r = 0; r < 16; ++r) {
                float rr = fmaxf(acc[mf][0][r] + biasv[0], 0.f);
                int crow = (r & 3) + 8*(r >> 2) + 4*hh2;
                T[l31][wm*96 + mf*32 + crow] = rr;
            }
        __syncthreads();
        for (int i = tid; i < COUT*BM; i += NT) {
            int c = i / BM, m = i - c*BM;
            outf[((size_t)bidx*COUT + c)*HW_ + br*288 + m] = T[c][m];
        }
    }
}

// ---------------------------------------------------------------------------
// Round-13 unified head kernel: r9 depth-1 X/Y schedule (no spill), race-
// hardened STAGEWAIT, HEAD-MAJOR dispatch (h = bx/768, per-head XCD swizzle)
// so L2 sees one weight stream at a time. 4 waves, NFR=2, 19.5KB, 3 blk/CU.
// ---------------------------------------------------------------------------
__global__ __launch_bounds__(256, 3)
void conv_sbu_kernel(const ushort_t* __restrict__ Agh, const ushort_t* __restrict__ Agl,
                     const ushort_t* __restrict__ wLh, const ushort_t* __restrict__ wLl,
                     const ushort_t* __restrict__ wRh, const ushort_t* __restrict__ wRl,
                     const ushort_t* __restrict__ wOh, const ushort_t* __restrict__ wOl,
                     const float* __restrict__ bias1all, const float* __restrict__ w2all,
                     const float* __restrict__ b2all, float* __restrict__ out_logits)
{
    constexpr int NG = 16, APAD = 304, ASZ = 2*APAD*16, AGR = 19, MFR = 3, NFR = 2;
    __shared__ __align__(16) ushort_t ALds[ASZ];

    const int tid  = threadIdx.x;
    const int lane = tid & 63;
    const int wid  = __builtin_amdgcn_readfirstlane(tid >> 6);
    const int l31  = lane & 31, hh2 = lane >> 5;
    const int wnb  = wid * 64;                 // wave's 64-channel column base

    // head-major: all L blocks dispatch before R before O (L2 phase locality);
    // per-head bijective XCD swizzle over 768 = 8 x 96.
    const int h    = blockIdx.x / 768;
    const int subx = blockIdx.x - h*768;
    const int sub  = (subx & 7)*96 + (subx >> 3);
    const int bidx = sub / 96, prow = sub - bidx*96;
    const int pimg0 = prow * 96;
    const size_t S = (size_t)bidx*PADIMG_ + (size_t)prow*PADW_;

    const ushort_t* Wh = (h == 0) ? wLh : (h == 1) ? wRh : wOh;
    const ushort_t* Wl = (h == 0) ? wLl : (h == 1) ? wRl : wOl;
    const float* bias1 = bias1all + h*256;
    const float* w2    = w2all + (size_t)h*2816;      // [11][256]
    const float* b2    = b2all + h*11;
    const int kklim = (h == 2) ? 11 : 2;
    float* dst = out_logits + ((h == 0) ? 0 : (h == 1) ? 147456 : 294912);

    auto stageA = [&](int g) {
#pragma unroll 1
        for (int c = wid; c < AGR; c += 4) {
            int id = c*64 + lane;
            int split = id / (2*APAD);
            int r2 = id % (2*APAD);
            int row = r2 >> 1, slot = r2 & 1;
            int ch = slot ^ ((row >> 2) & 1);     // inverse of read swizzle
            const ushort_t* src = (split ? Agl : Agh) + (S + row)*C_ + g*16 + ch*8;
            gl16(src, ALds + (size_t)c*512);
        }
    };

    f32x16 acc[MFR][NFR];
#pragma unroll
    for (int i = 0; i < MFR; ++i)
#pragma unroll
        for (int j = 0; j < NFR; ++j)
#pragma unroll
            for (int r = 0; r < 16; ++r) acc[i][j][r] = 0.f;

    bf16x8 bhX[NFR], blX[NFR], bhY[NFR], blY[NFR];

#define LOADB(G, T, BH, BL)                                                    \
    {                                                                          \
        _Pragma("unroll")                                                      \
        for (int nf = 0; nf < NFR; ++nf) {                                     \
            size_t o = ((size_t)((T)*NG + (G))*256 + (wnb + nf*32 + l31))*16   \
                       + hh2*8;                                                \
            BH[nf] = *(const bf16x8*)&Wh[o];                                   \
            BL[nf] = *(const bf16x8*)&Wl[o];                                   \
        }                                                                      \
    }

#define TAPBODY(G, T, BHC, BLC, BHN, BLN)                                      \
    {                                                                          \
        if ((T) < 8)             LOADB((G), (T)+1, BHN, BLN)                   \
        else if ((G) + 1 < NG)   LOADB((G)+1, 0, BHN, BLN)                     \
        const int tapoff = ((T)/3)*PADW_ + ((T) % 3);                          \
        _Pragma("unroll")                                                      \
        for (int mf = 0; mf < MFR; ++mf) {                                     \
            int row = tapoff + mf*32 + l31;                                    \
            int o = row*16 + ((hh2 ^ ((row >> 2) & 1)) << 3);                  \
            bf16x8 ah = *(const bf16x8*)&ALds[o];                              \
            bf16x8 al = *(const bf16x8*)&ALds[o + APAD*16];                    \
            _Pragma("unroll")                                                  \
            for (int nf = 0; nf < NFR; ++nf) {                                 \
                acc[mf][nf] = __builtin_amdgcn_mfma_f32_32x32x16_bf16(         \
                    ah, BHC[nf], acc[mf][nf], 0, 0, 0);                        \
                acc[mf][nf] = __builtin_amdgcn_mfma_f32_32x32x16_bf16(         \
                    al, BHC[nf], acc[mf][nf], 0, 0, 0);                        \
                acc[mf][nf] = __builtin_amdgcn_mfma_f32_32x32x16_bf16(         \
                    ah, BLC[nf], acc[mf][nf], 0, 0, 0);                        \
            }                                                                  \
        }                                                                      \
    }

#define GROUPBODY(G, S0h, S0l, S1h, S1l)                                       \
    {                                                                          \
        TAPBODY((G), 0, S0h, S0l, S1h, S1l);                                   \
        TAPBODY((G), 1, S1h, S1l, S0h, S0l);                                   \
        TAPBODY((G), 2, S0h, S0l, S1h, S1l);                                   \
        TAPBODY((G), 3, S1h, S1l, S0h, S0l);                                   \
        TAPBODY((G), 4, S0h, S0l, S1h, S1l);                                   \
        TAPBODY((G), 5, S1h, S1l, S0h, S0l);                                   \
        TAPBODY((G), 6, S0h, S0l, S1h, S1l);                                   \
        TAPBODY((G), 7, S1h, S1l, S0h, S0l);                                   \
        TAPBODY((G), 8, S0h, S0l, S1h, S1l);                                   \
    }

// HARDENED: lgkmcnt(0)+sched_barrier BEFORE the overwrite barrier (r11 race).
#define STAGEWAIT(G)                                                           \
    __builtin_amdgcn_sched_barrier(0);                                         \
    asm volatile("s_waitcnt lgkmcnt(0)" ::: "memory");                         \
    __builtin_amdgcn_sched_barrier(0);                                         \
    __builtin_amdgcn_s_barrier();        /* prior group's reads in regs */     \
    stageA(G);                                                                 \
    __builtin_amdgcn_sched_barrier(0);                                         \
    asm volatile("s_waitcnt vmcnt(0)" ::: "memory");                           \
    __builtin_amdgcn_s_barrier();                                              \
    __builtin_amdgcn_sched_barrier(0);

    LOADB(0, 0, bhX, blX);

#pragma unroll 1
    for (int g = 0; g < NG; g += 2) {
        STAGEWAIT(g)
        GROUPBODY(g,     bhX, blX, bhY, blY);
        STAGEWAIT(g + 1)
        GROUPBODY(g + 1, bhY, blY, bhX, blX);
    }
#undef STAGEWAIT
#undef GROUPBODY
#undef TAPBODY
#undef LOADB
    __syncthreads();

    // ---- fused 1x1 epilogue: full COUT in this block -> direct write ----
    float biasv[NFR];
#pragma unroll
    for (int nf = 0; nf < NFR; ++nf) biasv[nf] = bias1[wnb + nf*32 + l31];
    float w2v[NFR][11];
#pragma unroll
    for (int nf = 0; nf < NFR; ++nf)
#pragma unroll
        for (int k = 0; k < 11; ++k) w2v[nf][k] = w2[k*256 + wnb + nf*32 + l31];

    float* Lacc = (float*)ALds;               // [4][96][11] = 16.9KB
#pragma unroll
    for (int mf = 0; mf < MFR; ++mf) {
#pragma unroll
        for (int r = 0; r < 16; ++r) {
            float v[11];
#pragma unroll
            for (int k = 0; k < 11; ++k) v[k] = 0.f;
#pragma unroll
            for (int nf = 0; nf < NFR; ++nf) {
                float rr = fmaxf(acc[mf][nf][r] + biasv[nf], 0.f);
#pragma unroll
                for (int k = 0; k < 11; ++k)
                    if (k < kklim) v[k] += rr * w2v[nf][k];
            }
#pragma unroll
            for (int k = 0; k < 11; ++k) {
                if (k < kklim) {
                    v[k] += __shfl_xor(v[k], 1);
                    v[k] += __shfl_xor(v[k], 2);
                    v[k] += __shfl_xor(v[k], 4);
                    v[k] += __shfl_xor(v[k], 8);
                    v[k] += __shfl_xor(v[k], 16);
                }
            }
            if (l31 == 0) {
                int crow = (r & 3) + 8*(r >> 2) + 4*hh2;
                int row96 = mf*32 + crow;
#pragma unroll
                for (int k = 0; k < 11; ++k)
                    if (k < kklim)
                        Lacc[((size_t)wid*96 + row96)*11 + k] = v[k];
            }
        }
    }
    __syncthreads();
    for (int i = tid; i < 96*kklim; i += 256) {
        int row96 = i / kklim, k = i - row96*kklim;
        float s = b2[k];
#pragma unroll
        for (int w = 0; w < 4; ++w) s += Lacc[((size_t)w*96 + row96)*11 + k];
        dst[((size_t)bidx*kklim + k)*HW_ + pimg0 + row96] = s;
    }
}

// ---------------------------------------------------------------------------
// Softmax / mask / NMS-score kernels. L/R heads batched over blockIdx.y.
// ---------------------------------------------------------------------------
__global__ __launch_bounds__(256)
void prob2b_kernel(const float* __restrict__ l2, const float* __restrict__ l3,
                   float* __restrict__ pL, float* __restrict__ pR)
{
    const float* logits = blockIdx.y ? l3 : l2;
    float* p0 = blockIdx.y ? pR : pL;
    int i = blockIdx.x * 256 + threadIdx.x;
    if (i >= B_ * HW_) return;
    int b = i / HW_, pix = i - b * HW_;
    float l0 = logits[(size_t)b * 2 * HW_ + pix];
    float l1 = logits[(size_t)b * 2 * HW_ + HW_ + pix];
    float m = fmaxf(l0, l1);
    float e0 = expf(l0 - m), e1 = expf(l1 - m);
    p0[i] = e0 / (e0 + e1);
}

__global__ __launch_bounds__(256)
void score2b_kernel(const float* __restrict__ pL, const float* __restrict__ pR,
                    float* __restrict__ sL, float* __restrict__ sR)
{
    const float* p = blockIdx.y ? pR : pL;
    float* sc = blockIdx.y ? sR : sL;
    int i = blockIdx.x * 256 + threadIdx.x;
    if (i >= B_ * HW_) return;
    int pix = i % HW_;
    int yy = pix / W_, xx = pix - (pix / W_) * W_;
    float c = p[i];
    bool ok = (c >= EPS_);
    const float* pb = p + (i - pix);
#pragma unroll
    for (int dy = -1; dy <= 1; ++dy)
#pragma unroll
        for (int dx = -1; dx <= 1; ++dx) {
            if (dy == 0 && dx == 0) continue;
            int ny = yy + dy, nx = xx + dx;
            float v = 0.f;
            if (ny >= 0 && ny < H_ && nx >= 0 && nx < W_) v = pb[ny * W_ + nx];
            ok = ok && (c >= v);
        }
    sc[i] = c + (ok ? 1.f : 0.f);
}

__global__ __launch_bounds__(256)
void probobj_kernel(const float* __restrict__ logits, float* __restrict__ pval,
                    int* __restrict__ cstar)
{
    int i = blockIdx.x * 256 + threadIdx.x;
    if (i >= B_ * HW_) return;
    int b = i / HW_, pix = i - b * HW_;
    const float* lb = logits + (size_t)b * 11 * HW_ + pix;
    float l[11];
#pragma unroll
    for (int c2 = 0; c2 < 11; ++c2) l[c2] = lb[(size_t)c2 * HW_];
    float m = l[0];
#pragma unroll
    for (int c2 = 1; c2 < 11; ++c2) m = fmaxf(m, l[c2]);
    float sum = 0.f;
#pragma unroll
    for (int c2 = 0; c2 < 11; ++c2) sum += expf(l[c2] - m);
    int a = 0; float bestl = l[0];
#pragma unroll
    for (int c2 = 1; c2 < 10; ++c2)
        if (l[c2] > bestl) { bestl = l[c2]; a = c2; }
    pval[i] = expf(bestl - m) / sum;
    cstar[i] = a;
}

__global__ __launch_bounds__(256)
void score11_kernel(const float* __restrict__ p, const int* __restrict__ cs,
                    float* __restrict__ sc)
{
    int i = blockIdx.x * 256 + threadIdx.x;
    if (i >= B_ * HW_) return;
    int pix = i % HW_;
    int yy = pix / W_, xx = pix - (pix / W_) * W_;
    float c = p[i];
    int cc = cs[i];
    bool ok = (c >= EPS_);
    int base = i - pix;
#pragma unroll
    for (int dy = -1; dy <= 1; ++dy)
#pragma unroll
        for (int dx = -1; dx <= 1; ++dx) {
            if (dy == 0 && dx == 0) continue;
            int ny = yy + dy, nx = xx + dx;
            float v = 0.f;
            if (ny >= 0 && ny < H_ && nx >= 0 && nx < W_) {
                int n = base + ny * W_ + nx;
                v = (cs[n] == cc) ? p[n] : 0.f;
            }
            ok = ok && (c >= v);
        }
    sc[i] = c + (ok ? 1.f : 0.f);
}

// ---------------------------------------------------------------------------
// top-k by iterative argmax (matches jax.lax.top_k ordering)
// ---------------------------------------------------------------------------
__global__ __launch_bounds__(256)
void topk_kernel(const float* __restrict__ scL, const float* __restrict__ scR,
                 const float* __restrict__ scO, int* __restrict__ idx)
{
    __shared__ float sv[HW_];
    __shared__ float rv[256];
    __shared__ int   ri[256];
    const int h = blockIdx.x, b = blockIdx.y;
    const float* src = (h == 0) ? scL : (h == 1) ? scR : scO;
    const int k = (h == 2) ? 20 : 40;
    const int off = b * NQ_ + ((h == 0) ? 0 : (h == 1) ? 40 : 80);

    for (int t = threadIdx.x; t < HW_; t += 256) sv[t] = src[(size_t)b * HW_ + t];
    __syncthreads();

    for (int kk = 0; kk < k; ++kk) {
        float bestv = -FLT_MAX; int besti = HW_;
        for (int t = threadIdx.x; t < HW_; t += 256) {
            float v = sv[t];
            if (v > bestv) { bestv = v; besti = t; }
        }
        rv[threadIdx.x] = bestv; ri[threadIdx.x] = besti;
        __syncthreads();
        for (int s = 128; s > 0; s >>= 1) {
            if (threadIdx.x < s) {
                float v2 = rv[threadIdx.x + s]; int i2 = ri[threadIdx.x + s];
                if (v2 > rv[threadIdx.x] ||
                    (v2 == rv[threadIdx.x] && i2 < ri[threadIdx.x])) {
                    rv[threadIdx.x] = v2; ri[threadIdx.x] = i2;
                }
            }
            __syncthreads();
        }
        if (threadIdx.x == 0) { idx[off + kk] = ri[0]; sv[ri[0]] = -FLT_MAX; }
        __syncthreads();
    }
}

// ---------------------------------------------------------------------------
// Contact branch tail (unchanged)
// ---------------------------------------------------------------------------
__global__ __launch_bounds__(128)
void pool_kernel(const float* __restrict__ h2, float* __restrict__ pooled)
{
    int bc = blockIdx.x;
    __shared__ float row[96];
    for (int hh = threadIdx.x; hh < 96; hh += 128) {
        const float* p = h2 + (size_t)bc * HW_ + hh * W_;
        float s = 0.f;
        for (int ww = 0; ww < 96; ++ww) s += p[ww];
        row[hh] = s * (1.f / 96.f);
    }
    __syncthreads();
    for (int i = threadIdx.x; i < 778; i += 128) {
        int s0 = (i * 96) / 778;
        int e0 = ((i + 1) * 96 + 777) / 778;
        float s = 0.f;
        for (int t = s0; t < e0; ++t) s += row[t];
        pooled[(size_t)bc * 778 + i] = s / (float)(e0 - s0);
    }
}

__global__ __launch_bounds__(256)
void cm_kernel(const float* __restrict__ pooled, const float* __restrict__ cm_lw,
               const float* __restrict__ cm_lb, float* __restrict__ out5)
{
    const int j = blockIdx.x;
    const float* wr = cm_lw + (size_t)j * 24896;
    float acc[8];
#pragma unroll
    for (int b = 0; b < 8; ++b) acc[b] = 0.f;
    for (int t = threadIdx.x; t < 24896; t += 256) {
        float w = wr[t];
#pragma unroll
        for (int b = 0; b < 8; ++b) acc[b] += w * pooled[(size_t)b * 24896 + t];
    }
    __shared__ float red[8][256];
#pragma unroll
    for (int b = 0; b < 8; ++b) red[b][threadIdx.x] = acc[b];
    __syncthreads();
    for (int s = 128; s > 0; s >>= 1) {
        if (threadIdx.x < s) {
#pragma unroll
            for (int b = 0; b < 8; ++b) red[b][threadIdx.x] += red[b][threadIdx.x + s];
        }
        __syncthreads();
    }
    if (threadIdx.x < 8)
        out5[(size_t)threadIdx.x * 1556 + j] = red[threadIdx.x][0] + cm_lb[j];
}

__global__ __launch_bounds__(256)
void c1d_kernel(const float* __restrict__ cmap, const float* __restrict__ w,
                const float* __restrict__ bias, float* __restrict__ ccmean)
{
    int b = blockIdx.x;
    __shared__ float r[2][778];
    __shared__ float T[2][3];
    for (int t = threadIdx.x; t < 1556; t += 256)
        r[t / 778][t % 778] = cmap[(size_t)b * 1556 + t];
    __syncthreads();
    if (threadIdx.x < 2) {
        int ic = threadIdx.x;
        float s = 0.f;
        for (int i2 = 0; i2 < 778; ++i2) s += r[ic][i2];
        T[ic][0] = s - r[ic][776] - r[ic][777];
        T[ic][1] = s - r[ic][0]   - r[ic][777];
        T[ic][2] = s - r[ic][0]   - r[ic][1];
    }
    __syncthreads();
    int oc = threadIdx.x;
    float a = 0.f;
#pragma unroll
    for (int ic = 0; ic < 2; ++ic)
#pragma unroll
        for (int k = 0; k < 3; ++k)
            a += w[oc * 6 + ic * 3 + k] * T[ic][k];
    ccmean[b * 256 + oc] = a / 776.f + bias[oc];
}

__global__ __launch_bounds__(256)
void feat_kernel(const float* __restrict__ ccmean, const float* __restrict__ q_lw,
                 const float* __restrict__ q_lb, float* __restrict__ feat)
{
    __shared__ float cc[8][256];
    for (int t = threadIdx.x; t < 2048; t += 256) cc[t >> 8][t & 255] = ccmean[t];
    __syncthreads();
    int j = blockIdx.x * 256 + threadIdx.x;
    const float* wr = q_lw + (size_t)j * 256;
    float acc[8];
#pragma unroll
    for (int b = 0; b < 8; ++b) acc[b] = 0.f;
    for (int c = 0; c < 256; ++c) {
        float wv = wr[c];
#pragma unroll
        for (int b = 0; b < 8; ++b) acc[b] += wv * cc[b][c];
    }
    float qb = q_lb[j];
#pragma unroll
    for (int b = 0; b < 8; ++b) feat[(size_t)b * 25600 + j] = acc[b] + qb;
}

__global__ __launch_bounds__(256)
void gather_kernel(const float* __restrict__ x, const float* __restrict__ pos,
                   const float* __restrict__ feat, const int* __restrict__ idx,
                   float* __restrict__ out0, float* __restrict__ out1)
{
    int t = blockIdx.x * 256 + threadIdx.x;
    if (t >= B_ * C_ * NQ_) return;
    int q = t % NQ_;
    int c2 = (t / NQ_) % C_;
    int b = t / (C_ * NQ_);
    int p = idx[b * NQ_ + q];
    out0[t] = x[((size_t)b * C_ + c2) * HW_ + p] + feat[(size_t)b * 25600 + c2 * NQ_ + q];
    out1[t] = pos[(size_t)c2 * HW_ + p];
}

// ---------------------------------------------------------------------------
extern "C" void kernel_launch(void* const* d_in, const int* in_sizes, int n_in,
                              void* d_out, int out_size, void* d_ws, size_t ws_size,
                              hipStream_t stream) {
    const float* x    = (const float*)d_in[0];
    const float* y    = (const float*)d_in[1];
    const float* pos  = (const float*)d_in[2];
    const float* lw1  = (const float*)d_in[3];  const float* lb1 = (const float*)d_in[4];
    const float* lw2  = (const float*)d_in[5];  const float* lb2 = (const float*)d_in[6];
    const float* rw1  = (const float*)d_in[7];  const float* rb1 = (const float*)d_in[8];
    const float* rw2  = (const float*)d_in[9];  const float* rb2 = (const float*)d_in[10];
    const float* ow1  = (const float*)d_in[11]; const float* ob1 = (const float*)d_in[12];
    const float* ow2  = (const float*)d_in[13]; const float* ob2 = (const float*)d_in[14];
    const float* cw1  = (const float*)d_in[15]; const float* cb1 = (const float*)d_in[16];
    const float* cw2  = (const float*)d_in[17]; const float* cb2 = (const float*)d_in[18];
    const float* cmlw = (const float*)d_in[19]; const float* cmlb = (const float*)d_in[20];
    const float* c1dw = (const float*)d_in[21]; const float* c1db = (const float*)d_in[22];
    const float* qlw  = (const float*)d_in[23]; const float* qlb  = (const float*)d_in[24];

    float* out  = (float*)d_out;
    float* out0 = out;                 // topk_proposals [8,256,100]
    float* out1 = out + 204800;        // topk_pos       [8,256,100]
    float* out2 = out + 409600;        // left_logits    [8,2,96,96]
    float* out3 = out + 557056;        // right_logits   [8,2,96,96]
    float* out4 = out + 704512;        // obj_logits     [8,11,96,96]
    float* out5 = out + 1515520;       // contact_map    [8,2,778,1]

    float* ws = (float*)d_ws;
    ushort_t* Rh   = (ushort_t*)(ws);                       // 76880*256 ush
    ushort_t* Rl   = (ushort_t*)(ws + 9840640);
    ushort_t* h1h  = (ushort_t*)(ws + 19681280);            // 76880*64 ush
    ushort_t* h1l  = (ushort_t*)(ws + 22141440);
    float*    h2   = ws + 24601600;                         // 8*32*9216 fp32
    ushort_t* wLh  = (ushort_t*)(ws + 26960896);            // 9*256*256 ush each
    ushort_t* wLl  = (ushort_t*)(ws + 27255808);
    ushort_t* wRh  = (ushort_t*)(ws + 27550720);
    ushort_t* wRl  = (ushort_t*)(ws + 27845632);
    ushort_t* wOh  = (ushort_t*)(ws + 28140544);
    ushort_t* wOl  = (ushort_t*)(ws + 28435456);
    ushort_t* wc1h = (ushort_t*)(ws + 28730368);            // 9*64*256
    ushort_t* wc1l = (ushort_t*)(ws + 28804096);
    ushort_t* wc2h = (ushort_t*)(ws + 28877824);            // 9*32*64
    ushort_t* wc2l = (ushort_t*)(ws + 28887040);
    float* pooled  = ws + 28896256;                         // 8*32*778
    float* ccmean  = ws + 29095424;                         // 2048
    float* feat    = ws + 29097472;                         // 204800
    float* pmapL   = ws + 29302272;                         // 73728
    int*   csmap   = (int*)(ws + 29376000);                 // 73728
    float* scL     = ws + 29449728;
    float* scR     = ws + 29523456;
    float* scO     = ws + 29597184;
    int*   idxb    = (int*)(ws + 29670912);                 // 800
    float* bias1all= ws + 29671712;                         // 768
    float* w2all   = ws + 29672480;                         // 8448
    float* b2all   = ws + 29680928;                         // 48
    float* pmapR   = ws + 29680976;                         // 73728
    float* pmapO   = ws + 29754704;                         // 73728
    (void)in_sizes; (void)n_in; (void)out_size; (void)ws_size; (void)pos;

    // ---- one-time zeroing of padded borders + weight/param packing ----
    zero_border_kernel<<<388, 256, 0, stream>>>(Rh, Rl, 256);
    zero_border_kernel<<<97,  256, 0, stream>>>(h1h, h1l, 64);
    repack_kernel<<<(9*256*256+255)/256, 256, 0, stream>>>(lw1, wLh, wLl, 256, 256);
    repack_kernel<<<(9*256*256+255)/256, 256, 0, stream>>>(rw1, wRh, wRl, 256, 256);
    repack_kernel<<<(9*256*256+255)/256, 256, 0, stream>>>(ow1, wOh, wOl, 256, 256);
    repack_kernel<<<(9*64*256+255)/256,  256, 0, stream>>>(cw1, wc1h, wc1l, 64, 256);
    repack_kernel<<<(9*32*64+255)/256,   256, 0, stream>>>(cw2, wc2h, wc2l, 32, 64);
    pack_heads3_kernel<<<33, 256, 0, stream>>>(lb1, rb1, ob1, lw2, rw2, ow2,
                                               lb2, rb2, ob2, bias1all, w2all, b2all);

    // ---- contact branch (R holds padded yt; freed after conv1) ----
    tsplit_kernel<<<dim3(288, 8, 8), 256, 0, stream>>>(y, Rh, Rl, 256);
    conv_gemm_kernel<3,2,3,1,256,1><<<256, 384, 0, stream>>>(
        Rh, Rl, wc1h, wc1l, cb1, h1h, h1l, nullptr);
    conv_gemm_kernel<3,1,3,1,64,2><<<256, 192, 0, stream>>>(
        h1h, h1l, wc2h, wc2l, cb2, nullptr, nullptr, h2);
    pool_kernel<<<256, 128, 0, stream>>>(h2, pooled);
    cm_kernel<<<1556, 256, 0, stream>>>(pooled, cmlw, cmlb, out5);
    c1d_kernel<<<8, 256, 0, stream>>>(out5, c1dw, c1db, ccmean);
    feat_kernel<<<100, 256, 0, stream>>>(ccmean, qlw, qlb, feat);

    // ---- unified heads: head-major dispatch, depth-1 X/Y (no spill) ----
    tsplit_kernel<<<dim3(288, 8, 8), 256, 0, stream>>>(x, Rh, Rl, 256);
    conv_sbu_kernel<<<2304, 256, 0, stream>>>(
        Rh, Rl, wLh, wLl, wRh, wRl, wOh, wOl, bias1all, w2all, b2all, out2);

    // ---- probs / NMS scores (L/R batched) ----
    prob2b_kernel<<<dim3(288, 2), 256, 0, stream>>>(out2, out3, pmapL, pmapR);
    score2b_kernel<<<dim3(288, 2), 256, 0, stream>>>(pmapL, pmapR, scL, scR);
    probobj_kernel<<<288, 256, 0, stream>>>(out4, pmapO, csmap);
    score11_kernel<<<288, 256, 0, stream>>>(pmapO, csmap, scO);

    // ---- topk + gathers ----
    topk_kernel<<<dim3(3, 8), 256, 0, stream>>>(scL, scR, scO, idxb);
    gather_kernel<<<800, 256, 0, stream>>>(x, pos, feat, idxb, out0, out1);
}

// Round 14
// 1147.376 us; speedup vs baseline: 1.2812x; 1.0801x over previous
//
#include <hip/hip_runtime.h>
#include <float.h>
#include <math.h>

#define B_ 8
#define C_ 256
#define H_ 96
#define W_ 96
#define HW_ 9216
#define NQ_ 100
#define EPS_ 1e-6f
#define PADW_ 98
#define PADIMG_ 9604          // 98*98 padded image
#define PALLOC_ 76880         // 8*9604 + slack rows for A-stage overrun

typedef unsigned short ushort_t;
typedef __attribute__((ext_vector_type(8))) short bf16x8;
typedef __attribute__((ext_vector_type(16))) float f32x16;

typedef __attribute__((address_space(3))) unsigned int as3_u32;
typedef __attribute__((address_space(1))) unsigned int as1_u32;

__device__ __forceinline__ void gl16(const void* g, void* l) {
    __builtin_amdgcn_global_load_lds(
        (const as1_u32*)(unsigned long long)g,
        (as3_u32*)(unsigned int)(unsigned long long)l, 16, 0, 0);
}

__device__ __forceinline__ ushort_t bf16_of(float v) {
    unsigned u = __float_as_uint(v);
    u += 0x7fffu + ((u >> 16) & 1u);
    return (ushort_t)(u >> 16);
}
__device__ __forceinline__ float f_of_bf16(ushort_t h) {
    return __uint_as_float((unsigned)h << 16);
}

// ---------------------------------------------------------------------------
// Zero the 1-px border of each padded image (388 px/img), both splits.
// ---------------------------------------------------------------------------
__global__ __launch_bounds__(256)
void zero_border_kernel(ushort_t* __restrict__ bh, ushort_t* __restrict__ bl, int Cch)
{
    int per = 388 * Cch / 8;
    int id = blockIdx.x * 256 + threadIdx.x;
    if (id >= 8 * per) return;
    int b = id / per, i = id - b * per;
    int pi = (i * 8) / Cch, c8 = (i * 8) % Cch;
    int yy, xx;
    if (pi < 98)      { yy = 0;            xx = pi; }
    else if (pi < 196){ yy = 97;           xx = pi - 98; }
    else if (pi < 292){ yy = pi - 195;     xx = 0; }
    else              { yy = pi - 291;     xx = 97; }
    size_t base = ((size_t)b * PADIMG_ + yy * PADW_ + xx) * Cch + c8;
    *(bf16x8*)&bh[base] = (bf16x8)(short)0;
    *(bf16x8*)&bl[base] = (bf16x8)(short)0;
}

// ---------------------------------------------------------------------------
// Transpose+split into padded layout: in [b][C][96*96] fp32 ->
// oh/ol [b*PADIMG + (y+1)*98 + x+1][C] bf16 hi/lo (interior only)
// ---------------------------------------------------------------------------
__global__ __launch_bounds__(256)
void tsplit_kernel(const float* __restrict__ in, ushort_t* __restrict__ oh,
                   ushort_t* __restrict__ ol, int Cch)
{
    __shared__ float T[32][33];
    const int tx = threadIdx.x & 31, ty = threadIdx.x >> 5;
    const int p0 = blockIdx.x * 32, ci0 = blockIdx.y * 32, b = blockIdx.z;
#pragma unroll
    for (int i = 0; i < 4; ++i)
        T[ty + 8*i][tx] = in[((size_t)b*Cch + ci0 + ty + 8*i)*HW_ + p0 + tx];
    __syncthreads();
    const int y = p0 / 96, x0 = p0 - y * 96;
    const size_t Pp = (size_t)b*PADIMG_ + (size_t)(y + 1)*PADW_ + x0 + 1;
#pragma unroll
    for (int i = 0; i < 4; ++i) {
        float v = T[tx][ty + 8*i];
        ushort_t hi = bf16_of(v);
        float lo = v - f_of_bf16(hi);
        size_t o = (Pp + ty + 8*i)*Cch + ci0 + tx;
        oh[o] = hi;
        ol[o] = bf16_of(lo);
    }
}

// ---------------------------------------------------------------------------
// Weight repack: w [oc][ci][3][3] fp32 -> wh/wl [tap][g][oc][ci16] bf16 hi/lo
// ---------------------------------------------------------------------------
__global__ __launch_bounds__(256)
void repack_kernel(const float* __restrict__ w, ushort_t* __restrict__ wh,
                   ushort_t* __restrict__ wl, int Cout, int Cin)
{
    int id = blockIdx.x*256 + threadIdx.x;
    int tot = 9*Cout*Cin;
    if (id >= tot) return;
    int tap = id / (Cout*Cin);
    int r   = id - tap*(Cout*Cin);
    int g   = r / (Cout*16);
    int r2  = r - g*(Cout*16);
    int oc  = r2 >> 4, cr = r2 & 15;
    int ci  = g*16 + cr;
    float v = w[((size_t)oc*Cin + ci)*9 + tap];
    ushort_t hi = bf16_of(v);
    wh[id] = hi;
    wl[id] = bf16_of(v - f_of_bf16(hi));
}

// ---------------------------------------------------------------------------
// Pack per-head params: bias1all[3][256]; w2all[3][11][256] (zero-padded for
// L/R); b2all[3][11] (zero-padded).
// ---------------------------------------------------------------------------
__global__ __launch_bounds__(256)
void pack_heads3_kernel(const float* lb1, const float* rb1, const float* ob1,
                        const float* lw2, const float* rw2, const float* ow2,
                        const float* lb2, const float* rb2, const float* ob2,
                        float* __restrict__ bias1all, float* __restrict__ w2all,
                        float* __restrict__ b2all)
{
    int i = blockIdx.x * 256 + threadIdx.x;
    if (i < 768) bias1all[i] = (i < 256) ? lb1[i] : (i < 512) ? rb1[i-256] : ob1[i-512];
    if (i < 33) {
        int h = i / 11, k = i - h*11;
        b2all[i] = (h == 0) ? (k < 2 ? lb2[k] : 0.f)
                 : (h == 1) ? (k < 2 ? rb2[k] : 0.f)
                 : ob2[k];
    }
    if (i < 3*11*256) {
        int h = i / 2816, r = i - h*2816;
        int k = r / 256, oc = r - k*256;
        float v = 0.f;
        if (h == 0)      { if (k < 2) v = lw2[k*256 + oc]; }
        else if (h == 1) { if (k < 2) v = rw2[k*256 + oc]; }
        else             v = ow2[k*256 + oc];
        w2all[i] = v;
    }
}

// ---------------------------------------------------------------------------
// Implicit-GEMM conv3x3 (round-6 structure, contact branch only), hardened.
//   MODE 1: bias+relu -> Oth/Otl padded-transposed [P'][COUT] bf16 hi/lo
//   MODE 2: bias+relu -> outf [b][COUT][HW] fp32 (LDS transpose)
// ---------------------------------------------------------------------------
template<int WM, int WN, int MFR, int NFR, int CIN, int MODE>
__global__ __launch_bounds__(WM*WN*64, (WM*WN + 3) / 4)
void conv_gemm_kernel(const ushort_t* __restrict__ Agh, const ushort_t* __restrict__ Agl,
                      const ushort_t* __restrict__ Wgh, const ushort_t* __restrict__ Wgl,
                      const float* __restrict__ bias1,
                      ushort_t* __restrict__ Oth, ushort_t* __restrict__ Otl,
                      float* __restrict__ outf)
{
    constexpr int NW    = WM*WN;
    constexpr int NT    = NW*64;
    constexpr int BM    = WM*MFR*32;      // 288
    constexpr int COUT  = WN*NFR*32;
    constexpr int NG    = CIN/16;
    constexpr int APAD  = 512;
    constexpr int ASZ   = 2*APAD*16;
    constexpr int AROUNDS = 32;
    static_assert(BM == 288, "BM must be 288");

    __shared__ __align__(16) ushort_t ALds[2*ASZ];

    const int tid  = threadIdx.x;
    const int lane = tid & 63;
    const int wid  = __builtin_amdgcn_readfirstlane(tid >> 6);
    const int wm   = wid / WN, wn = wid % WN;
    const int l31  = lane & 31, hh2 = lane >> 5;
    const int wnb  = wn * NFR * 32;

    const int cpx = gridDim.x >> 3;
    const int bid = (blockIdx.x & 7)*cpx + (blockIdx.x >> 3);
    const int bidx = bid >> 5;
    const int br   = bid & 31;
    const size_t S = (size_t)bidx*PADIMG_ + (size_t)(3*br)*PADW_;

    auto stageA = [&](int g, int sel) {
        ushort_t* dst = ALds + sel*ASZ;
#pragma unroll 1
        for (int c = wid; c < AROUNDS; c += NW) {
            int id = c*64 + lane;
            int split = id >> 10;
            int r2 = id & 1023;
            int row = r2 >> 1, slot = r2 & 1;
            int ch = slot ^ ((row >> 2) & 1);
            const ushort_t* src = (split ? Agl : Agh) + (S + row)*CIN + g*16 + ch*8;
            gl16(src, dst + (size_t)c*512);
        }
    };

    f32x16 acc[MFR][NFR];
#pragma unroll
    for (int i = 0; i < MFR; ++i)
#pragma unroll
        for (int j = 0; j < NFR; ++j)
#pragma unroll
            for (int r = 0; r < 16; ++r) acc[i][j][r] = 0.f;

    bf16x8 bh0[NFR], bl0[NFR], bh1[NFR], bl1[NFR], bh2[NFR], bl2[NFR];

#define LOADB(G, T, BH, BL)                                                    \
    {                                                                          \
        _Pragma("unroll")                                                      \
        for (int nf = 0; nf < NFR; ++nf) {                                     \
            size_t o = ((size_t)((T)*NG + (G))*COUT + (wnb + nf*32 + l31))*16  \
                       + hh2*8;                                                \
            BH[nf] = *(const bf16x8*)&Wgh[o];                                  \
            BL[nf] = *(const bf16x8*)&Wgl[o];                                  \
        }                                                                      \
    }

    stageA(0, 0);
    LOADB(0, 0, bh0, bl0);
    LOADB(0, 1, bh1, bl1);
    __builtin_amdgcn_sched_barrier(0);
    asm volatile("s_waitcnt vmcnt(%0)" :: "n"(4*NFR) : "memory");
    __builtin_amdgcn_s_barrier();
    __builtin_amdgcn_sched_barrier(0);

#define TAPBODY(T, BHC, BLC, BHN, BLN)                                         \
    {                                                                          \
        if ((T) <= 6)            LOADB(g,     (T)+2, BHN, BLN)                 \
        else if (g + 1 < NG)     LOADB(g+1,   (T)-7, BHN, BLN)                 \
        const int tapoff = ((T)/3)*PADW_ + ((T) % 3);                          \
        _Pragma("unroll")                                                      \
        for (int mf = 0; mf < MFR; ++mf) {                                     \
            int row = wm*PADW_ + tapoff + mf*32 + l31;                         \
            int o = abase + row*16 + ((hh2 ^ ((row >> 2) & 1)) << 3);          \
            bf16x8 ah = *(const bf16x8*)&ALds[o];                              \
            bf16x8 al = *(const bf16x8*)&ALds[o + APAD*16];                    \
            _Pragma("unroll")                                                  \
            for (int nf = 0; nf < NFR; ++nf) {                                 \
                acc[mf][nf] = __builtin_amdgcn_mfma_f32_32x32x16_bf16(         \
                    ah, BHC[nf], acc[mf][nf], 0, 0, 0);                        \
                acc[mf][nf] = __builtin_amdgcn_mfma_f32_32x32x16_bf16(         \
                    al, BHC[nf], acc[mf][nf], 0, 0, 0);                        \
                acc[mf][nf] = __builtin_amdgcn_mfma_f32_32x32x16_bf16(         \
                    ah, BLC[nf], acc[mf][nf], 0, 0, 0);                        \
            }                                                                  \
        }                                                                      \
    }

#pragma unroll 1
    for (int g = 0; g < NG; ++g) {
        if (g + 1 < NG) stageA(g + 1, (g + 1) & 1);
        const int abase = (g & 1) * ASZ;
        TAPBODY(0, bh0, bl0, bh2, bl2);
        TAPBODY(1, bh1, bl1, bh0, bl0);
        TAPBODY(2, bh2, bl2, bh1, bl1);
        TAPBODY(3, bh0, bl0, bh2, bl2);
        TAPBODY(4, bh1, bl1, bh0, bl0);
        TAPBODY(5, bh2, bl2, bh1, bl1);
        TAPBODY(6, bh0, bl0, bh2, bl2);
        TAPBODY(7, bh1, bl1, bh0, bl0);
        TAPBODY(8, bh2, bl2, bh1, bl1);
        __builtin_amdgcn_sched_barrier(0);
        asm volatile("s_waitcnt lgkmcnt(0)" ::: "memory");   // ds_read data home
        asm volatile("s_waitcnt vmcnt(%0)" :: "n"(4*NFR) : "memory");
        __builtin_amdgcn_s_barrier();
        __builtin_amdgcn_sched_barrier(0);
    }
#undef TAPBODY
#undef LOADB
    __syncthreads();

    float biasv[NFR];
#pragma unroll
    for (int nf = 0; nf < NFR; ++nf) biasv[nf] = bias1[wnb + nf*32 + l31];

    if constexpr (MODE == 1) {
#pragma unroll
        for (int mf = 0; mf < MFR; ++mf)
#pragma unroll
            for (int nf = 0; nf < NFR; ++nf)
#pragma unroll
                for (int r = 0; r < 16; ++r) {
                    float rr = fmaxf(acc[mf][nf][r] + biasv[nf], 0.f);
                    ushort_t hi = bf16_of(rr);
                    float lo = rr - f_of_bf16(hi);
                    int crow = (r & 3) + 8*(r >> 2) + 4*hh2;
                    int xx = mf*32 + crow;
                    size_t Pp = (size_t)bidx*PADIMG_
                              + (size_t)(3*br + wm + 1)*PADW_ + xx + 1;
                    size_t o = Pp*COUT + wnb + nf*32 + l31;
                    Oth[o] = hi;
                    Otl[o] = bf16_of(lo);
                }
    } else {
        float (*T)[BM + 1] = (float(*)[BM + 1])ALds;
#pragma unroll
        for (int mf = 0; mf < MFR; ++mf)
#pragma unroll
            for (int r = 0; r < 16; ++r) {
                float rr = fmaxf(acc[mf][0][r] + biasv[0], 0.f);
                int crow = (r & 3) + 8*(r >> 2) + 4*hh2;
                T[l31][wm*96 + mf*32 + crow] = rr;
            }
        __syncthreads();
        for (int i = tid; i < COUT*BM; i += NT) {
            int c = i / BM, m = i - c*BM;
            outf[((size_t)bidx*COUT + c)*HW_ + br*288 + m] = T[c][m];
        }
    }
}

// ---------------------------------------------------------------------------
// Round-14 head kernel: r13 schedule with COMPILE-TIME KK (the runtime-kklim
// epilogue forced the f32x16 accumulators into scratch: 225MB WRITE_SIZE =
// 96 dwords/thread = acc[3][2]; r6/r9 compile-time-KK kernels showed 3MB).
// template<KK, NH>: NH heads in one launch (head-major, grid NH*768), per-
// head XCD swizzle. 4 waves, NFR=2, 19.5KB single A-buffer, depth-1 X/Y,
// race-hardened STAGEWAIT.
// ---------------------------------------------------------------------------
template<int KK, int NH>
__global__ __launch_bounds__(256, 3)
void conv_sbt_kernel(const ushort_t* __restrict__ Agh, const ushort_t* __restrict__ Agl,
                     const ushort_t* __restrict__ w0h, const ushort_t* __restrict__ w0l,
                     const ushort_t* __restrict__ w1h, const ushort_t* __restrict__ w1l,
                     const float* __restrict__ bias1base, const float* __restrict__ w2base,
                     const float* __restrict__ b2base, float* __restrict__ dstbase)
{
    constexpr int NG = 16, APAD = 304, ASZ = 2*APAD*16, AGR = 19, MFR = 3, NFR = 2;
    __shared__ __align__(16) ushort_t ALds[ASZ];

    const int tid  = threadIdx.x;
    const int lane = tid & 63;
    const int wid  = __builtin_amdgcn_readfirstlane(tid >> 6);
    const int l31  = lane & 31, hh2 = lane >> 5;
    const int wnb  = wid * 64;                 // wave's 64-channel column base

    // head-major dispatch; per-head bijective XCD swizzle over 768 = 8 x 96.
    const int h    = (NH == 1) ? 0 : (blockIdx.x / 768);
    const int subx = blockIdx.x - h*768;
    const int sub  = (subx & 7)*96 + (subx >> 3);
    const int bidx = sub / 96, prow = sub - bidx*96;
    const int pimg0 = prow * 96;
    const size_t S = (size_t)bidx*PADIMG_ + (size_t)prow*PADW_;

    const ushort_t* Wh = (h == 0) ? w0h : w1h;
    const ushort_t* Wl = (h == 0) ? w0l : w1l;
    const float* bias1 = bias1base + h*256;
    const float* w2    = w2base + (size_t)h*2816;     // [11][256] stride
    const float* b2    = b2base + h*11;
    float* dst = dstbase + (size_t)h*147456;

    auto stageA = [&](int g) {
#pragma unroll 1
        for (int c = wid; c < AGR; c += 4) {
            int id = c*64 + lane;
            int split = id / (2*APAD);
            int r2 = id % (2*APAD);
            int row = r2 >> 1, slot = r2 & 1;
            int ch = slot ^ ((row >> 2) & 1);     // inverse of read swizzle
            const ushort_t* src = (split ? Agl : Agh) + (S + row)*C_ + g*16 + ch*8;
            gl16(src, ALds + (size_t)c*512);
        }
    };

    f32x16 acc[MFR][NFR];
#pragma unroll
    for (int i = 0; i < MFR; ++i)
#pragma unroll
        for (int j = 0; j < NFR; ++j)
#pragma unroll
            for (int r = 0; r < 16; ++r) acc[i][j][r] = 0.f;

    bf16x8 bhX[NFR], blX[NFR], bhY[NFR], blY[NFR];

#define LOADB(G, T, BH, BL)                                                    \
    {                                                                          \
        _Pragma("unroll")                                                      \
        for (int nf = 0; nf < NFR; ++nf) {                                     \
            size_t o = ((size_t)((T)*NG + (G))*256 + (wnb + nf*32 + l31))*16   \
                       + hh2*8;                                                \
            BH[nf] = *(const bf16x8*)&Wh[o];                                   \
            BL[nf] = *(const bf16x8*)&Wl[o];                                   \
        }                                                                      \
    }

#define TAPBODY(G, T, BHC, BLC, BHN, BLN)                                      \
    {                                                                          \
        if ((T) < 8)             LOADB((G), (T)+1, BHN, BLN)                   \
        else if ((G) + 1 < NG)   LOADB((G)+1, 0, BHN, BLN)                     \
        const int tapoff = ((T)/3)*PADW_ + ((T) % 3);                          \
        _Pragma("unroll")                                                      \
        for (int mf = 0; mf < MFR; ++mf) {                                     \
            int row = tapoff + mf*32 + l31;                                    \
            int o = row*16 + ((hh2 ^ ((row >> 2) & 1)) << 3);                  \
            bf16x8 ah = *(const bf16x8*)&ALds[o];                              \
            bf16x8 al = *(const bf16x8*)&ALds[o + APAD*16];                    \
            _Pragma("unroll")                                                  \
            for (int nf = 0; nf < NFR; ++nf) {                                 \
                acc[mf][nf] = __builtin_amdgcn_mfma_f32_32x32x16_bf16(         \
                    ah, BHC[nf], acc[mf][nf], 0, 0, 0);                        \
                acc[mf][nf] = __builtin_amdgcn_mfma_f32_32x32x16_bf16(         \
                    al, BHC[nf], acc[mf][nf], 0, 0, 0);                        \
                acc[mf][nf] = __builtin_amdgcn_mfma_f32_32x32x16_bf16(         \
                    ah, BLC[nf], acc[mf][nf], 0, 0, 0);                        \
            }                                                                  \
        }                                                                      \
    }

#define GROUPBODY(G, S0h, S0l, S1h, S1l)                                       \
    {                                                                          \
        TAPBODY((G), 0, S0h, S0l, S1h, S1l);                                   \
        TAPBODY((G), 1, S1h, S1l, S0h, S0l);                                   \
        TAPBODY((G), 2, S0h, S0l, S1h, S1l);                                   \
        TAPBODY((G), 3, S1h, S1l, S0h, S0l);                                   \
        TAPBODY((G), 4, S0h, S0l, S1h, S1l);                                   \
        TAPBODY((G), 5, S1h, S1l, S0h, S0l);                                   \
        TAPBODY((G), 6, S0h, S0l, S1h, S1l);                                   \
        TAPBODY((G), 7, S1h, S1l, S0h, S0l);                                   \
        TAPBODY((G), 8, S0h, S0l, S1h, S1l);                                   \
    }

// HARDENED: lgkmcnt(0)+sched_barrier BEFORE the overwrite barrier (r11 race).
#define STAGEWAIT(G)                                                           \
    __builtin_amdgcn_sched_barrier(0);                                         \
    asm volatile("s_waitcnt lgkmcnt(0)" ::: "memory");                         \
    __builtin_amdgcn_sched_barrier(0);                                         \
    __builtin_amdgcn_s_barrier();        /* prior group's reads in regs */     \
    stageA(G);                                                                 \
    __builtin_amdgcn_sched_barrier(0);                                         \
    asm volatile("s_waitcnt vmcnt(0)" ::: "memory");                           \
    __builtin_amdgcn_s_barrier();                                              \
    __builtin_amdgcn_sched_barrier(0);

    LOADB(0, 0, bhX, blX);

#pragma unroll 1
    for (int g = 0; g < NG; g += 2) {
        STAGEWAIT(g)
        GROUPBODY(g,     bhX, blX, bhY, blY);
        STAGEWAIT(g + 1)
        GROUPBODY(g + 1, bhY, blY, bhX, blX);
    }
#undef STAGEWAIT
#undef GROUPBODY
#undef TAPBODY
#undef LOADB
    __syncthreads();

    // ---- fused 1x1 epilogue (compile-time KK, exact r9 structure) ----
    float biasv[NFR];
#pragma unroll
    for (int nf = 0; nf < NFR; ++nf) biasv[nf] = bias1[wnb + nf*32 + l31];
    float w2v[NFR][KK];
#pragma unroll
    for (int nf = 0; nf < NFR; ++nf)
#pragma unroll
        for (int k = 0; k < KK; ++k) w2v[nf][k] = w2[k*256 + wnb + nf*32 + l31];

    float* Lacc = (float*)ALds;               // [4][96][KK] <= 16.9KB
#pragma unroll
    for (int mf = 0; mf < MFR; ++mf) {
#pragma unroll
        for (int r = 0; r < 16; ++r) {
            float v[KK];
#pragma unroll
            for (int k = 0; k < KK; ++k) v[k] = 0.f;
#pragma unroll
            for (int nf = 0; nf < NFR; ++nf) {
                float rr = fmaxf(acc[mf][nf][r] + biasv[nf], 0.f);
#pragma unroll
                for (int k = 0; k < KK; ++k) v[k] += rr * w2v[nf][k];
            }
#pragma unroll
            for (int k = 0; k < KK; ++k) {
                v[k] += __shfl_xor(v[k], 1);
                v[k] += __shfl_xor(v[k], 2);
                v[k] += __shfl_xor(v[k], 4);
                v[k] += __shfl_xor(v[k], 8);
                v[k] += __shfl_xor(v[k], 16);
            }
            if (l31 == 0) {
                int crow = (r & 3) + 8*(r >> 2) + 4*hh2;
                int row96 = mf*32 + crow;
#pragma unroll
                for (int k = 0; k < KK; ++k)
                    Lacc[((size_t)wid*96 + row96)*KK + k] = v[k];
            }
        }
    }
    __syncthreads();
    for (int i = tid; i < 96*KK; i += 256) {
        int row96 = i / KK, k = i - row96*KK;
        float s = b2[k];
#pragma unroll
        for (int w = 0; w < 4; ++w) s += Lacc[((size_t)w*96 + row96)*KK + k];
        dst[((size_t)bidx*KK + k)*HW_ + pimg0 + row96] = s;
    }
}

// ---------------------------------------------------------------------------
// Softmax / mask / NMS-score kernels. L/R heads batched over blockIdx.y.
// ---------------------------------------------------------------------------
__global__ __launch_bounds__(256)
void prob2b_kernel(const float* __restrict__ l2, const float* __restrict__ l3,
                   float* __restrict__ pL, float* __restrict__ pR)
{
    const float* logits = blockIdx.y ? l3 : l2;
    float* p0 = blockIdx.y ? pR : pL;
    int i = blockIdx.x * 256 + threadIdx.x;
    if (i >= B_ * HW_) return;
    int b = i / HW_, pix = i - b * HW_;
    float l0 = logits[(size_t)b * 2 * HW_ + pix];
    float l1 = logits[(size_t)b * 2 * HW_ + HW_ + pix];
    float m = fmaxf(l0, l1);
    float e0 = expf(l0 - m), e1 = expf(l1 - m);
    p0[i] = e0 / (e0 + e1);
}

__global__ __launch_bounds__(256)
void score2b_kernel(const float* __restrict__ pL, const float* __restrict__ pR,
                    float* __restrict__ sL, float* __restrict__ sR)
{
    const float* p = blockIdx.y ? pR : pL;
    float* sc = blockIdx.y ? sR : sL;
    int i = blockIdx.x * 256 + threadIdx.x;
    if (i >= B_ * HW_) return;
    int pix = i % HW_;
    int yy = pix / W_, xx = pix - (pix / W_) * W_;
    float c = p[i];
    bool ok = (c >= EPS_);
    const float* pb = p + (i - pix);
#pragma unroll
    for (int dy = -1; dy <= 1; ++dy)
#pragma unroll
        for (int dx = -1; dx <= 1; ++dx) {
            if (dy == 0 && dx == 0) continue;
            int ny = yy + dy, nx = xx + dx;
            float v = 0.f;
            if (ny >= 0 && ny < H_ && nx >= 0 && nx < W_) v = pb[ny * W_ + nx];
            ok = ok && (c >= v);
        }
    sc[i] = c + (ok ? 1.f : 0.f);
}

__global__ __launch_bounds__(256)
void probobj_kernel(const float* __restrict__ logits, float* __restrict__ pval,
                    int* __restrict__ cstar)
{
    int i = blockIdx.x * 256 + threadIdx.x;
    if (i >= B_ * HW_) return;
    int b = i / HW_, pix = i - b * HW_;
    const float* lb = logits + (size_t)b * 11 * HW_ + pix;
    float l[11];
#pragma unroll
    for (int c2 = 0; c2 < 11; ++c2) l[c2] = lb[(size_t)c2 * HW_];
    float m = l[0];
#pragma unroll
    for (int c2 = 1; c2 < 11; ++c2) m = fmaxf(m, l[c2]);
    float sum = 0.f;
#pragma unroll
    for (int c2 = 0; c2 < 11; ++c2) sum += expf(l[c2] - m);
    int a = 0; float bestl = l[0];
#pragma unroll
    for (int c2 = 1; c2 < 10; ++c2)
        if (l[c2] > bestl) { bestl = l[c2]; a = c2; }
    pval[i] = expf(bestl - m) / sum;
    cstar[i] = a;
}

__global__ __launch_bounds__(256)
void score11_kernel(const float* __restrict__ p, const int* __restrict__ cs,
                    float* __restrict__ sc)
{
    int i = blockIdx.x * 256 + threadIdx.x;
    if (i >= B_ * HW_) return;
    int pix = i % HW_;
    int yy = pix / W_, xx = pix - (pix / W_) * W_;
    float c = p[i];
    int cc = cs[i];
    bool ok = (c >= EPS_);
    int base = i - pix;
#pragma unroll
    for (int dy = -1; dy <= 1; ++dy)
#pragma unroll
        for (int dx = -1; dx <= 1; ++dx) {
            if (dy == 0 && dx == 0) continue;
            int ny = yy + dy, nx = xx + dx;
            float v = 0.f;
            if (ny >= 0 && ny < H_ && nx >= 0 && nx < W_) {
                int n = base + ny * W_ + nx;
                v = (cs[n] == cc) ? p[n] : 0.f;
            }
            ok = ok && (c >= v);
        }
    sc[i] = c + (ok ? 1.f : 0.f);
}

// ---------------------------------------------------------------------------
// top-k by iterative argmax (matches jax.lax.top_k ordering)
// ---------------------------------------------------------------------------
__global__ __launch_bounds__(256)
void topk_kernel(const float* __restrict__ scL, const float* __restrict__ scR,
                 const float* __restrict__ scO, int* __restrict__ idx)
{
    __shared__ float sv[HW_];
    __shared__ float rv[256];
    __shared__ int   ri[256];
    const int h = blockIdx.x, b = blockIdx.y;
    const float* src = (h == 0) ? scL : (h == 1) ? scR : scO;
    const int k = (h == 2) ? 20 : 40;
    const int off = b * NQ_ + ((h == 0) ? 0 : (h == 1) ? 40 : 80);

    for (int t = threadIdx.x; t < HW_; t += 256) sv[t] = src[(size_t)b * HW_ + t];
    __syncthreads();

    for (int kk = 0; kk < k; ++kk) {
        float bestv = -FLT_MAX; int besti = HW_;
        for (int t = threadIdx.x; t < HW_; t += 256) {
            float v = sv[t];
            if (v > bestv) { bestv = v; besti = t; }
        }
        rv[threadIdx.x] = bestv; ri[threadIdx.x] = besti;
        __syncthreads();
        for (int s = 128; s > 0; s >>= 1) {
            if (threadIdx.x < s) {
                float v2 = rv[threadIdx.x + s]; int i2 = ri[threadIdx.x + s];
                if (v2 > rv[threadIdx.x] ||
                    (v2 == rv[threadIdx.x] && i2 < ri[threadIdx.x])) {
                    rv[threadIdx.x] = v2; ri[threadIdx.x] = i2;
                }
            }
            __syncthreads();
        }
        if (threadIdx.x == 0) { idx[off + kk] = ri[0]; sv[ri[0]] = -FLT_MAX; }
        __syncthreads();
    }
}

// ---------------------------------------------------------------------------
// Contact branch tail (unchanged)
// ---------------------------------------------------------------------------
__global__ __launch_bounds__(128)
void pool_kernel(const float* __restrict__ h2, float* __restrict__ pooled)
{
    int bc = blockIdx.x;
    __shared__ float row[96];
    for (int hh = threadIdx.x; hh < 96; hh += 128) {
        const float* p = h2 + (size_t)bc * HW_ + hh * W_;
        float s = 0.f;
        for (int ww = 0; ww < 96; ++ww) s += p[ww];
        row[hh] = s * (1.f / 96.f);
    }
    __syncthreads();
    for (int i = threadIdx.x; i < 778; i += 128) {
        int s0 = (i * 96) / 778;
        int e0 = ((i + 1) * 96 + 777) / 778;
        float s = 0.f;
        for (int t = s0; t < e0; ++t) s += row[t];
        pooled[(size_t)bc * 778 + i] = s / (float)(e0 - s0);
    }
}

__global__ __launch_bounds__(256)
void cm_kernel(const float* __restrict__ pooled, const float* __restrict__ cm_lw,
               const float* __restrict__ cm_lb, float* __restrict__ out5)
{
    const int j = blockIdx.x;
    const float* wr = cm_lw + (size_t)j * 24896;
    float acc[8];
#pragma unroll
    for (int b = 0; b < 8; ++b) acc[b] = 0.f;
    for (int t = threadIdx.x; t < 24896; t += 256) {
        float w = wr[t];
#pragma unroll
        for (int b = 0; b < 8; ++b) acc[b] += w * pooled[(size_t)b * 24896 + t];
    }
    __shared__ float red[8][256];
#pragma unroll
    for (int b = 0; b < 8; ++b) red[b][threadIdx.x] = acc[b];
    __syncthreads();
    for (int s = 128; s > 0; s >>= 1) {
        if (threadIdx.x < s) {
#pragma unroll
            for (int b = 0; b < 8; ++b) red[b][threadIdx.x] += red[b][threadIdx.x + s];
        }
        __syncthreads();
    }
    if (threadIdx.x < 8)
        out5[(size_t)threadIdx.x * 1556 + j] = red[threadIdx.x][0] + cm_lb[j];
}

__global__ __launch_bounds__(256)
void c1d_kernel(const float* __restrict__ cmap, const float* __restrict__ w,
                const float* __restrict__ bias, float* __restrict__ ccmean)
{
    int b = blockIdx.x;
    __shared__ float r[2][778];
    __shared__ float T[2][3];
    for (int t = threadIdx.x; t < 1556; t += 256)
        r[t / 778][t % 778] = cmap[(size_t)b * 1556 + t];
    __syncthreads();
    if (threadIdx.x < 2) {
        int ic = threadIdx.x;
        float s = 0.f;
        for (int i2 = 0; i2 < 778; ++i2) s += r[ic][i2];
        T[ic][0] = s - r[ic][776] - r[ic][777];
        T[ic][1] = s - r[ic][0]   - r[ic][777];
        T[ic][2] = s - r[ic][0]   - r[ic][1];
    }
    __syncthreads();
    int oc = threadIdx.x;
    float a = 0.f;
#pragma unroll
    for (int ic = 0; ic < 2; ++ic)
#pragma unroll
        for (int k = 0; k < 3; ++k)
            a += w[oc * 6 + ic * 3 + k] * T[ic][k];
    ccmean[b * 256 + oc] = a / 776.f + bias[oc];
}

__global__ __launch_bounds__(256)
void feat_kernel(const float* __restrict__ ccmean, const float* __restrict__ q_lw,
                 const float* __restrict__ q_lb, float* __restrict__ feat)
{
    __shared__ float cc[8][256];
    for (int t = threadIdx.x; t < 2048; t += 256) cc[t >> 8][t & 255] = ccmean[t];
    __syncthreads();
    int j = blockIdx.x * 256 + threadIdx.x;
    const float* wr = q_lw + (size_t)j * 256;
    float acc[8];
#pragma unroll
    for (int b = 0; b < 8; ++b) acc[b] = 0.f;
    for (int c = 0; c < 256; ++c) {
        float wv = wr[c];
#pragma unroll
        for (int b = 0; b < 8; ++b) acc[b] += wv * cc[b][c];
    }
    float qb = q_lb[j];
#pragma unroll
    for (int b = 0; b < 8; ++b) feat[(size_t)b * 25600 + j] = acc[b] + qb;
}

__global__ __launch_bounds__(256)
void gather_kernel(const float* __restrict__ x, const float* __restrict__ pos,
                   const float* __restrict__ feat, const int* __restrict__ idx,
                   float* __restrict__ out0, float* __restrict__ out1)
{
    int t = blockIdx.x * 256 + threadIdx.x;
    if (t >= B_ * C_ * NQ_) return;
    int q = t % NQ_;
    int c2 = (t / NQ_) % C_;
    int b = t / (C_ * NQ_);
    int p = idx[b * NQ_ + q];
    out0[t] = x[((size_t)b * C_ + c2) * HW_ + p] + feat[(size_t)b * 25600 + c2 * NQ_ + q];
    out1[t] = pos[(size_t)c2 * HW_ + p];
}

// ---------------------------------------------------------------------------
extern "C" void kernel_launch(void* const* d_in, const int* in_sizes, int n_in,
                              void* d_out, int out_size, void* d_ws, size_t ws_size,
                              hipStream_t stream) {
    const float* x    = (const float*)d_in[0];
    const float* y    = (const float*)d_in[1];
    const float* pos  = (const float*)d_in[2];
    const float* lw1  = (const float*)d_in[3];  const float* lb1 = (const float*)d_in[4];
    const float* lw2  = (const float*)d_in[5];  const float* lb2 = (const float*)d_in[6];
    const float* rw1  = (const float*)d_in[7];  const float* rb1 = (const float*)d_in[8];
    const float* rw2  = (const float*)d_in[9];  const float* rb2 = (const float*)d_in[10];
    const float* ow1  = (const float*)d_in[11]; const float* ob1 = (const float*)d_in[12];
    const float* ow2  = (const float*)d_in[13]; const float* ob2 = (const float*)d_in[14];
    const float* cw1  = (const float*)d_in[15]; const float* cb1 = (const float*)d_in[16];
    const float* cw2  = (const float*)d_in[17]; const float* cb2 = (const float*)d_in[18];
    const float* cmlw = (const float*)d_in[19]; const float* cmlb = (const float*)d_in[20];
    const float* c1dw = (const float*)d_in[21]; const float* c1db = (const float*)d_in[22];
    const float* qlw  = (const float*)d_in[23]; const float* qlb  = (const float*)d_in[24];

    float* out  = (float*)d_out;
    float* out0 = out;                 // topk_proposals [8,256,100]
    float* out1 = out + 204800;        // topk_pos       [8,256,100]
    float* out2 = out + 409600;        // left_logits    [8,2,96,96]
    float* out3 = out + 557056;        // right_logits   [8,2,96,96]
    float* out4 = out + 704512;        // obj_logits     [8,11,96,96]
    float* out5 = out + 1515520;       // contact_map    [8,2,778,1]

    float* ws = (float*)d_ws;
    ushort_t* Rh   = (ushort_t*)(ws);                       // 76880*256 ush
    ushort_t* Rl   = (ushort_t*)(ws + 9840640);
    ushort_t* h1h  = (ushort_t*)(ws + 19681280);            // 76880*64 ush
    ushort_t* h1l  = (ushort_t*)(ws + 22141440);
    float*    h2   = ws + 24601600;                         // 8*32*9216 fp32
    ushort_t* wLh  = (ushort_t*)(ws + 26960896);            // 9*256*256 ush each
    ushort_t* wLl  = (ushort_t*)(ws + 27255808);
    ushort_t* wRh  = (ushort_t*)(ws + 27550720);
    ushort_t* wRl  = (ushort_t*)(ws + 27845632);
    ushort_t* wOh  = (ushort_t*)(ws + 28140544);
    ushort_t* wOl  = (ushort_t*)(ws + 28435456);
    ushort_t* wc1h = (ushort_t*)(ws + 28730368);            // 9*64*256
    ushort_t* wc1l = (ushort_t*)(ws + 28804096);
    ushort_t* wc2h = (ushort_t*)(ws + 28877824);            // 9*32*64
    ushort_t* wc2l = (ushort_t*)(ws + 28887040);
    float* pooled  = ws + 28896256;                         // 8*32*778
    float* ccmean  = ws + 29095424;                         // 2048
    float* feat    = ws + 29097472;                         // 204800
    float* pmapL   = ws + 29302272;                         // 73728
    int*   csmap   = (int*)(ws + 29376000);                 // 73728
    float* scL     = ws + 29449728;
    float* scR     = ws + 29523456;
    float* scO     = ws + 29597184;
    int*   idxb    = (int*)(ws + 29670912);                 // 800
    float* bias1all= ws + 29671712;                         // 768
    float* w2all   = ws + 29672480;                         // 8448
    float* b2all   = ws + 29680928;                         // 48
    float* pmapR   = ws + 29680976;                         // 73728
    float* pmapO   = ws + 29754704;                         // 73728
    (void)in_sizes; (void)n_in; (void)out_size; (void)ws_size; (void)pos;

    // ---- one-time zeroing of padded borders + weight/param packing ----
    zero_border_kernel<<<388, 256, 0, stream>>>(Rh, Rl, 256);
    zero_border_kernel<<<97,  256, 0, stream>>>(h1h, h1l, 64);
    repack_kernel<<<(9*256*256+255)/256, 256, 0, stream>>>(lw1, wLh, wLl, 256, 256);
    repack_kernel<<<(9*256*256+255)/256, 256, 0, stream>>>(rw1, wRh, wRl, 256, 256);
    repack_kernel<<<(9*256*256+255)/256, 256, 0, stream>>>(ow1, wOh, wOl, 256, 256);
    repack_kernel<<<(9*64*256+255)/256,  256, 0, stream>>>(cw1, wc1h, wc1l, 64, 256);
    repack_kernel<<<(9*32*64+255)/256,   256, 0, stream>>>(cw2, wc2h, wc2l, 32, 64);
    pack_heads3_kernel<<<33, 256, 0, stream>>>(lb1, rb1, ob1, lw2, rw2, ow2,
                                               lb2, rb2, ob2, bias1all, w2all, b2all);

    // ---- contact branch (R holds padded yt; freed after conv1) ----
    tsplit_kernel<<<dim3(288, 8, 8), 256, 0, stream>>>(y, Rh, Rl, 256);
    conv_gemm_kernel<3,2,3,1,256,1><<<256, 384, 0, stream>>>(
        Rh, Rl, wc1h, wc1l, cb1, h1h, h1l, nullptr);
    conv_gemm_kernel<3,1,3,1,64,2><<<256, 192, 0, stream>>>(
        h1h, h1l, wc2h, wc2l, cb2, nullptr, nullptr, h2);
    pool_kernel<<<256, 128, 0, stream>>>(h2, pooled);
    cm_kernel<<<1556, 256, 0, stream>>>(pooled, cmlw, cmlb, out5);
    c1d_kernel<<<8, 256, 0, stream>>>(out5, c1dw, c1db, ccmean);
    feat_kernel<<<100, 256, 0, stream>>>(ccmean, qlw, qlb, feat);

    // ---- heads: L+R unified (KK=2, head-major), then O (KK=11) ----
    tsplit_kernel<<<dim3(288, 8, 8), 256, 0, stream>>>(x, Rh, Rl, 256);
    conv_sbt_kernel<2,2><<<1536, 256, 0, stream>>>(
        Rh, Rl, wLh, wLl, wRh, wRl, bias1all, w2all, b2all, out2);
    conv_sbt_kernel<11,1><<<768, 256, 0, stream>>>(
        Rh, Rl, wOh, wOl, wOh, wOl, bias1all + 512, w2all + 2*2816,
        b2all + 22, out4);

    // ---- probs / NMS scores (L/R batched) ----
    prob2b_kernel<<<dim3(288, 2), 256, 0, stream>>>(out2, out3, pmapL, pmapR);
    score2b_kernel<<<dim3(288, 2), 256, 0, stream>>>(pmapL, pmapR, scL, scR);
    probobj_kernel<<<288, 256, 0, stream>>>(out4, pmapO, csmap);
    score11_kernel<<<288, 256, 0, stream>>>(pmapO, csmap, scO);

    // ---- topk + gathers ----
    topk_kernel<<<dim3(3, 8), 256, 0, stream>>>(scL, scR, scO, idxb);
    gather_kernel<<<800, 256, 0, stream>>>(x, pos, feat, idxb, out0, out1);
}

// Round 15
// 1145.853 us; speedup vs baseline: 1.2829x; 1.0013x over previous
//
#include <hip/hip_runtime.h>
#include <float.h>
#include <math.h>

#define B_ 8
#define C_ 256
#define H_ 96
#define W_ 96
#define HW_ 9216
#define NQ_ 100
#define EPS_ 1e-6f
#define PADW_ 98
#define PADIMG_ 9604          // 98*98 padded image
#define PALLOC_ 76880         // 8*9604 + slack rows for A-stage overrun

typedef unsigned short ushort_t;
typedef __attribute__((ext_vector_type(8))) short bf16x8;
typedef __attribute__((ext_vector_type(16))) float f32x16;

typedef __attribute__((address_space(3))) unsigned int as3_u32;
typedef __attribute__((address_space(1))) unsigned int as1_u32;

__device__ __forceinline__ void gl16(const void* g, void* l) {
    __builtin_amdgcn_global_load_lds(
        (const as1_u32*)(unsigned long long)g,
        (as3_u32*)(unsigned int)(unsigned long long)l, 16, 0, 0);
}

__device__ __forceinline__ ushort_t bf16_of(float v) {
    unsigned u = __float_as_uint(v);
    u += 0x7fffu + ((u >> 16) & 1u);
    return (ushort_t)(u >> 16);
}
__device__ __forceinline__ float f_of_bf16(ushort_t h) {
    return __uint_as_float((unsigned)h << 16);
}

// ---------------------------------------------------------------------------
// Zero the 1-px border of each padded image (388 px/img), both splits.
// ---------------------------------------------------------------------------
__global__ __launch_bounds__(256)
void zero_border_kernel(ushort_t* __restrict__ bh, ushort_t* __restrict__ bl, int Cch)
{
    int per = 388 * Cch / 8;
    int id = blockIdx.x * 256 + threadIdx.x;
    if (id >= 8 * per) return;
    int b = id / per, i = id - b * per;
    int pi = (i * 8) / Cch, c8 = (i * 8) % Cch;
    int yy, xx;
    if (pi < 98)      { yy = 0;            xx = pi; }
    else if (pi < 196){ yy = 97;           xx = pi - 98; }
    else if (pi < 292){ yy = pi - 195;     xx = 0; }
    else              { yy = pi - 291;     xx = 97; }
    size_t base = ((size_t)b * PADIMG_ + yy * PADW_ + xx) * Cch + c8;
    *(bf16x8*)&bh[base] = (bf16x8)(short)0;
    *(bf16x8*)&bl[base] = (bf16x8)(short)0;
}

// ---------------------------------------------------------------------------
// Transpose+split into padded layout: in [b][C][96*96] fp32 ->
// oh/ol [b*PADIMG + (y+1)*98 + x+1][C] bf16 hi/lo (interior only)
// ---------------------------------------------------------------------------
__global__ __launch_bounds__(256)
void tsplit_kernel(const float* __restrict__ in, ushort_t* __restrict__ oh,
                   ushort_t* __restrict__ ol, int Cch)
{
    __shared__ float T[32][33];
    const int tx = threadIdx.x & 31, ty = threadIdx.x >> 5;
    const int p0 = blockIdx.x * 32, ci0 = blockIdx.y * 32, b = blockIdx.z;
#pragma unroll
    for (int i = 0; i < 4; ++i)
        T[ty + 8*i][tx] = in[((size_t)b*Cch + ci0 + ty + 8*i)*HW_ + p0 + tx];
    __syncthreads();
    const int y = p0 / 96, x0 = p0 - y * 96;
    const size_t Pp = (size_t)b*PADIMG_ + (size_t)(y + 1)*PADW_ + x0 + 1;
#pragma unroll
    for (int i = 0; i < 4; ++i) {
        float v = T[tx][ty + 8*i];
        ushort_t hi = bf16_of(v);
        float lo = v - f_of_bf16(hi);
        size_t o = (Pp + ty + 8*i)*Cch + ci0 + tx;
        oh[o] = hi;
        ol[o] = bf16_of(lo);
    }
}

// ---------------------------------------------------------------------------
// Weight repack: w [oc][ci][3][3] fp32 -> wh/wl [tap][g][oc][ci16] bf16 hi/lo
// ---------------------------------------------------------------------------
__global__ __launch_bounds__(256)
void repack_kernel(const float* __restrict__ w, ushort_t* __restrict__ wh,
                   ushort_t* __restrict__ wl, int Cout, int Cin)
{
    int id = blockIdx.x*256 + threadIdx.x;
    int tot = 9*Cout*Cin;
    if (id >= tot) return;
    int tap = id / (Cout*Cin);
    int r   = id - tap*(Cout*Cin);
    int g   = r / (Cout*16);
    int r2  = r - g*(Cout*16);
    int oc  = r2 >> 4, cr = r2 & 15;
    int ci  = g*16 + cr;
    float v = w[((size_t)oc*Cin + ci)*9 + tap];
    ushort_t hi = bf16_of(v);
    wh[id] = hi;
    wl[id] = bf16_of(v - f_of_bf16(hi));
}

// ---------------------------------------------------------------------------
// Pack per-head params: bias1all[3][256]; w2all[3][11][256] (zero-padded for
// L/R); b2all[3][11] (zero-padded).
// ---------------------------------------------------------------------------
__global__ __launch_bounds__(256)
void pack_heads3_kernel(const float* lb1, const float* rb1, const float* ob1,
                        const float* lw2, const float* rw2, const float* ow2,
                        const float* lb2, const float* rb2, const float* ob2,
                        float* __restrict__ bias1all, float* __restrict__ w2all,
                        float* __restrict__ b2all)
{
    int i = blockIdx.x * 256 + threadIdx.x;
    if (i < 768) bias1all[i] = (i < 256) ? lb1[i] : (i < 512) ? rb1[i-256] : ob1[i-512];
    if (i < 33) {
        int h = i / 11, k = i - h*11;
        b2all[i] = (h == 0) ? (k < 2 ? lb2[k] : 0.f)
                 : (h == 1) ? (k < 2 ? rb2[k] : 0.f)
                 : ob2[k];
    }
    if (i < 3*11*256) {
        int h = i / 2816, r = i - h*2816;
        int k = r / 256, oc = r - k*256;
        float v = 0.f;
        if (h == 0)      { if (k < 2) v = lw2[k*256 + oc]; }
        else if (h == 1) { if (k < 2) v = rw2[k*256 + oc]; }
        else             v = ow2[k*256 + oc];
        w2all[i] = v;
    }
}

// ---------------------------------------------------------------------------
// Implicit-GEMM conv3x3 (round-6 structure, contact branch only), hardened.
//   MODE 1: bias+relu -> Oth/Otl padded-transposed [P'][COUT] bf16 hi/lo
//   MODE 2: bias+relu -> outf [b][COUT][HW] fp32 (LDS transpose)
// ---------------------------------------------------------------------------
template<int WM, int WN, int MFR, int NFR, int CIN, int MODE>
__global__ __launch_bounds__(WM*WN*64, (WM*WN + 3) / 4)
void conv_gemm_kernel(const ushort_t* __restrict__ Agh, const ushort_t* __restrict__ Agl,
                      const ushort_t* __restrict__ Wgh, const ushort_t* __restrict__ Wgl,
                      const float* __restrict__ bias1,
                      ushort_t* __restrict__ Oth, ushort_t* __restrict__ Otl,
                      float* __restrict__ outf)
{
    constexpr int NW    = WM*WN;
    constexpr int NT    = NW*64;
    constexpr int BM    = WM*MFR*32;      // 288
    constexpr int COUT  = WN*NFR*32;
    constexpr int NG    = CIN/16;
    constexpr int APAD  = 512;
    constexpr int ASZ   = 2*APAD*16;
    constexpr int AROUNDS = 32;
    static_assert(BM == 288, "BM must be 288");

    __shared__ __align__(16) ushort_t ALds[2*ASZ];

    const int tid  = threadIdx.x;
    const int lane = tid & 63;
    const int wid  = __builtin_amdgcn_readfirstlane(tid >> 6);
    const int wm   = wid / WN, wn = wid % WN;
    const int l31  = lane & 31, hh2 = lane >> 5;
    const int wnb  = wn * NFR * 32;

    const int cpx = gridDim.x >> 3;
    const int bid = (blockIdx.x & 7)*cpx + (blockIdx.x >> 3);
    const int bidx = bid >> 5;
    const int br   = bid & 31;
    const size_t S = (size_t)bidx*PADIMG_ + (size_t)(3*br)*PADW_;

    auto stageA = [&](int g, int sel) {
        ushort_t* dst = ALds + sel*ASZ;
#pragma unroll 1
        for (int c = wid; c < AROUNDS; c += NW) {
            int id = c*64 + lane;
            int split = id >> 10;
            int r2 = id & 1023;
            int row = r2 >> 1, slot = r2 & 1;
            int ch = slot ^ ((row >> 2) & 1);
            const ushort_t* src = (split ? Agl : Agh) + (S + row)*CIN + g*16 + ch*8;
            gl16(src, dst + (size_t)c*512);
        }
    };

    f32x16 acc[MFR][NFR];
#pragma unroll
    for (int i = 0; i < MFR; ++i)
#pragma unroll
        for (int j = 0; j < NFR; ++j)
#pragma unroll
            for (int r = 0; r < 16; ++r) acc[i][j][r] = 0.f;

    bf16x8 bh0[NFR], bl0[NFR], bh1[NFR], bl1[NFR], bh2[NFR], bl2[NFR];

#define LOADB(G, T, BH, BL)                                                    \
    {                                                                          \
        _Pragma("unroll")                                                      \
        for (int nf = 0; nf < NFR; ++nf) {                                     \
            size_t o = ((size_t)((T)*NG + (G))*COUT + (wnb + nf*32 + l31))*16  \
                       + hh2*8;                                                \
            BH[nf] = *(const bf16x8*)&Wgh[o];                                  \
            BL[nf] = *(const bf16x8*)&Wgl[o];                                  \
        }                                                                      \
    }

    stageA(0, 0);
    LOADB(0, 0, bh0, bl0);
    LOADB(0, 1, bh1, bl1);
    __builtin_amdgcn_sched_barrier(0);
    asm volatile("s_waitcnt vmcnt(%0)" :: "n"(4*NFR) : "memory");
    __builtin_amdgcn_s_barrier();
    __builtin_amdgcn_sched_barrier(0);

#define TAPBODY(T, BHC, BLC, BHN, BLN)                                         \
    {                                                                          \
        if ((T) <= 6)            LOADB(g,     (T)+2, BHN, BLN)                 \
        else if (g + 1 < NG)     LOADB(g+1,   (T)-7, BHN, BLN)                 \
        const int tapoff = ((T)/3)*PADW_ + ((T) % 3);                          \
        _Pragma("unroll")                                                      \
        for (int mf = 0; mf < MFR; ++mf) {                                     \
            int row = wm*PADW_ + tapoff + mf*32 + l31;                         \
            int o = abase + row*16 + ((hh2 ^ ((row >> 2) & 1)) << 3);          \
            bf16x8 ah = *(const bf16x8*)&ALds[o];                              \
            bf16x8 al = *(const bf16x8*)&ALds[o + APAD*16];                    \
            _Pragma("unroll")                                                  \
            for (int nf = 0; nf < NFR; ++nf) {                                 \
                acc[mf][nf] = __builtin_amdgcn_mfma_f32_32x32x16_bf16(         \
                    ah, BHC[nf], acc[mf][nf], 0, 0, 0);                        \
                acc[mf][nf] = __builtin_amdgcn_mfma_f32_32x32x16_bf16(         \
                    al, BHC[nf], acc[mf][nf], 0, 0, 0);                        \
                acc[mf][nf] = __builtin_amdgcn_mfma_f32_32x32x16_bf16(         \
                    ah, BLC[nf], acc[mf][nf], 0, 0, 0);                        \
            }                                                                  \
        }                                                                      \
    }

#pragma unroll 1
    for (int g = 0; g < NG; ++g) {
        if (g + 1 < NG) stageA(g + 1, (g + 1) & 1);
        const int abase = (g & 1) * ASZ;
        TAPBODY(0, bh0, bl0, bh2, bl2);
        TAPBODY(1, bh1, bl1, bh0, bl0);
        TAPBODY(2, bh2, bl2, bh1, bl1);
        TAPBODY(3, bh0, bl0, bh2, bl2);
        TAPBODY(4, bh1, bl1, bh0, bl0);
        TAPBODY(5, bh2, bl2, bh1, bl1);
        TAPBODY(6, bh0, bl0, bh2, bl2);
        TAPBODY(7, bh1, bl1, bh0, bl0);
        TAPBODY(8, bh2, bl2, bh1, bl1);
        __builtin_amdgcn_sched_barrier(0);
        asm volatile("s_waitcnt lgkmcnt(0)" ::: "memory");   // ds_read data home
        asm volatile("s_waitcnt vmcnt(%0)" :: "n"(4*NFR) : "memory");
        __builtin_amdgcn_s_barrier();
        __builtin_amdgcn_sched_barrier(0);
    }
#undef TAPBODY
#undef LOADB
    __syncthreads();

    float biasv[NFR];
#pragma unroll
    for (int nf = 0; nf < NFR; ++nf) biasv[nf] = bias1[wnb + nf*32 + l31];

    if constexpr (MODE == 1) {
#pragma unroll
        for (int mf = 0; mf < MFR; ++mf)
#pragma unroll
            for (int nf = 0; nf < NFR; ++nf)
#pragma unroll
                for (int r = 0; r < 16; ++r) {
                    float rr = fmaxf(acc[mf][nf][r] + biasv[nf], 0.f);
                    ushort_t hi = bf16_of(rr);
                    float lo = rr - f_of_bf16(hi);
                    int crow = (r & 3) + 8*(r >> 2) + 4*hh2;
                    int xx = mf*32 + crow;
                    size_t Pp = (size_t)bidx*PADIMG_
                              + (size_t)(3*br + wm + 1)*PADW_ + xx + 1;
                    size_t o = Pp*COUT + wnb + nf*32 + l31;
                    Oth[o] = hi;
                    Otl[o] = bf16_of(lo);
                }
    } else {
        float (*T)[BM + 1] = (float(*)[BM + 1])ALds;
#pragma unroll
        for (int mf = 0; mf < MFR; ++mf)
#pragma unroll
            for (int r = 0; r < 16; ++r) {
                float rr = fmaxf(acc[mf][0][r] + biasv[0], 0.f);
                int crow = (r & 3) + 8*(r >> 2) + 4*hh2;
                T[l31][wm*96 + mf*32 + crow] = rr;
            }
        __syncthreads();
        for (int i = tid; i < COUT*BM; i += NT) {
            int c = i / BM, m = i - c*BM;
            outf[((size_t)bidx*COUT + c)*HW_ + br*288 + m] = T[c][m];
        }
    }
}

// ---------------------------------------------------------------------------
// Round-15 head kernel: r14 + DOUBLE-BUFFERED A. stageA(g+1) issued at group
// START (a full group of MFMA covers the latency); group end waits counted
// vmcnt(2*NFR) (tap-8's B register prefetch may stay in flight) + lgkm drain
// (race hardening) + ONE barrier. LDS 2x19456 = 38912B -> 3 blocks/CU fits
// (117KB < 160KB); Occupancy counter verifies co-residency.
// ---------------------------------------------------------------------------
template<int KK, int NH>
__global__ __launch_bounds__(256, 3)
void conv_sbt_kernel(const ushort_t* __restrict__ Agh, const ushort_t* __restrict__ Agl,
                     const ushort_t* __restrict__ w0h, const ushort_t* __restrict__ w0l,
                     const ushort_t* __restrict__ w1h, const ushort_t* __restrict__ w1l,
                     const float* __restrict__ bias1base, const float* __restrict__ w2base,
                     const float* __restrict__ b2base, float* __restrict__ dstbase)
{
    constexpr int NG = 16, APAD = 304, ASZ = 2*APAD*16, AGR = 19, MFR = 3, NFR = 2;
    __shared__ __align__(16) ushort_t ALds[2*ASZ];

    const int tid  = threadIdx.x;
    const int lane = tid & 63;
    const int wid  = __builtin_amdgcn_readfirstlane(tid >> 6);
    const int l31  = lane & 31, hh2 = lane >> 5;
    const int wnb  = wid * 64;                 // wave's 64-channel column base

    // head-major dispatch; per-head bijective XCD swizzle over 768 = 8 x 96.
    const int h    = (NH == 1) ? 0 : (blockIdx.x / 768);
    const int subx = blockIdx.x - h*768;
    const int sub  = (subx & 7)*96 + (subx >> 3);
    const int bidx = sub / 96, prow = sub - bidx*96;
    const int pimg0 = prow * 96;
    const size_t S = (size_t)bidx*PADIMG_ + (size_t)prow*PADW_;

    const ushort_t* Wh = (h == 0) ? w0h : w1h;
    const ushort_t* Wl = (h == 0) ? w0l : w1l;
    const float* bias1 = bias1base + h*256;
    const float* w2    = w2base + (size_t)h*2816;     // [11][256] stride
    const float* b2    = b2base + h*11;
    float* dst = dstbase + (size_t)h*147456;

    auto stageA = [&](int g, int sel) {
        ushort_t* dstl = ALds + sel*ASZ;
#pragma unroll 1
        for (int c = wid; c < AGR; c += 4) {
            int id = c*64 + lane;
            int split = id / (2*APAD);
            int r2 = id % (2*APAD);
            int row = r2 >> 1, slot = r2 & 1;
            int ch = slot ^ ((row >> 2) & 1);     // inverse of read swizzle
            const ushort_t* src = (split ? Agl : Agh) + (S + row)*C_ + g*16 + ch*8;
            gl16(src, dstl + (size_t)c*512);
        }
    };

    f32x16 acc[MFR][NFR];
#pragma unroll
    for (int i = 0; i < MFR; ++i)
#pragma unroll
        for (int j = 0; j < NFR; ++j)
#pragma unroll
            for (int r = 0; r < 16; ++r) acc[i][j][r] = 0.f;

    bf16x8 bhX[NFR], blX[NFR], bhY[NFR], blY[NFR];

#define LOADB(G, T, BH, BL)                                                    \
    {                                                                          \
        _Pragma("unroll")                                                      \
        for (int nf = 0; nf < NFR; ++nf) {                                     \
            size_t o = ((size_t)((T)*NG + (G))*256 + (wnb + nf*32 + l31))*16   \
                       + hh2*8;                                                \
            BH[nf] = *(const bf16x8*)&Wh[o];                                   \
            BL[nf] = *(const bf16x8*)&Wl[o];                                   \
        }                                                                      \
    }

#define TAPBODY(G, T, ABASE, BHC, BLC, BHN, BLN)                               \
    {                                                                          \
        if ((T) < 8)             LOADB((G), (T)+1, BHN, BLN)                   \
        else if ((G) + 1 < NG)   LOADB((G)+1, 0, BHN, BLN)                     \
        const int tapoff = ((T)/3)*PADW_ + ((T) % 3);                          \
        _Pragma("unroll")                                                      \
        for (int mf = 0; mf < MFR; ++mf) {                                     \
            int row = tapoff + mf*32 + l31;                                    \
            int o = (ABASE) + row*16 + ((hh2 ^ ((row >> 2) & 1)) << 3);        \
            bf16x8 ah = *(const bf16x8*)&ALds[o];                              \
            bf16x8 al = *(const bf16x8*)&ALds[o + APAD*16];                    \
            _Pragma("unroll")                                                  \
            for (int nf = 0; nf < NFR; ++nf) {                                 \
                acc[mf][nf] = __builtin_amdgcn_mfma_f32_32x32x16_bf16(         \
                    ah, BHC[nf], acc[mf][nf], 0, 0, 0);                        \
                acc[mf][nf] = __builtin_amdgcn_mfma_f32_32x32x16_bf16(         \
                    al, BHC[nf], acc[mf][nf], 0, 0, 0);                        \
                acc[mf][nf] = __builtin_amdgcn_mfma_f32_32x32x16_bf16(         \
                    ah, BLC[nf], acc[mf][nf], 0, 0, 0);                        \
            }                                                                  \
        }                                                                      \
    }

#define GROUPBODY(G, ABASE, S0h, S0l, S1h, S1l)                                \
    {                                                                          \
        TAPBODY((G), 0, (ABASE), S0h, S0l, S1h, S1l);                          \
        TAPBODY((G), 1, (ABASE), S1h, S1l, S0h, S0l);                          \
        TAPBODY((G), 2, (ABASE), S0h, S0l, S1h, S1l);                          \
        TAPBODY((G), 3, (ABASE), S1h, S1l, S0h, S0l);                          \
        TAPBODY((G), 4, (ABASE), S0h, S0l, S1h, S1l);                          \
        TAPBODY((G), 5, (ABASE), S1h, S1l, S0h, S0l);                          \
        TAPBODY((G), 6, (ABASE), S0h, S0l, S1h, S1l);                          \
        TAPBODY((G), 7, (ABASE), S1h, S1l, S0h, S0l);                          \
        TAPBODY((G), 8, (ABASE), S0h, S0l, S1h, S1l);                          \
    }

// group end: ds_read data home (race class), stage prefetch landed (counted
// vmcnt leaves tap-8's B register prefetch in flight), ONE barrier.
#define GROUPEND                                                               \
    __builtin_amdgcn_sched_barrier(0);                                         \
    asm volatile("s_waitcnt lgkmcnt(0)" ::: "memory");                         \
    asm volatile("s_waitcnt vmcnt(%0)" :: "n"(2*NFR) : "memory");              \
    __builtin_amdgcn_s_barrier();                                              \
    __builtin_amdgcn_sched_barrier(0);

    // prologue: A(0) staged+landed; B(0,0) in X
    stageA(0, 0);
    LOADB(0, 0, bhX, blX);
    __builtin_amdgcn_sched_barrier(0);
    asm volatile("s_waitcnt vmcnt(%0)" :: "n"(2*NFR) : "memory");
    __builtin_amdgcn_s_barrier();
    __builtin_amdgcn_sched_barrier(0);

#pragma unroll 1
    for (int g = 0; g < NG; g += 2) {
        if (g + 1 < NG) stageA(g + 1, 1);
        GROUPBODY(g, 0, bhX, blX, bhY, blY);
        GROUPEND
        if (g + 2 < NG) stageA(g + 2, 0);
        GROUPBODY(g + 1, ASZ, bhY, blY, bhX, blX);
        GROUPEND
    }
#undef GROUPEND
#undef GROUPBODY
#undef TAPBODY
#undef LOADB
    __syncthreads();

    // ---- fused 1x1 epilogue (compile-time KK) ----
    float biasv[NFR];
#pragma unroll
    for (int nf = 0; nf < NFR; ++nf) biasv[nf] = bias1[wnb + nf*32 + l31];
    float w2v[NFR][KK];
#pragma unroll
    for (int nf = 0; nf < NFR; ++nf)
#pragma unroll
        for (int k = 0; k < KK; ++k) w2v[nf][k] = w2[k*256 + wnb + nf*32 + l31];

    float* Lacc = (float*)ALds;               // [4][96][KK] <= 16.9KB
#pragma unroll
    for (int mf = 0; mf < MFR; ++mf) {
#pragma unroll
        for (int r = 0; r < 16; ++r) {
            float v[KK];
#pragma unroll
            for (int k = 0; k < KK; ++k) v[k] = 0.f;
#pragma unroll
            for (int nf = 0; nf < NFR; ++nf) {
                float rr = fmaxf(acc[mf][nf][r] + biasv[nf], 0.f);
#pragma unroll
                for (int k = 0; k < KK; ++k) v[k] += rr * w2v[nf][k];
            }
#pragma unroll
            for (int k = 0; k < KK; ++k) {
                v[k] += __shfl_xor(v[k], 1);
                v[k] += __shfl_xor(v[k], 2);
                v[k] += __shfl_xor(v[k], 4);
                v[k] += __shfl_xor(v[k], 8);
                v[k] += __shfl_xor(v[k], 16);
            }
            if (l31 == 0) {
                int crow = (r & 3) + 8*(r >> 2) + 4*hh2;
                int row96 = mf*32 + crow;
#pragma unroll
                for (int k = 0; k < KK; ++k)
                    Lacc[((size_t)wid*96 + row96)*KK + k] = v[k];
            }
        }
    }
    __syncthreads();
    for (int i = tid; i < 96*KK; i += 256) {
        int row96 = i / KK, k = i - row96*KK;
        float s = b2[k];
#pragma unroll
        for (int w = 0; w < 4; ++w) s += Lacc[((size_t)w*96 + row96)*KK + k];
        dst[((size_t)bidx*KK + k)*HW_ + pimg0 + row96] = s;
    }
}

// ---------------------------------------------------------------------------
// Softmax / mask / NMS-score kernels. L/R heads batched over blockIdx.y.
// ---------------------------------------------------------------------------
__global__ __launch_bounds__(256)
void prob2b_kernel(const float* __restrict__ l2, const float* __restrict__ l3,
                   float* __restrict__ pL, float* __restrict__ pR)
{
    const float* logits = blockIdx.y ? l3 : l2;
    float* p0 = blockIdx.y ? pR : pL;
    int i = blockIdx.x * 256 + threadIdx.x;
    if (i >= B_ * HW_) return;
    int b = i / HW_, pix = i - b * HW_;
    float l0 = logits[(size_t)b * 2 * HW_ + pix];
    float l1 = logits[(size_t)b * 2 * HW_ + HW_ + pix];
    float m = fmaxf(l0, l1);
    float e0 = expf(l0 - m), e1 = expf(l1 - m);
    p0[i] = e0 / (e0 + e1);
}

__global__ __launch_bounds__(256)
void score2b_kernel(const float* __restrict__ pL, const float* __restrict__ pR,
                    float* __restrict__ sL, float* __restrict__ sR)
{
    const float* p = blockIdx.y ? pR : pL;
    float* sc = blockIdx.y ? sR : sL;
    int i = blockIdx.x * 256 + threadIdx.x;
    if (i >= B_ * HW_) return;
    int pix = i % HW_;
    int yy = pix / W_, xx = pix - (pix / W_) * W_;
    float c = p[i];
    bool ok = (c >= EPS_);
    const float* pb = p + (i - pix);
#pragma unroll
    for (int dy = -1; dy <= 1; ++dy)
#pragma unroll
        for (int dx = -1; dx <= 1; ++dx) {
            if (dy == 0 && dx == 0) continue;
            int ny = yy + dy, nx = xx + dx;
            float v = 0.f;
            if (ny >= 0 && ny < H_ && nx >= 0 && nx < W_) v = pb[ny * W_ + nx];
            ok = ok && (c >= v);
        }
    sc[i] = c + (ok ? 1.f : 0.f);
}

__global__ __launch_bounds__(256)
void probobj_kernel(const float* __restrict__ logits, float* __restrict__ pval,
                    int* __restrict__ cstar)
{
    int i = blockIdx.x * 256 + threadIdx.x;
    if (i >= B_ * HW_) return;
    int b = i / HW_, pix = i - b * HW_;
    const float* lb = logits + (size_t)b * 11 * HW_ + pix;
    float l[11];
#pragma unroll
    for (int c2 = 0; c2 < 11; ++c2) l[c2] = lb[(size_t)c2 * HW_];
    float m = l[0];
#pragma unroll
    for (int c2 = 1; c2 < 11; ++c2) m = fmaxf(m, l[c2]);
    float sum = 0.f;
#pragma unroll
    for (int c2 = 0; c2 < 11; ++c2) sum += expf(l[c2] - m);
    int a = 0; float bestl = l[0];
#pragma unroll
    for (int c2 = 1; c2 < 10; ++c2)
        if (l[c2] > bestl) { bestl = l[c2]; a = c2; }
    pval[i] = expf(bestl - m) / sum;
    cstar[i] = a;
}

__global__ __launch_bounds__(256)
void score11_kernel(const float* __restrict__ p, const int* __restrict__ cs,
                    float* __restrict__ sc)
{
    int i = blockIdx.x * 256 + threadIdx.x;
    if (i >= B_ * HW_) return;
    int pix = i % HW_;
    int yy = pix / W_, xx = pix - (pix / W_) * W_;
    float c = p[i];
    int cc = cs[i];
    bool ok = (c >= EPS_);
    int base = i - pix;
#pragma unroll
    for (int dy = -1; dy <= 1; ++dy)
#pragma unroll
        for (int dx = -1; dx <= 1; ++dx) {
            if (dy == 0 && dx == 0) continue;
            int ny = yy + dy, nx = xx + dx;
            float v = 0.f;
            if (ny >= 0 && ny < H_ && nx >= 0 && nx < W_) {
                int n = base + ny * W_ + nx;
                v = (cs[n] == cc) ? p[n] : 0.f;
            }
            ok = ok && (c >= v);
        }
    sc[i] = c + (ok ? 1.f : 0.f);
}

// ---------------------------------------------------------------------------
// top-k by iterative argmax (matches jax.lax.top_k ordering)
// ---------------------------------------------------------------------------
__global__ __launch_bounds__(256)
void topk_kernel(const float* __restrict__ scL, const float* __restrict__ scR,
                 const float* __restrict__ scO, int* __restrict__ idx)
{
    __shared__ float sv[HW_];
    __shared__ float rv[256];
    __shared__ int   ri[256];
    const int h = blockIdx.x, b = blockIdx.y;
    const float* src = (h == 0) ? scL : (h == 1) ? scR : scO;
    const int k = (h == 2) ? 20 : 40;
    const int off = b * NQ_ + ((h == 0) ? 0 : (h == 1) ? 40 : 80);

    for (int t = threadIdx.x; t < HW_; t += 256) sv[t] = src[(size_t)b * HW_ + t];
    __syncthreads();

    for (int kk = 0; kk < k; ++kk) {
        float bestv = -FLT_MAX; int besti = HW_;
        for (int t = threadIdx.x; t < HW_; t += 256) {
            float v = sv[t];
            if (v > bestv) { bestv = v; besti = t; }
        }
        rv[threadIdx.x] = bestv; ri[threadIdx.x] = besti;
        __syncthreads();
        for (int s = 128; s > 0; s >>= 1) {
            if (threadIdx.x < s) {
                float v2 = rv[threadIdx.x + s]; int i2 = ri[threadIdx.x + s];
                if (v2 > rv[threadIdx.x] ||
                    (v2 == rv[threadIdx.x] && i2 < ri[threadIdx.x])) {
                    rv[threadIdx.x] = v2; ri[threadIdx.x] = i2;
                }
            }
            __syncthreads();
        }
        if (threadIdx.x == 0) { idx[off + kk] = ri[0]; sv[ri[0]] = -FLT_MAX; }
        __syncthreads();
    }
}

// ---------------------------------------------------------------------------
// Contact branch tail (unchanged)
// ---------------------------------------------------------------------------
__global__ __launch_bounds__(128)
void pool_kernel(const float* __restrict__ h2, float* __restrict__ pooled)
{
    int bc = blockIdx.x;
    __shared__ float row[96];
    for (int hh = threadIdx.x; hh < 96; hh += 128) {
        const float* p = h2 + (size_t)bc * HW_ + hh * W_;
        float s = 0.f;
        for (int ww = 0; ww < 96; ++ww) s += p[ww];
        row[hh] = s * (1.f / 96.f);
    }
    __syncthreads();
    for (int i = threadIdx.x; i < 778; i += 128) {
        int s0 = (i * 96) / 778;
        int e0 = ((i + 1) * 96 + 777) / 778;
        float s = 0.f;
        for (int t = s0; t < e0; ++t) s += row[t];
        pooled[(size_t)bc * 778 + i] = s / (float)(e0 - s0);
    }
}

__global__ __launch_bounds__(256)
void cm_kernel(const float* __restrict__ pooled, const float* __restrict__ cm_lw,
               const float* __restrict__ cm_lb, float* __restrict__ out5)
{
    const int j = blockIdx.x;
    const float* wr = cm_lw + (size_t)j * 24896;
    float acc[8];
#pragma unroll
    for (int b = 0; b < 8; ++b) acc[b] = 0.f;
    for (int t = threadIdx.x; t < 24896; t += 256) {
        float w = wr[t];
#pragma unroll
        for (int b = 0; b < 8; ++b) acc[b] += w * pooled[(size_t)b * 24896 + t];
    }
    __shared__ float red[8][256];
#pragma unroll
    for (int b = 0; b < 8; ++b) red[b][threadIdx.x] = acc[b];
    __syncthreads();
    for (int s = 128; s > 0; s >>= 1) {
        if (threadIdx.x < s) {
#pragma unroll
            for (int b = 0; b < 8; ++b) red[b][threadIdx.x] += red[b][threadIdx.x + s];
        }
        __syncthreads();
    }
    if (threadIdx.x < 8)
        out5[(size_t)threadIdx.x * 1556 + j] = red[threadIdx.x][0] + cm_lb[j];
}

__global__ __launch_bounds__(256)
void c1d_kernel(const float* __restrict__ cmap, const float* __restrict__ w,
                const float* __restrict__ bias, float* __restrict__ ccmean)
{
    int b = blockIdx.x;
    __shared__ float r[2][778];
    __shared__ float T[2][3];
    for (int t = threadIdx.x; t < 1556; t += 256)
        r[t / 778][t % 778] = cmap[(size_t)b * 1556 + t];
    __syncthreads();
    if (threadIdx.x < 2) {
        int ic = threadIdx.x;
        float s = 0.f;
        for (int i2 = 0; i2 < 778; ++i2) s += r[ic][i2];
        T[ic][0] = s - r[ic][776] - r[ic][777];
        T[ic][1] = s - r[ic][0]   - r[ic][777];
        T[ic][2] = s - r[ic][0]   - r[ic][1];
    }
    __syncthreads();
    int oc = threadIdx.x;
    float a = 0.f;
#pragma unroll
    for (int ic = 0; ic < 2; ++ic)
#pragma unroll
        for (int k = 0; k < 3; ++k)
            a += w[oc * 6 + ic * 3 + k] * T[ic][k];
    ccmean[b * 256 + oc] = a / 776.f + bias[oc];
}

__global__ __launch_bounds__(256)
void feat_kernel(const float* __restrict__ ccmean, const float* __restrict__ q_lw,
                 const float* __restrict__ q_lb, float* __restrict__ feat)
{
    __shared__ float cc[8][256];
    for (int t = threadIdx.x; t < 2048; t += 256) cc[t >> 8][t & 255] = ccmean[t];
    __syncthreads();
    int j = blockIdx.x * 256 + threadIdx.x;
    const float* wr = q_lw + (size_t)j * 256;
    float acc[8];
#pragma unroll
    for (int b = 0; b < 8; ++b) acc[b] = 0.f;
    for (int c = 0; c < 256; ++c) {
        float wv = wr[c];
#pragma unroll
        for (int b = 0; b < 8; ++b) acc[b] += wv * cc[b][c];
    }
    float qb = q_lb[j];
#pragma unroll
    for (int b = 0; b < 8; ++b) feat[(size_t)b * 25600 + j] = acc[b] + qb;
}

__global__ __launch_bounds__(256)
void gather_kernel(const float* __restrict__ x, const float* __restrict__ pos,
                   const float* __restrict__ feat, const int* __restrict__ idx,
                   float* __restrict__ out0, float* __restrict__ out1)
{
    int t = blockIdx.x * 256 + threadIdx.x;
    if (t >= B_ * C_ * NQ_) return;
    int q = t % NQ_;
    int c2 = (t / NQ_) % C_;
    int b = t / (C_ * NQ_);
    int p = idx[b * NQ_ + q];
    out0[t] = x[((size_t)b * C_ + c2) * HW_ + p] + feat[(size_t)b * 25600 + c2 * NQ_ + q];
    out1[t] = pos[(size_t)c2 * HW_ + p];
}

// ---------------------------------------------------------------------------
extern "C" void kernel_launch(void* const* d_in, const int* in_sizes, int n_in,
                              void* d_out, int out_size, void* d_ws, size_t ws_size,
                              hipStream_t stream) {
    const float* x    = (const float*)d_in[0];
    const float* y    = (const float*)d_in[1];
    const float* pos  = (const float*)d_in[2];
    const float* lw1  = (const float*)d_in[3];  const float* lb1 = (const float*)d_in[4];
    const float* lw2  = (const float*)d_in[5];  const float* lb2 = (const float*)d_in[6];
    const float* rw1  = (const float*)d_in[7];  const float* rb1 = (const float*)d_in[8];
    const float* rw2  = (const float*)d_in[9];  const float* rb2 = (const float*)d_in[10];
    const float* ow1  = (const float*)d_in[11]; const float* ob1 = (const float*)d_in[12];
    const float* ow2  = (const float*)d_in[13]; const float* ob2 = (const float*)d_in[14];
    const float* cw1  = (const float*)d_in[15]; const float* cb1 = (const float*)d_in[16];
    const float* cw2  = (const float*)d_in[17]; const float* cb2 = (const float*)d_in[18];
    const float* cmlw = (const float*)d_in[19]; const float* cmlb = (const float*)d_in[20];
    const float* c1dw = (const float*)d_in[21]; const float* c1db = (const float*)d_in[22];
    const float* qlw  = (const float*)d_in[23]; const float* qlb  = (const float*)d_in[24];

    float* out  = (float*)d_out;
    float* out0 = out;                 // topk_proposals [8,256,100]
    float* out1 = out + 204800;        // topk_pos       [8,256,100]
    float* out2 = out + 409600;        // left_logits    [8,2,96,96]
    float* out3 = out + 557056;        // right_logits   [8,2,96,96]
    float* out4 = out + 704512;        // obj_logits     [8,11,96,96]
    float* out5 = out + 1515520;       // contact_map    [8,2,778,1]

    float* ws = (float*)d_ws;
    ushort_t* Rh   = (ushort_t*)(ws);                       // 76880*256 ush
    ushort_t* Rl   = (ushort_t*)(ws + 9840640);
    ushort_t* h1h  = (ushort_t*)(ws + 19681280);            // 76880*64 ush
    ushort_t* h1l  = (ushort_t*)(ws + 22141440);
    float*    h2   = ws + 24601600;                         // 8*32*9216 fp32
    ushort_t* wLh  = (ushort_t*)(ws + 26960896);            // 9*256*256 ush each
    ushort_t* wLl  = (ushort_t*)(ws + 27255808);
    ushort_t* wRh  = (ushort_t*)(ws + 27550720);
    ushort_t* wRl  = (ushort_t*)(ws + 27845632);
    ushort_t* wOh  = (ushort_t*)(ws + 28140544);
    ushort_t* wOl  = (ushort_t*)(ws + 28435456);
    ushort_t* wc1h = (ushort_t*)(ws + 28730368);            // 9*64*256
    ushort_t* wc1l = (ushort_t*)(ws + 28804096);
    ushort_t* wc2h = (ushort_t*)(ws + 28877824);            // 9*32*64
    ushort_t* wc2l = (ushort_t*)(ws + 28887040);
    float* pooled  = ws + 28896256;                         // 8*32*778
    float* ccmean  = ws + 29095424;                         // 2048
    float* feat    = ws + 29097472;                         // 204800
    float* pmapL   = ws + 29302272;                         // 73728
    int*   csmap   = (int*)(ws + 29376000);                 // 73728
    float* scL     = ws + 29449728;
    float* scR     = ws + 29523456;
    float* scO     = ws + 29597184;
    int*   idxb    = (int*)(ws + 29670912);                 // 800
    float* bias1all= ws + 29671712;                         // 768
    float* w2all   = ws + 29672480;                         // 8448
    float* b2all   = ws + 29680928;                         // 48
    float* pmapR   = ws + 29680976;                         // 73728
    float* pmapO   = ws + 29754704;                         // 73728
    (void)in_sizes; (void)n_in; (void)out_size; (void)ws_size; (void)pos;

    // ---- one-time zeroing of padded borders + weight/param packing ----
    zero_border_kernel<<<388, 256, 0, stream>>>(Rh, Rl, 256);
    zero_border_kernel<<<97,  256, 0, stream>>>(h1h, h1l, 64);
    repack_kernel<<<(9*256*256+255)/256, 256, 0, stream>>>(lw1, wLh, wLl, 256, 256);
    repack_kernel<<<(9*256*256+255)/256, 256, 0, stream>>>(rw1, wRh, wRl, 256, 256);
    repack_kernel<<<(9*256*256+255)/256, 256, 0, stream>>>(ow1, wOh, wOl, 256, 256);
    repack_kernel<<<(9*64*256+255)/256,  256, 0, stream>>>(cw1, wc1h, wc1l, 64, 256);
    repack_kernel<<<(9*32*64+255)/256,   256, 0, stream>>>(cw2, wc2h, wc2l, 32, 64);
    pack_heads3_kernel<<<33, 256, 0, stream>>>(lb1, rb1, ob1, lw2, rw2, ow2,
                                               lb2, rb2, ob2, bias1all, w2all, b2all);

    // ---- contact branch (R holds padded yt; freed after conv1) ----
    tsplit_kernel<<<dim3(288, 8, 8), 256, 0, stream>>>(y, Rh, Rl, 256);
    conv_gemm_kernel<3,2,3,1,256,1><<<256, 384, 0, stream>>>(
        Rh, Rl, wc1h, wc1l, cb1, h1h, h1l, nullptr);
    conv_gemm_kernel<3,1,3,1,64,2><<<256, 192, 0, stream>>>(
        h1h, h1l, wc2h, wc2l, cb2, nullptr, nullptr, h2);
    pool_kernel<<<256, 128, 0, stream>>>(h2, pooled);
    cm_kernel<<<1556, 256, 0, stream>>>(pooled, cmlw, cmlb, out5);
    c1d_kernel<<<8, 256, 0, stream>>>(out5, c1dw, c1db, ccmean);
    feat_kernel<<<100, 256, 0, stream>>>(ccmean, qlw, qlb, feat);

    // ---- heads: L+R unified (KK=2, head-major), then O (KK=11) ----
    tsplit_kernel<<<dim3(288, 8, 8), 256, 0, stream>>>(x, Rh, Rl, 256);
    conv_sbt_kernel<2,2><<<1536, 256, 0, stream>>>(
        Rh, Rl, wLh, wLl, wRh, wRl, bias1all, w2all, b2all, out2);
    conv_sbt_kernel<11,1><<<768, 256, 0, stream>>>(
        Rh, Rl, wOh, wOl, wOh, wOl, bias1all + 512, w2all + 2*2816,
        b2all + 22, out4);

    // ---- probs / NMS scores (L/R batched) ----
    prob2b_kernel<<<dim3(288, 2), 256, 0, stream>>>(out2, out3, pmapL, pmapR);
    score2b_kernel<<<dim3(288, 2), 256, 0, stream>>>(pmapL, pmapR, scL, scR);
    probobj_kernel<<<288, 256, 0, stream>>>(out4, pmapO, csmap);
    score11_kernel<<<288, 256, 0, stream>>>(pmapO, csmap, scO);

    // ---- topk + gathers ----
    topk_kernel<<<dim3(3, 8), 256, 0, stream>>>(scL, scR, scO, idxb);
    gather_kernel<<<800, 256, 0, stream>>>(x, pos, feat, idxb, out0, out1);
}

// Round 16
// 1133.951 us; speedup vs baseline: 1.2964x; 1.0105x over previous
//
#include <hip/hip_runtime.h>
#include <float.h>
#include <math.h>

#define B_ 8
#define C_ 256
#define H_ 96
#define W_ 96
#define HW_ 9216
#define NQ_ 100
#define EPS_ 1e-6f
#define PADW_ 98
#define PADIMG_ 9604          // 98*98 padded image
#define PALLOC_ 76880         // 8*9604 + slack rows for A-stage overrun

typedef unsigned short ushort_t;
typedef __attribute__((ext_vector_type(8))) short bf16x8;
typedef __attribute__((ext_vector_type(16))) float f32x16;

typedef __attribute__((address_space(3))) unsigned int as3_u32;
typedef __attribute__((address_space(1))) unsigned int as1_u32;

__device__ __forceinline__ void gl16(const void* g, void* l) {
    __builtin_amdgcn_global_load_lds(
        (const as1_u32*)(unsigned long long)g,
        (as3_u32*)(unsigned int)(unsigned long long)l, 16, 0, 0);
}

__device__ __forceinline__ ushort_t bf16_of(float v) {
    unsigned u = __float_as_uint(v);
    u += 0x7fffu + ((u >> 16) & 1u);
    return (ushort_t)(u >> 16);
}
__device__ __forceinline__ float f_of_bf16(ushort_t h) {
    return __uint_as_float((unsigned)h << 16);
}

// ---------------------------------------------------------------------------
// Zero the 1-px border of both padded images (y-dispatch: 0=R/256ch, 1=h1/64ch)
// ---------------------------------------------------------------------------
__device__ __forceinline__ void zb_body(ushort_t* bh, ushort_t* bl, int Cch, int id)
{
    int per = 388 * Cch / 8;
    if (id >= 8 * per) return;
    int b = id / per, i = id - b * per;
    int pi = (i * 8) / Cch, c8 = (i * 8) % Cch;
    int yy, xx;
    if (pi < 98)      { yy = 0;            xx = pi; }
    else if (pi < 196){ yy = 97;           xx = pi - 98; }
    else if (pi < 292){ yy = pi - 195;     xx = 0; }
    else              { yy = pi - 291;     xx = 97; }
    size_t base = ((size_t)b * PADIMG_ + yy * PADW_ + xx) * Cch + c8;
    *(bf16x8*)&bh[base] = (bf16x8)(short)0;
    *(bf16x8*)&bl[base] = (bf16x8)(short)0;
}

__global__ __launch_bounds__(256)
void zero_border2_kernel(ushort_t* __restrict__ bh0, ushort_t* __restrict__ bl0,
                         ushort_t* __restrict__ bh1, ushort_t* __restrict__ bl1)
{
    int id = blockIdx.x * 256 + threadIdx.x;
    if (blockIdx.y == 0) zb_body(bh0, bl0, 256, id);
    else                 zb_body(bh1, bl1, 64, id);
}

// ---------------------------------------------------------------------------
// Transpose+split into padded layout: in [b][C][96*96] fp32 ->
// oh/ol [b*PADIMG + (y+1)*98 + x+1][C] bf16 hi/lo (interior only)
// ---------------------------------------------------------------------------
__global__ __launch_bounds__(256)
void tsplit_kernel(const float* __restrict__ in, ushort_t* __restrict__ oh,
                   ushort_t* __restrict__ ol, int Cch)
{
    __shared__ float T[32][33];
    const int tx = threadIdx.x & 31, ty = threadIdx.x >> 5;
    const int p0 = blockIdx.x * 32, ci0 = blockIdx.y * 32, b = blockIdx.z;
#pragma unroll
    for (int i = 0; i < 4; ++i)
        T[ty + 8*i][tx] = in[((size_t)b*Cch + ci0 + ty + 8*i)*HW_ + p0 + tx];
    __syncthreads();
    const int y = p0 / 96, x0 = p0 - y * 96;
    const size_t Pp = (size_t)b*PADIMG_ + (size_t)(y + 1)*PADW_ + x0 + 1;
#pragma unroll
    for (int i = 0; i < 4; ++i) {
        float v = T[tx][ty + 8*i];
        ushort_t hi = bf16_of(v);
        float lo = v - f_of_bf16(hi);
        size_t o = (Pp + ty + 8*i)*Cch + ci0 + tx;
        oh[o] = hi;
        ol[o] = bf16_of(lo);
    }
}

// ---------------------------------------------------------------------------
// Weight repack: w [oc][ci][3][3] fp32 -> wh/wl [tap][g][oc][ci16] bf16 hi/lo
// ---------------------------------------------------------------------------
__device__ __forceinline__ void repack_body(const float* w, ushort_t* wh,
                                            ushort_t* wl, int Cout, int Cin, int id)
{
    int tot = 9*Cout*Cin;
    if (id >= tot) return;
    int tap = id / (Cout*Cin);
    int r   = id - tap*(Cout*Cin);
    int g   = r / (Cout*16);
    int r2  = r - g*(Cout*16);
    int oc  = r2 >> 4, cr = r2 & 15;
    int ci  = g*16 + cr;
    float v = w[((size_t)oc*Cin + ci)*9 + tap];
    ushort_t hi = bf16_of(v);
    wh[id] = hi;
    wl[id] = bf16_of(v - f_of_bf16(hi));
}

__global__ __launch_bounds__(256)
void repack_kernel(const float* __restrict__ w, ushort_t* __restrict__ wh,
                   ushort_t* __restrict__ wl, int Cout, int Cin)
{
    repack_body(w, wh, wl, Cout, Cin, blockIdx.x*256 + threadIdx.x);
}

// three 256x256 head repacks in one launch (blockIdx.y picks the head)
__global__ __launch_bounds__(256)
void repack3_kernel(const float* __restrict__ wL, const float* __restrict__ wR,
                    const float* __restrict__ wO,
                    ushort_t* __restrict__ wLh, ushort_t* __restrict__ wLl,
                    ushort_t* __restrict__ wRh, ushort_t* __restrict__ wRl,
                    ushort_t* __restrict__ wOh, ushort_t* __restrict__ wOl)
{
    int id = blockIdx.x*256 + threadIdx.x;
    if (blockIdx.y == 0)      repack_body(wL, wLh, wLl, 256, 256, id);
    else if (blockIdx.y == 1) repack_body(wR, wRh, wRl, 256, 256, id);
    else                      repack_body(wO, wOh, wOl, 256, 256, id);
}

// ---------------------------------------------------------------------------
// Pack per-head params: bias1all[3][256]; w2all[3][11][256] (zero-padded for
// L/R); b2all[3][11] (zero-padded).
// ---------------------------------------------------------------------------
__global__ __launch_bounds__(256)
void pack_heads3_kernel(const float* lb1, const float* rb1, const float* ob1,
                        const float* lw2, const float* rw2, const float* ow2,
                        const float* lb2, const float* rb2, const float* ob2,
                        float* __restrict__ bias1all, float* __restrict__ w2all,
                        float* __restrict__ b2all)
{
    int i = blockIdx.x * 256 + threadIdx.x;
    if (i < 768) bias1all[i] = (i < 256) ? lb1[i] : (i < 512) ? rb1[i-256] : ob1[i-512];
    if (i < 33) {
        int h = i / 11, k = i - h*11;
        b2all[i] = (h == 0) ? (k < 2 ? lb2[k] : 0.f)
                 : (h == 1) ? (k < 2 ? rb2[k] : 0.f)
                 : ob2[k];
    }
    if (i < 3*11*256) {
        int h = i / 2816, r = i - h*2816;
        int k = r / 256, oc = r - k*256;
        float v = 0.f;
        if (h == 0)      { if (k < 2) v = lw2[k*256 + oc]; }
        else if (h == 1) { if (k < 2) v = rw2[k*256 + oc]; }
        else             v = ow2[k*256 + oc];
        w2all[i] = v;
    }
}

// ---------------------------------------------------------------------------
// Implicit-GEMM conv3x3 (round-6 structure, contact branch only), hardened.
//   MODE 1: bias+relu -> Oth/Otl padded-transposed [P'][COUT] bf16 hi/lo
//   MODE 2: bias+relu -> outf [b][COUT][HW] fp32 (LDS transpose)
// ---------------------------------------------------------------------------
template<int WM, int WN, int MFR, int NFR, int CIN, int MODE>
__global__ __launch_bounds__(WM*WN*64, (WM*WN + 3) / 4)
void conv_gemm_kernel(const ushort_t* __restrict__ Agh, const ushort_t* __restrict__ Agl,
                      const ushort_t* __restrict__ Wgh, const ushort_t* __restrict__ Wgl,
                      const float* __restrict__ bias1,
                      ushort_t* __restrict__ Oth, ushort_t* __restrict__ Otl,
                      float* __restrict__ outf)
{
    constexpr int NW    = WM*WN;
    constexpr int NT    = NW*64;
    constexpr int BM    = WM*MFR*32;      // 288
    constexpr int COUT  = WN*NFR*32;
    constexpr int NG    = CIN/16;
    constexpr int APAD  = 512;
    constexpr int ASZ   = 2*APAD*16;
    constexpr int AROUNDS = 32;
    static_assert(BM == 288, "BM must be 288");

    __shared__ __align__(16) ushort_t ALds[2*ASZ];

    const int tid  = threadIdx.x;
    const int lane = tid & 63;
    const int wid  = __builtin_amdgcn_readfirstlane(tid >> 6);
    const int wm   = wid / WN, wn = wid % WN;
    const int l31  = lane & 31, hh2 = lane >> 5;
    const int wnb  = wn * NFR * 32;

    const int cpx = gridDim.x >> 3;
    const int bid = (blockIdx.x & 7)*cpx + (blockIdx.x >> 3);
    const int bidx = bid >> 5;
    const int br   = bid & 31;
    const size_t S = (size_t)bidx*PADIMG_ + (size_t)(3*br)*PADW_;

    auto stageA = [&](int g, int sel) {
        ushort_t* dst = ALds + sel*ASZ;
#pragma unroll 1
        for (int c = wid; c < AROUNDS; c += NW) {
            int id = c*64 + lane;
            int split = id >> 10;
            int r2 = id & 1023;
            int row = r2 >> 1, slot = r2 & 1;
            int ch = slot ^ ((row >> 2) & 1);
            const ushort_t* src = (split ? Agl : Agh) + (S + row)*CIN + g*16 + ch*8;
            gl16(src, dst + (size_t)c*512);
        }
    };

    f32x16 acc[MFR][NFR];
#pragma unroll
    for (int i = 0; i < MFR; ++i)
#pragma unroll
        for (int j = 0; j < NFR; ++j)
#pragma unroll
            for (int r = 0; r < 16; ++r) acc[i][j][r] = 0.f;

    bf16x8 bh0[NFR], bl0[NFR], bh1[NFR], bl1[NFR], bh2[NFR], bl2[NFR];

#define LOADB(G, T, BH, BL)                                                    \
    {                                                                          \
        _Pragma("unroll")                                                      \
        for (int nf = 0; nf < NFR; ++nf) {                                     \
            size_t o = ((size_t)((T)*NG + (G))*COUT + (wnb + nf*32 + l31))*16  \
                       + hh2*8;                                                \
            BH[nf] = *(const bf16x8*)&Wgh[o];                                  \
            BL[nf] = *(const bf16x8*)&Wgl[o];                                  \
        }                                                                      \
    }

    stageA(0, 0);
    LOADB(0, 0, bh0, bl0);
    LOADB(0, 1, bh1, bl1);
    __builtin_amdgcn_sched_barrier(0);
    asm volatile("s_waitcnt vmcnt(%0)" :: "n"(4*NFR) : "memory");
    __builtin_amdgcn_s_barrier();
    __builtin_amdgcn_sched_barrier(0);

#define TAPBODY(T, BHC, BLC, BHN, BLN)                                         \
    {                                                                          \
        if ((T) <= 6)            LOADB(g,     (T)+2, BHN, BLN)                 \
        else if (g + 1 < NG)     LOADB(g+1,   (T)-7, BHN, BLN)                 \
        const int tapoff = ((T)/3)*PADW_ + ((T) % 3);                          \
        _Pragma("unroll")                                                      \
        for (int mf = 0; mf < MFR; ++mf) {                                     \
            int row = wm*PADW_ + tapoff + mf*32 + l31;                         \
            int o = abase + row*16 + ((hh2 ^ ((row >> 2) & 1)) << 3);          \
            bf16x8 ah = *(const bf16x8*)&ALds[o];                              \
            bf16x8 al = *(const bf16x8*)&ALds[o + APAD*16];                    \
            _Pragma("unroll")                                                  \
            for (int nf = 0; nf < NFR; ++nf) {                                 \
                acc[mf][nf] = __builtin_amdgcn_mfma_f32_32x32x16_bf16(         \
                    ah, BHC[nf], acc[mf][nf], 0, 0, 0);                        \
                acc[mf][nf] = __builtin_amdgcn_mfma_f32_32x32x16_bf16(         \
                    al, BHC[nf], acc[mf][nf], 0, 0, 0);                        \
                acc[mf][nf] = __builtin_amdgcn_mfma_f32_32x32x16_bf16(         \
                    ah, BLC[nf], acc[mf][nf], 0, 0, 0);                        \
            }                                                                  \
        }                                                                      \
    }

#pragma unroll 1
    for (int g = 0; g < NG; ++g) {
        if (g + 1 < NG) stageA(g + 1, (g + 1) & 1);
        const int abase = (g & 1) * ASZ;
        TAPBODY(0, bh0, bl0, bh2, bl2);
        TAPBODY(1, bh1, bl1, bh0, bl0);
        TAPBODY(2, bh2, bl2, bh1, bl1);
        TAPBODY(3, bh0, bl0, bh2, bl2);
        TAPBODY(4, bh1, bl1, bh0, bl0);
        TAPBODY(5, bh2, bl2, bh1, bl1);
        TAPBODY(6, bh0, bl0, bh2, bl2);
        TAPBODY(7, bh1, bl1, bh0, bl0);
        TAPBODY(8, bh2, bl2, bh1, bl1);
        __builtin_amdgcn_sched_barrier(0);
        asm volatile("s_waitcnt lgkmcnt(0)" ::: "memory");   // ds_read data home
        asm volatile("s_waitcnt vmcnt(%0)" :: "n"(4*NFR) : "memory");
        __builtin_amdgcn_s_barrier();
        __builtin_amdgcn_sched_barrier(0);
    }
#undef TAPBODY
#undef LOADB
    __syncthreads();

    float biasv[NFR];
#pragma unroll
    for (int nf = 0; nf < NFR; ++nf) biasv[nf] = bias1[wnb + nf*32 + l31];

    if constexpr (MODE == 1) {
#pragma unroll
        for (int mf = 0; mf < MFR; ++mf)
#pragma unroll
            for (int nf = 0; nf < NFR; ++nf)
#pragma unroll
                for (int r = 0; r < 16; ++r) {
                    float rr = fmaxf(acc[mf][nf][r] + biasv[nf], 0.f);
                    ushort_t hi = bf16_of(rr);
                    float lo = rr - f_of_bf16(hi);
                    int crow = (r & 3) + 8*(r >> 2) + 4*hh2;
                    int xx = mf*32 + crow;
                    size_t Pp = (size_t)bidx*PADIMG_
                              + (size_t)(3*br + wm + 1)*PADW_ + xx + 1;
                    size_t o = Pp*COUT + wnb + nf*32 + l31;
                    Oth[o] = hi;
                    Otl[o] = bf16_of(lo);
                }
    } else {
        float (*T)[BM + 1] = (float(*)[BM + 1])ALds;
#pragma unroll
        for (int mf = 0; mf < MFR; ++mf)
#pragma unroll
            for (int r = 0; r < 16; ++r) {
                float rr = fmaxf(acc[mf][0][r] + biasv[0], 0.f);
                int crow = (r & 3) + 8*(r >> 2) + 4*hh2;
                T[l31][wm*96 + mf*32 + crow] = rr;
            }
        __syncthreads();
        for (int i = tid; i < COUT*BM; i += NT) {
            int c = i / BM, m = i - c*BM;
            outf[((size_t)bidx*COUT + c)*HW_ + br*288 + m] = T[c][m];
        }
    }
}

// ---------------------------------------------------------------------------
// Round-15 head kernel (unchanged, verified): double-buffered A, depth-1 X/Y
// B prefetch, compile-time KK, race-hardened group end, head-major dispatch.
// ---------------------------------------------------------------------------
template<int KK, int NH>
__global__ __launch_bounds__(256, 3)
void conv_sbt_kernel(const ushort_t* __restrict__ Agh, const ushort_t* __restrict__ Agl,
                     const ushort_t* __restrict__ w0h, const ushort_t* __restrict__ w0l,
                     const ushort_t* __restrict__ w1h, const ushort_t* __restrict__ w1l,
                     const float* __restrict__ bias1base, const float* __restrict__ w2base,
                     const float* __restrict__ b2base, float* __restrict__ dstbase)
{
    constexpr int NG = 16, APAD = 304, ASZ = 2*APAD*16, AGR = 19, MFR = 3, NFR = 2;
    __shared__ __align__(16) ushort_t ALds[2*ASZ];

    const int tid  = threadIdx.x;
    const int lane = tid & 63;
    const int wid  = __builtin_amdgcn_readfirstlane(tid >> 6);
    const int l31  = lane & 31, hh2 = lane >> 5;
    const int wnb  = wid * 64;                 // wave's 64-channel column base

    const int h    = (NH == 1) ? 0 : (blockIdx.x / 768);
    const int subx = blockIdx.x - h*768;
    const int sub  = (subx & 7)*96 + (subx >> 3);
    const int bidx = sub / 96, prow = sub - bidx*96;
    const int pimg0 = prow * 96;
    const size_t S = (size_t)bidx*PADIMG_ + (size_t)prow*PADW_;

    const ushort_t* Wh = (h == 0) ? w0h : w1h;
    const ushort_t* Wl = (h == 0) ? w0l : w1l;
    const float* bias1 = bias1base + h*256;
    const float* w2    = w2base + (size_t)h*2816;
    const float* b2    = b2base + h*11;
    float* dst = dstbase + (size_t)h*147456;

    auto stageA = [&](int g, int sel) {
        ushort_t* dstl = ALds + sel*ASZ;
#pragma unroll 1
        for (int c = wid; c < AGR; c += 4) {
            int id = c*64 + lane;
            int split = id / (2*APAD);
            int r2 = id % (2*APAD);
            int row = r2 >> 1, slot = r2 & 1;
            int ch = slot ^ ((row >> 2) & 1);
            const ushort_t* src = (split ? Agl : Agh) + (S + row)*C_ + g*16 + ch*8;
            gl16(src, dstl + (size_t)c*512);
        }
    };

    f32x16 acc[MFR][NFR];
#pragma unroll
    for (int i = 0; i < MFR; ++i)
#pragma unroll
        for (int j = 0; j < NFR; ++j)
#pragma unroll
            for (int r = 0; r < 16; ++r) acc[i][j][r] = 0.f;

    bf16x8 bhX[NFR], blX[NFR], bhY[NFR], blY[NFR];

#define LOADB(G, T, BH, BL)                                                    \
    {                                                                          \
        _Pragma("unroll")                                                      \
        for (int nf = 0; nf < NFR; ++nf) {                                     \
            size_t o = ((size_t)((T)*NG + (G))*256 + (wnb + nf*32 + l31))*16   \
                       + hh2*8;                                                \
            BH[nf] = *(const bf16x8*)&Wh[o];                                   \
            BL[nf] = *(const bf16x8*)&Wl[o];                                   \
        }                                                                      \
    }

#define TAPBODY(G, T, ABASE, BHC, BLC, BHN, BLN)                               \
    {                                                                          \
        if ((T) < 8)             LOADB((G), (T)+1, BHN, BLN)                   \
        else if ((G) + 1 < NG)   LOADB((G)+1, 0, BHN, BLN)                     \
        const int tapoff = ((T)/3)*PADW_ + ((T) % 3);                          \
        _Pragma("unroll")                                                      \
        for (int mf = 0; mf < MFR; ++mf) {                                     \
            int row = tapoff + mf*32 + l31;                                    \
            int o = (ABASE) + row*16 + ((hh2 ^ ((row >> 2) & 1)) << 3);        \
            bf16x8 ah = *(const bf16x8*)&ALds[o];                              \
            bf16x8 al = *(const bf16x8*)&ALds[o + APAD*16];                    \
            _Pragma("unroll")                                                  \
            for (int nf = 0; nf < NFR; ++nf) {                                 \
                acc[mf][nf] = __builtin_amdgcn_mfma_f32_32x32x16_bf16(         \
                    ah, BHC[nf], acc[mf][nf], 0, 0, 0);                        \
                acc[mf][nf] = __builtin_amdgcn_mfma_f32_32x32x16_bf16(         \
                    al, BHC[nf], acc[mf][nf], 0, 0, 0);                        \
                acc[mf][nf] = __builtin_amdgcn_mfma_f32_32x32x16_bf16(         \
                    ah, BLC[nf], acc[mf][nf], 0, 0, 0);                        \
            }                                                                  \
        }                                                                      \
    }

#define GROUPBODY(G, ABASE, S0h, S0l, S1h, S1l)                                \
    {                                                                          \
        TAPBODY((G), 0, (ABASE), S0h, S0l, S1h, S1l);                          \
        TAPBODY((G), 1, (ABASE), S1h, S1l, S0h, S0l);                          \
        TAPBODY((G), 2, (ABASE), S0h, S0l, S1h, S1l);                          \
        TAPBODY((G), 3, (ABASE), S1h, S1l, S0h, S0l);                          \
        TAPBODY((G), 4, (ABASE), S0h, S0l, S1h, S1l);                          \
        TAPBODY((G), 5, (ABASE), S1h, S1l, S0h, S0l);                          \
        TAPBODY((G), 6, (ABASE), S0h, S0l, S1h, S1l);                          \
        TAPBODY((G), 7, (ABASE), S1h, S1l, S0h, S0l);                          \
        TAPBODY((G), 8, (ABASE), S0h, S0l, S1h, S1l);                          \
    }

#define GROUPEND                                                               \
    __builtin_amdgcn_sched_barrier(0);                                         \
    asm volatile("s_waitcnt lgkmcnt(0)" ::: "memory");                         \
    asm volatile("s_waitcnt vmcnt(%0)" :: "n"(2*NFR) : "memory");              \
    __builtin_amdgcn_s_barrier();                                              \
    __builtin_amdgcn_sched_barrier(0);

    stageA(0, 0);
    LOADB(0, 0, bhX, blX);
    __builtin_amdgcn_sched_barrier(0);
    asm volatile("s_waitcnt vmcnt(%0)" :: "n"(2*NFR) : "memory");
    __builtin_amdgcn_s_barrier();
    __builtin_amdgcn_sched_barrier(0);

#pragma unroll 1
    for (int g = 0; g < NG; g += 2) {
        if (g + 1 < NG) stageA(g + 1, 1);
        GROUPBODY(g, 0, bhX, blX, bhY, blY);
        GROUPEND
        if (g + 2 < NG) stageA(g + 2, 0);
        GROUPBODY(g + 1, ASZ, bhY, blY, bhX, blX);
        GROUPEND
    }
#undef GROUPEND
#undef GROUPBODY
#undef TAPBODY
#undef LOADB
    __syncthreads();

    // ---- fused 1x1 epilogue (compile-time KK) ----
    float biasv[NFR];
#pragma unroll
    for (int nf = 0; nf < NFR; ++nf) biasv[nf] = bias1[wnb + nf*32 + l31];
    float w2v[NFR][KK];
#pragma unroll
    for (int nf = 0; nf < NFR; ++nf)
#pragma unroll
        for (int k = 0; k < KK; ++k) w2v[nf][k] = w2[k*256 + wnb + nf*32 + l31];

    float* Lacc = (float*)ALds;               // [4][96][KK] <= 16.9KB
#pragma unroll
    for (int mf = 0; mf < MFR; ++mf) {
#pragma unroll
        for (int r = 0; r < 16; ++r) {
            float v[KK];
#pragma unroll
            for (int k = 0; k < KK; ++k) v[k] = 0.f;
#pragma unroll
            for (int nf = 0; nf < NFR; ++nf) {
                float rr = fmaxf(acc[mf][nf][r] + biasv[nf], 0.f);
#pragma unroll
                for (int k = 0; k < KK; ++k) v[k] += rr * w2v[nf][k];
            }
#pragma unroll
            for (int k = 0; k < KK; ++k) {
                v[k] += __shfl_xor(v[k], 1);
                v[k] += __shfl_xor(v[k], 2);
                v[k] += __shfl_xor(v[k], 4);
                v[k] += __shfl_xor(v[k], 8);
                v[k] += __shfl_xor(v[k], 16);
            }
            if (l31 == 0) {
                int crow = (r & 3) + 8*(r >> 2) + 4*hh2;
                int row96 = mf*32 + crow;
#pragma unroll
                for (int k = 0; k < KK; ++k)
                    Lacc[((size_t)wid*96 + row96)*KK + k] = v[k];
            }
        }
    }
    __syncthreads();
    for (int i = tid; i < 96*KK; i += 256) {
        int row96 = i / KK, k = i - row96*KK;
        float s = b2[k];
#pragma unroll
        for (int w = 0; w < 4; ++w) s += Lacc[((size_t)w*96 + row96)*KK + k];
        dst[((size_t)bidx*KK + k)*HW_ + pimg0 + row96] = s;
    }
}

// ---------------------------------------------------------------------------
// Fused softmax/mask probability maps: blockIdx.y 0=L, 1=R (2-class), 2=O
// (11-class argmax+softmax, writes pO + class map).
// ---------------------------------------------------------------------------
__global__ __launch_bounds__(256)
void prob3_kernel(const float* __restrict__ l2, const float* __restrict__ l3,
                  const float* __restrict__ l4, float* __restrict__ pL,
                  float* __restrict__ pR, float* __restrict__ pO,
                  int* __restrict__ cstar)
{
    int i = blockIdx.x * 256 + threadIdx.x;
    if (i >= B_ * HW_) return;
    int b = i / HW_, pix = i - b * HW_;
    if (blockIdx.y < 2) {
        const float* logits = blockIdx.y ? l3 : l2;
        float* p0 = blockIdx.y ? pR : pL;
        float v0 = logits[(size_t)b * 2 * HW_ + pix];
        float v1 = logits[(size_t)b * 2 * HW_ + HW_ + pix];
        float m = fmaxf(v0, v1);
        float e0 = expf(v0 - m), e1 = expf(v1 - m);
        p0[i] = e0 / (e0 + e1);
    } else {
        const float* lb = l4 + (size_t)b * 11 * HW_ + pix;
        float l[11];
#pragma unroll
        for (int c2 = 0; c2 < 11; ++c2) l[c2] = lb[(size_t)c2 * HW_];
        float m = l[0];
#pragma unroll
        for (int c2 = 1; c2 < 11; ++c2) m = fmaxf(m, l[c2]);
        float sum = 0.f;
#pragma unroll
        for (int c2 = 0; c2 < 11; ++c2) sum += expf(l[c2] - m);
        int a = 0; float bestl = l[0];
#pragma unroll
        for (int c2 = 1; c2 < 10; ++c2)
            if (l[c2] > bestl) { bestl = l[c2]; a = c2; }
        pO[i] = expf(bestl - m) / sum;
        cstar[i] = a;
    }
}

// Fused NMS score maps: blockIdx.y 0=L, 1=R, 2=O (class-masked neighbors).
__global__ __launch_bounds__(256)
void score3_kernel(const float* __restrict__ pL, const float* __restrict__ pR,
                   const float* __restrict__ pO, const int* __restrict__ cs,
                   float* __restrict__ sL, float* __restrict__ sR,
                   float* __restrict__ sO)
{
    int i = blockIdx.x * 256 + threadIdx.x;
    if (i >= B_ * HW_) return;
    int pix = i % HW_;
    int yy = pix / W_, xx = pix - (pix / W_) * W_;
    const float* p = (blockIdx.y == 0) ? pL : (blockIdx.y == 1) ? pR : pO;
    float* sc = (blockIdx.y == 0) ? sL : (blockIdx.y == 1) ? sR : sO;
    float c = p[i];
    bool ok = (c >= EPS_);
    int base = i - pix;
    if (blockIdx.y < 2) {
#pragma unroll
        for (int dy = -1; dy <= 1; ++dy)
#pragma unroll
            for (int dx = -1; dx <= 1; ++dx) {
                if (dy == 0 && dx == 0) continue;
                int ny = yy + dy, nx = xx + dx;
                float v = 0.f;
                if (ny >= 0 && ny < H_ && nx >= 0 && nx < W_) v = p[base + ny * W_ + nx];
                ok = ok && (c >= v);
            }
    } else {
        int cc = cs[i];
#pragma unroll
        for (int dy = -1; dy <= 1; ++dy)
#pragma unroll
            for (int dx = -1; dx <= 1; ++dx) {
                if (dy == 0 && dx == 0) continue;
                int ny = yy + dy, nx = xx + dx;
                float v = 0.f;
                if (ny >= 0 && ny < H_ && nx >= 0 && nx < W_) {
                    int n = base + ny * W_ + nx;
                    v = (cs[n] == cc) ? p[n] : 0.f;
                }
                ok = ok && (c >= v);
            }
    }
    sc[i] = c + (ok ? 1.f : 0.f);
}

// ---------------------------------------------------------------------------
// top-k by iterative argmax, fast path: scores are strictly positive, so the
// IEEE bit pattern is order-monotone -> pack (valueBits<<32 | (HW-idx)) into
// a u64; max-reduce == (value desc, index asc) == jax.lax.top_k order.
// Per-thread max cached; only the winner's owner thread (idx%256) rescans.
// 2 barriers/iter (was 9).
// ---------------------------------------------------------------------------
__global__ __launch_bounds__(256)
void topk_kernel(const float* __restrict__ scL, const float* __restrict__ scR,
                 const float* __restrict__ scO, int* __restrict__ idx)
{
    __shared__ float sv[HW_];
    __shared__ unsigned long long wb[4];
    __shared__ int bsh;
    const int h = blockIdx.x, b = blockIdx.y;
    const float* src = (h == 0) ? scL : (h == 1) ? scR : scO;
    const int k = (h == 2) ? 20 : 40;
    const int off = b * NQ_ + ((h == 0) ? 0 : (h == 1) ? 40 : 80);
    const int tid = threadIdx.x, lane = tid & 63, wid = tid >> 6;

    for (int t = tid; t < HW_; t += 256) sv[t] = src[(size_t)b * HW_ + t];
    __syncthreads();

    unsigned long long best = 0;
    for (int t = tid; t < HW_; t += 256) {
        float v = sv[t];
        unsigned long long key = ((unsigned long long)__float_as_uint(v) << 32)
                               | (unsigned)(HW_ - t);
        if (v >= 0.f && key > best) best = key;
    }

    for (int kk = 0; kk < k; ++kk) {
        unsigned long long r = best;
#pragma unroll
        for (int o = 32; o > 0; o >>= 1) {
            unsigned long long q = __shfl_xor(r, o);
            if (q > r) r = q;
        }
        if (lane == 0) wb[wid] = r;
        __syncthreads();
        if (tid == 0) {
            unsigned long long m = wb[0];
            if (wb[1] > m) m = wb[1];
            if (wb[2] > m) m = wb[2];
            if (wb[3] > m) m = wb[3];
            int bi = HW_ - (int)(unsigned)(m & 0xffffffffu);
            idx[off + kk] = bi;
            sv[bi] = -1.f;                 // removed marker (scores > 0)
            bsh = bi;
        }
        __syncthreads();
        if ((bsh & 255) == tid) {          // owner rebuilds its cached max
            best = 0;
            for (int t = tid; t < HW_; t += 256) {
                float v = sv[t];
                unsigned long long key = ((unsigned long long)__float_as_uint(v) << 32)
                                       | (unsigned)(HW_ - t);
                if (v >= 0.f && key > best) best = key;
            }
        }
    }
}

// ---------------------------------------------------------------------------
// Contact branch tail (unchanged)
// ---------------------------------------------------------------------------
__global__ __launch_bounds__(128)
void pool_kernel(const float* __restrict__ h2, float* __restrict__ pooled)
{
    int bc = blockIdx.x;
    __shared__ float row[96];
    for (int hh = threadIdx.x; hh < 96; hh += 128) {
        const float* p = h2 + (size_t)bc * HW_ + hh * W_;
        float s = 0.f;
        for (int ww = 0; ww < 96; ++ww) s += p[ww];
        row[hh] = s * (1.f / 96.f);
    }
    __syncthreads();
    for (int i = threadIdx.x; i < 778; i += 128) {
        int s0 = (i * 96) / 778;
        int e0 = ((i + 1) * 96 + 777) / 778;
        float s = 0.f;
        for (int t = s0; t < e0; ++t) s += row[t];
        pooled[(size_t)bc * 778 + i] = s / (float)(e0 - s0);
    }
}

__global__ __launch_bounds__(256)
void cm_kernel(const float* __restrict__ pooled, const float* __restrict__ cm_lw,
               const float* __restrict__ cm_lb, float* __restrict__ out5)
{
    const int j = blockIdx.x;
    const float* wr = cm_lw + (size_t)j * 24896;
    float acc[8];
#pragma unroll
    for (int b = 0; b < 8; ++b) acc[b] = 0.f;
    for (int t = threadIdx.x; t < 24896; t += 256) {
        float w = wr[t];
#pragma unroll
        for (int b = 0; b < 8; ++b) acc[b] += w * pooled[(size_t)b * 24896 + t];
    }
    __shared__ float red[8][256];
#pragma unroll
    for (int b = 0; b < 8; ++b) red[b][threadIdx.x] = acc[b];
    __syncthreads();
    for (int s = 128; s > 0; s >>= 1) {
        if (threadIdx.x < s) {
#pragma unroll
            for (int b = 0; b < 8; ++b) red[b][threadIdx.x] += red[b][threadIdx.x + s];
        }
        __syncthreads();
    }
    if (threadIdx.x < 8)
        out5[(size_t)threadIdx.x * 1556 + j] = red[threadIdx.x][0] + cm_lb[j];
}

__global__ __launch_bounds__(256)
void c1d_kernel(const float* __restrict__ cmap, const float* __restrict__ w,
                const float* __restrict__ bias, float* __restrict__ ccmean)
{
    int b = blockIdx.x;
    __shared__ float r[2][778];
    __shared__ float T[2][3];
    for (int t = threadIdx.x; t < 1556; t += 256)
        r[t / 778][t % 778] = cmap[(size_t)b * 1556 + t];
    __syncthreads();
    if (threadIdx.x < 2) {
        int ic = threadIdx.x;
        float s = 0.f;
        for (int i2 = 0; i2 < 778; ++i2) s += r[ic][i2];
        T[ic][0] = s - r[ic][776] - r[ic][777];
        T[ic][1] = s - r[ic][0]   - r[ic][777];
        T[ic][2] = s - r[ic][0]   - r[ic][1];
    }
    __syncthreads();
    int oc = threadIdx.x;
    float a = 0.f;
#pragma unroll
    for (int ic = 0; ic < 2; ++ic)
#pragma unroll
        for (int k = 0; k < 3; ++k)
            a += w[oc * 6 + ic * 3 + k] * T[ic][k];
    ccmean[b * 256 + oc] = a / 776.f + bias[oc];
}

__global__ __launch_bounds__(256)
void feat_kernel(const float* __restrict__ ccmean, const float* __restrict__ q_lw,
                 const float* __restrict__ q_lb, float* __restrict__ feat)
{
    __shared__ float cc[8][256];
    for (int t = threadIdx.x; t < 2048; t += 256) cc[t >> 8][t & 255] = ccmean[t];
    __syncthreads();
    int j = blockIdx.x * 256 + threadIdx.x;
    const float* wr = q_lw + (size_t)j * 256;
    float acc[8];
#pragma unroll
    for (int b = 0; b < 8; ++b) acc[b] = 0.f;
    for (int c = 0; c < 256; ++c) {
        float wv = wr[c];
#pragma unroll
        for (int b = 0; b < 8; ++b) acc[b] += wv * cc[b][c];
    }
    float qb = q_lb[j];
#pragma unroll
    for (int b = 0; b < 8; ++b) feat[(size_t)b * 25600 + j] = acc[b] + qb;
}

__global__ __launch_bounds__(256)
void gather_kernel(const float* __restrict__ x, const float* __restrict__ pos,
                   const float* __restrict__ feat, const int* __restrict__ idx,
                   float* __restrict__ out0, float* __restrict__ out1)
{
    int t = blockIdx.x * 256 + threadIdx.x;
    if (t >= B_ * C_ * NQ_) return;
    int q = t % NQ_;
    int c2 = (t / NQ_) % C_;
    int b = t / (C_ * NQ_);
    int p = idx[b * NQ_ + q];
    out0[t] = x[((size_t)b * C_ + c2) * HW_ + p] + feat[(size_t)b * 25600 + c2 * NQ_ + q];
    out1[t] = pos[(size_t)c2 * HW_ + p];
}

// ---------------------------------------------------------------------------
extern "C" void kernel_launch(void* const* d_in, const int* in_sizes, int n_in,
                              void* d_out, int out_size, void* d_ws, size_t ws_size,
                              hipStream_t stream) {
    const float* x    = (const float*)d_in[0];
    const float* y    = (const float*)d_in[1];
    const float* pos  = (const float*)d_in[2];
    const float* lw1  = (const float*)d_in[3];  const float* lb1 = (const float*)d_in[4];
    const float* lw2  = (const float*)d_in[5];  const float* lb2 = (const float*)d_in[6];
    const float* rw1  = (const float*)d_in[7];  const float* rb1 = (const float*)d_in[8];
    const float* rw2  = (const float*)d_in[9];  const float* rb2 = (const float*)d_in[10];
    const float* ow1  = (const float*)d_in[11]; const float* ob1 = (const float*)d_in[12];
    const float* ow2  = (const float*)d_in[13]; const float* ob2 = (const float*)d_in[14];
    const float* cw1  = (const float*)d_in[15]; const float* cb1 = (const float*)d_in[16];
    const float* cw2  = (const float*)d_in[17]; const float* cb2 = (const float*)d_in[18];
    const float* cmlw = (const float*)d_in[19]; const float* cmlb = (const float*)d_in[20];
    const float* c1dw = (const float*)d_in[21]; const float* c1db = (const float*)d_in[22];
    const float* qlw  = (const float*)d_in[23]; const float* qlb  = (const float*)d_in[24];

    float* out  = (float*)d_out;
    float* out0 = out;                 // topk_proposals [8,256,100]
    float* out1 = out + 204800;        // topk_pos       [8,256,100]
    float* out2 = out + 409600;        // left_logits    [8,2,96,96]
    float* out3 = out + 557056;        // right_logits   [8,2,96,96]
    float* out4 = out + 704512;        // obj_logits     [8,11,96,96]
    float* out5 = out + 1515520;       // contact_map    [8,2,778,1]

    float* ws = (float*)d_ws;
    ushort_t* Rh   = (ushort_t*)(ws);                       // 76880*256 ush
    ushort_t* Rl   = (ushort_t*)(ws + 9840640);
    ushort_t* h1h  = (ushort_t*)(ws + 19681280);            // 76880*64 ush
    ushort_t* h1l  = (ushort_t*)(ws + 22141440);
    float*    h2   = ws + 24601600;                         // 8*32*9216 fp32
    ushort_t* wLh  = (ushort_t*)(ws + 26960896);            // 9*256*256 ush each
    ushort_t* wLl  = (ushort_t*)(ws + 27255808);
    ushort_t* wRh  = (ushort_t*)(ws + 27550720);
    ushort_t* wRl  = (ushort_t*)(ws + 27845632);
    ushort_t* wOh  = (ushort_t*)(ws + 28140544);
    ushort_t* wOl  = (ushort_t*)(ws + 28435456);
    ushort_t* wc1h = (ushort_t*)(ws + 28730368);            // 9*64*256
    ushort_t* wc1l = (ushort_t*)(ws + 28804096);
    ushort_t* wc2h = (ushort_t*)(ws + 28877824);            // 9*32*64
    ushort_t* wc2l = (ushort_t*)(ws + 28887040);
    float* pooled  = ws + 28896256;                         // 8*32*778
    float* ccmean  = ws + 29095424;                         // 2048
    float* feat    = ws + 29097472;                         // 204800
    float* pmapL   = ws + 29302272;                         // 73728
    int*   csmap   = (int*)(ws + 29376000);                 // 73728
    float* scL     = ws + 29449728;
    float* scR     = ws + 29523456;
    float* scO     = ws + 29597184;
    int*   idxb    = (int*)(ws + 29670912);                 // 800
    float* bias1all= ws + 29671712;                         // 768
    float* w2all   = ws + 29672480;                         // 8448
    float* b2all   = ws + 29680928;                         // 48
    float* pmapR   = ws + 29680976;                         // 73728
    float* pmapO   = ws + 29754704;                         // 73728
    (void)in_sizes; (void)n_in; (void)out_size; (void)ws_size; (void)pos;

    // ---- one-time zeroing + weight/param packing (merged launches) ----
    zero_border2_kernel<<<dim3(388, 2), 256, 0, stream>>>(Rh, Rl, h1h, h1l);
    repack3_kernel<<<dim3((9*256*256+255)/256, 3), 256, 0, stream>>>(
        lw1, rw1, ow1, wLh, wLl, wRh, wRl, wOh, wOl);
    repack_kernel<<<(9*64*256+255)/256,  256, 0, stream>>>(cw1, wc1h, wc1l, 64, 256);
    repack_kernel<<<(9*32*64+255)/256,   256, 0, stream>>>(cw2, wc2h, wc2l, 32, 64);
    pack_heads3_kernel<<<33, 256, 0, stream>>>(lb1, rb1, ob1, lw2, rw2, ow2,
                                               lb2, rb2, ob2, bias1all, w2all, b2all);

    // ---- contact branch (R holds padded yt; freed after conv1) ----
    tsplit_kernel<<<dim3(288, 8, 8), 256, 0, stream>>>(y, Rh, Rl, 256);
    conv_gemm_kernel<3,2,3,1,256,1><<<256, 384, 0, stream>>>(
        Rh, Rl, wc1h, wc1l, cb1, h1h, h1l, nullptr);
    conv_gemm_kernel<3,1,3,1,64,2><<<256, 192, 0, stream>>>(
        h1h, h1l, wc2h, wc2l, cb2, nullptr, nullptr, h2);
    pool_kernel<<<256, 128, 0, stream>>>(h2, pooled);
    cm_kernel<<<1556, 256, 0, stream>>>(pooled, cmlw, cmlb, out5);
    c1d_kernel<<<8, 256, 0, stream>>>(out5, c1dw, c1db, ccmean);
    feat_kernel<<<100, 256, 0, stream>>>(ccmean, qlw, qlb, feat);

    // ---- heads: L+R unified (KK=2, head-major), then O (KK=11) ----
    tsplit_kernel<<<dim3(288, 8, 8), 256, 0, stream>>>(x, Rh, Rl, 256);
    conv_sbt_kernel<2,2><<<1536, 256, 0, stream>>>(
        Rh, Rl, wLh, wLl, wRh, wRl, bias1all, w2all, b2all, out2);
    conv_sbt_kernel<11,1><<<768, 256, 0, stream>>>(
        Rh, Rl, wOh, wOl, wOh, wOl, bias1all + 512, w2all + 2*2816,
        b2all + 22, out4);

    // ---- probs / NMS scores (all 3 heads in 2 launches) ----
    prob3_kernel<<<dim3(288, 3), 256, 0, stream>>>(out2, out3, out4,
                                                   pmapL, pmapR, pmapO, csmap);
    score3_kernel<<<dim3(288, 3), 256, 0, stream>>>(pmapL, pmapR, pmapO, csmap,
                                                    scL, scR, scO);

    // ---- topk + gathers ----
    topk_kernel<<<dim3(3, 8), 256, 0, stream>>>(scL, scR, scO, idxb);
    gather_kernel<<<800, 256, 0, stream>>>(x, pos, feat, idxb, out0, out1);
}